// Round 8
// baseline (652.302 us; speedup 1.0000x reference)
//
#include <hip/hip_runtime.h>
#include <hip/hip_bf16.h>
#include <cstdint>
#include <cstddef>

#define NN 50000     // nodes
#define EE 1000000   // edges
#define NB 2         // batch

#define MSTR 72      // activation tile stride (shorts): 144 B rows (cols 0..63 = m, 64..71 = phi/swv spare)

// packed-weight layout (shorts): B-fragment order [kstep][ntile][lane][8]
#define P_E1 0
#define P_E2 10240
#define P_C1 14336
#define P_F1 18432
#define P_F2 26624

// d_ws byte offsets
#define WS_CNT   0            // int[NN]
#define WS_OFF   200704       // int[NN+1]
#define WS_CUR   401408       // int[NN]
#define WS_EIDS  602112       // int[EE]
#define WS_PK    4602112      // short[30720]
#define WS_HB    4663552      // short[NB*NN*64]   (12.8 MB)
#define WS_RS    17463552     // int[EE]           (4 MB)
#define WS_CS    21463552     // int[EE]           (4 MB)
#define WS_RAD   25463552     // float[NB*EE]      (8 MB)
#define WS_XC    33463552     // short[NB*EE*4]    (16 MB)
#define WS_EAS   49463552     // short[NB*EE*16]   (64 MB)
// total ~113.5 MB

typedef __attribute__((ext_vector_type(8))) short short8;
typedef __attribute__((ext_vector_type(4))) short short4_t;
typedef __attribute__((ext_vector_type(4))) float f32x4;

__device__ __forceinline__ float fast_rcp(float v) { return __builtin_amdgcn_rcpf(v); }
__device__ __forceinline__ float silu_f(float v) { return v * fast_rcp(1.0f + __expf(-v)); }
__device__ __forceinline__ float ssgn_f(float v) { return v * fast_rcp(1.0f + fabsf(v)); }

__device__ __forceinline__ short f2bf(float f) {
    __hip_bfloat16 h = __float2bfloat16(f);
    return *reinterpret_cast<short*>(&h);
}
__device__ __forceinline__ float bf2f(short s) {
    union { unsigned u; float f; } c; c.u = ((unsigned)(unsigned short)s) << 16; return c.f;
}
__device__ __forceinline__ short8 pack8(float4 a, float4 b) {
    short8 r;
    r[0] = f2bf(a.x); r[1] = f2bf(a.y); r[2] = f2bf(a.z); r[3] = f2bf(a.w);
    r[4] = f2bf(b.x); r[5] = f2bf(b.y); r[6] = f2bf(b.z); r[7] = f2bf(b.w);
    return r;
}

// ---------------------------------------------------------------------------
__global__ void conv_h(const float* __restrict__ h, short* __restrict__ hb16) {
    size_t i = ((size_t)blockIdx.x * 256 + threadIdx.x) * 8;
    float4 lo = *reinterpret_cast<const float4*>(h + i);
    float4 hi = *reinterpret_cast<const float4*>(h + i + 4);
    *reinterpret_cast<short8*>(hb16 + i) = pack8(lo, hi);
}

__global__ void hist_kernel(const int* __restrict__ ei, int* __restrict__ cnt_i) {
    int e = blockIdx.x * 256 + threadIdx.x;
    if (e < EE) atomicAdd(&cnt_i[ei[e]], 1);
}

__global__ void scan_kernel(const int* __restrict__ cnt_i,
                            int* __restrict__ off, int* __restrict__ cur) {
    __shared__ int part[1024];
    const int t = threadIdx.x;
    const int CH = (NN + 1023) / 1024;
    int base = t * CH;
    int s = 0;
    for (int j = 0; j < CH; j++) { int idx = base + j; if (idx < NN) s += cnt_i[idx]; }
    part[t] = s;
    __syncthreads();
    for (int d = 1; d < 1024; d <<= 1) {
        int v = (t >= d) ? part[t - d] : 0;
        __syncthreads();
        part[t] += v;
        __syncthreads();
    }
    int excl = (t == 0) ? 0 : part[t - 1];
    for (int j = 0; j < CH; j++) {
        int idx = base + j;
        if (idx < NN) { off[idx] = excl; cur[idx] = excl; excl += cnt_i[idx]; }
    }
    if (t == 1023) off[NN] = part[1023];
}

__global__ void scatter_kernel(const int* __restrict__ ei,
                               int* __restrict__ cur, int* __restrict__ eids) {
    int e = blockIdx.x * 256 + threadIdx.x;
    if (e < EE) {
        int p = atomicAdd(&cur[ei[e]], 1);
        eids[p] = e;
    }
}

// ---------------------------------------------------------------------------
// Pregather: resolve all per-edge random accesses once, emit sorted coalesced
// streams. Pure-memory kernel at max occupancy -> TA lookups fully pipelined.
// ---------------------------------------------------------------------------
__global__ void pregather(const int* __restrict__ ei, const float* __restrict__ x,
                          const float* __restrict__ ea, const int* __restrict__ eids,
                          int* __restrict__ rs, int* __restrict__ cs,
                          float* __restrict__ radS, short* __restrict__ xcS,
                          short* __restrict__ eaS)
{
    int p = blockIdx.x * 256 + threadIdx.x;
    if (p >= EE) return;
    int eid = eids[p];
    int r = ei[eid], c = ei[EE + eid];
    rs[p] = r; cs[p] = c;
    #pragma unroll
    for (int b = 0; b < NB; b++) {
        float4 xr = *reinterpret_cast<const float4*>(x + ((size_t)b * NN + r) * 4);
        float4 xc = *reinterpret_cast<const float4*>(x + ((size_t)b * NN + c) * 4);
        float d0 = xr.x - xc.x, d1 = xr.y - xc.y, d2 = xr.z - xc.z, d3 = xr.w - xc.w;
        radS[(size_t)b * EE + p] = d1 * d1 + d2 * d2 + d3 * d3 - d0 * d0;
        short4_t s4;
        s4[0] = f2bf(xc.x); s4[1] = f2bf(xc.y); s4[2] = f2bf(xc.z); s4[3] = f2bf(xc.w);
        *reinterpret_cast<short4_t*>(xcS + ((size_t)b * EE + p) * 4) = s4;
        const float4* eap = reinterpret_cast<const float4*>(ea + ((size_t)b * EE + eid) * 16);
        float4 a0 = eap[0], a1 = eap[1], a2 = eap[2], a3 = eap[3];
        short* dst = eaS + ((size_t)b * EE + p) * 16;
        *reinterpret_cast<short8*>(dst)     = pack8(a0, a1);
        *reinterpret_cast<short8*>(dst + 8) = pack8(a2, a3);
    }
}

// ---------------------------------------------------------------------------
__global__ void pack_weights(const float* __restrict__ w_e1,
                             const float* __restrict__ w_e2,
                             const float* __restrict__ w_c1,
                             const float* __restrict__ w_f1,
                             const float* __restrict__ w_f2,
                             short* __restrict__ pk)
{
    int g = blockIdx.x * 256 + threadIdx.x;
    const int G_E1 = 5 * 4 * 64, G_E2 = 2 * 4 * 64, G_C1 = 2 * 4 * 64;
    const int G_F1 = 4 * 4 * 64, G_F2 = 2 * 4 * 64;
    if (g >= G_E1 + G_E2 + G_C1 + G_F1 + G_F2) return;
    const float* W; int loc; int mat;
    if (g < G_E1)                        { W = w_e1; loc = g;                         mat = 0; }
    else if (g < G_E1+G_E2)              { W = w_e2; loc = g - G_E1;                  mat = 1; }
    else if (g < G_E1+G_E2+G_C1)         { W = w_c1; loc = g - G_E1 - G_E2;           mat = 2; }
    else if (g < G_E1+G_E2+G_C1+G_F1)    { W = w_f1; loc = g - G_E1 - G_E2 - G_C1;    mat = 3; }
    else                                 { W = w_f2; loc = g - G_E1-G_E2-G_C1-G_F1;   mat = 4; }
    int l = loc & 63, n = (loc >> 6) & 3, s = loc >> 8;
    short8 out;
    #pragma unroll
    for (int j = 0; j < 8; j++) {
        int kp = s * 32 + ((l >> 4) * 8) + j;
        int ko; bool valid;
        if (mat == 0) {
            if (kp < 128)      { ko = kp;     valid = true; }
            else if (kp < 144) { ko = kp + 1; valid = true; }   // ea rows (orig 129..144)
            else if (kp == 144){ ko = 128;    valid = true; }   // radial row
            else               { ko = 0;      valid = false; }
        } else if (mat == 3) { ko = kp; valid = kp < 128; }
        else                 { ko = kp; valid = kp < 64; }
        float v = valid ? W[ko * 64 + (n * 16 + (l & 15))] : 0.0f;
        out[j] = f2bf(v);
    }
    *reinterpret_cast<short8*>(pk + (size_t)g * 8) = out;
}

// ---------------------------------------------------------------------------
// Edge kernel: only h gathers remain divergent; all else coalesced streams.
// ---------------------------------------------------------------------------
__global__ __launch_bounds__(256, 4) void edge_kernel(
    const short* __restrict__ hb16, const float* __restrict__ x,
    const int* __restrict__ rs, const int* __restrict__ cs,
    const float* __restrict__ radS, const short* __restrict__ xcS,
    const short* __restrict__ eaS,
    const float* __restrict__ b_e1, const float* __restrict__ b_e2,
    const float* __restrict__ b_c1, const float* __restrict__ w_c2,
    const short* __restrict__ pk,
    const float* __restrict__ sm_p, const float* __restrict__ om_p,
    float* __restrict__ agg, float* __restrict__ xagg)
{
    __shared__ short smem[4][64 * MSTR];   // 9216 B / wave, 36864 / block
    const int wid  = threadIdx.x >> 6;
    const int lane = threadIdx.x & 63;
    short* sm  = smem[wid];
    float* smf = reinterpret_cast<float*>(sm);

    // bijective XCD swizzle (m204)
    const int nwg = gridDim.x;
    const int q = nwg >> 3, r_ = nwg & 7;
    const int xcd = blockIdx.x & 7, kk = blockIdx.x >> 3;
    const int bswz = (xcd < r_ ? xcd * (q + 1) : r_ * (q + 1) + (xcd - r_) * q) + kk;

    const int WPB = EE / 64;
    const int gw = bswz * 4 + wid;
    if (gw >= NB * WPB) return;            // no barriers anywhere: safe
    const int b  = gw / WPB;
    const int i0 = (gw - b * WPB) * 64;

    const int l15 = lane & 15;
    const int gq  = lane >> 4;
    const int kg  = gq * 8;

    const int row = rs[i0 + lane];         // coalesced
    const float4 xr = *reinterpret_cast<const float4*>(x + ((size_t)b * NN + row) * 4); // run-merged gather
    short4_t xc4 = *reinterpret_cast<const short4_t*>(xcS + ((size_t)b * EE + i0 + lane) * 4);
    const float xcx = bf2f(xc4[0]), xcy = bf2f(xc4[1]), xcz = bf2f(xc4[2]), xcw = bf2f(xc4[3]);

    int rowm[4], colm[4];
    #pragma unroll
    for (int m = 0; m < 4; m++) {
        rowm[m] = rs[i0 + m * 16 + l15];   // coalesced 16-wide
        colm[m] = cs[i0 + m * 16 + l15];
    }
    const short* hbb = hb16 + (size_t)b * NN * 64;
    const short8* pke1 = reinterpret_cast<const short8*>(pk + P_E1);
    const short8* pke2 = reinterpret_cast<const short8*>(pk + P_E2);
    const short8* pkc1 = reinterpret_cast<const short8*>(pk + P_C1);

    // ---- col fragments upfront (the only random-HBM-ish gathers left) ----
    short8 colf[2][4];
    #pragma unroll
    for (int s2 = 0; s2 < 2; s2++)
        #pragma unroll
        for (int m = 0; m < 4; m++)
            colf[s2][m] = *reinterpret_cast<const short8*>(
                hbb + (size_t)colm[m] * 64 + s2 * 32 + kg);

    // ---- tail fragment from coalesced eaS/radS ----
    short8 tail[4];
    #pragma unroll
    for (int m = 0; m < 4; m++) {
        short8 v = short8{0, 0, 0, 0, 0, 0, 0, 0};
        if (gq < 2)
            v = *reinterpret_cast<const short8*>(
                eaS + ((size_t)b * EE + i0 + m * 16 + l15) * 16 + gq * 8);
        else if (gq == 2)
            v[0] = f2bf(radS[(size_t)b * EE + i0 + m * 16 + l15]);
        tail[m] = v;
    }

    // ---- GEMM1 ----
    f32x4 acc[4][4];
    #pragma unroll
    for (int n = 0; n < 4; n++) {
        float bias = b_e1[n * 16 + l15];
        #pragma unroll
        for (int m = 0; m < 4; m++) acc[m][n] = f32x4{bias, bias, bias, bias};
    }
    // tail first (frees its registers early)
    __builtin_amdgcn_s_setprio(1);
    #pragma unroll
    for (int n = 0; n < 4; n++) {
        short8 bfr = pke1[(4 * 4 + n) * 64 + lane];
        #pragma unroll
        for (int m = 0; m < 4; m++)
            acc[m][n] = __builtin_amdgcn_mfma_f32_16x16x32_bf16(tail[m], bfr, acc[m][n], 0, 0, 0);
    }
    __builtin_amdgcn_s_setprio(0);
    // rows (L1-friendly, loaded in-loop)
    #pragma unroll
    for (int s = 0; s < 2; s++) {
        short8 afr[4];
        #pragma unroll
        for (int m = 0; m < 4; m++)
            afr[m] = *reinterpret_cast<const short8*>(
                hbb + (size_t)rowm[m] * 64 + s * 32 + kg);
        __builtin_amdgcn_s_setprio(1);
        #pragma unroll
        for (int n = 0; n < 4; n++) {
            short8 bfr = pke1[(s * 4 + n) * 64 + lane];
            #pragma unroll
            for (int m = 0; m < 4; m++)
                acc[m][n] = __builtin_amdgcn_mfma_f32_16x16x32_bf16(afr[m], bfr, acc[m][n], 0, 0, 0);
        }
        __builtin_amdgcn_s_setprio(0);
    }
    // cols (prefetched)
    #pragma unroll
    for (int s2 = 0; s2 < 2; s2++) {
        __builtin_amdgcn_s_setprio(1);
        #pragma unroll
        for (int n = 0; n < 4; n++) {
            short8 bfr = pke1[((2 + s2) * 4 + n) * 64 + lane];
            #pragma unroll
            for (int m = 0; m < 4; m++)
                acc[m][n] = __builtin_amdgcn_mfma_f32_16x16x32_bf16(colf[s2][m], bfr, acc[m][n], 0, 0, 0);
        }
        __builtin_amdgcn_s_setprio(0);
    }

    // ---- t1 = silu(acc) -> LDS ----
    #pragma unroll
    for (int m = 0; m < 4; m++)
        #pragma unroll
        for (int n = 0; n < 4; n++)
            #pragma unroll
            for (int r = 0; r < 4; r++)
                sm[(m * 16 + gq * 4 + r) * MSTR + n * 16 + l15] = f2bf(silu_f(acc[m][n][r]));
    asm volatile("s_waitcnt lgkmcnt(0)" ::: "memory");

    // ---- GEMM2 ----
    f32x4 acc2[4][4];
    #pragma unroll
    for (int n = 0; n < 4; n++) {
        float bias = b_e2[n * 16 + l15];
        #pragma unroll
        for (int m = 0; m < 4; m++) acc2[m][n] = f32x4{bias, bias, bias, bias};
    }
    #pragma unroll
    for (int s = 0; s < 2; s++) {
        short8 afr[4];
        #pragma unroll
        for (int m = 0; m < 4; m++)
            afr[m] = *reinterpret_cast<const short8*>(sm + (m * 16 + l15) * MSTR + s * 32 + kg);
        __builtin_amdgcn_s_setprio(1);
        #pragma unroll
        for (int n = 0; n < 4; n++) {
            short8 bfr = pke2[(s * 4 + n) * 64 + lane];
            #pragma unroll
            for (int m = 0; m < 4; m++)
                acc2[m][n] = __builtin_amdgcn_mfma_f32_16x16x32_bf16(afr[m], bfr, acc2[m][n], 0, 0, 0);
        }
        __builtin_amdgcn_s_setprio(0);
    }
    asm volatile("s_waitcnt lgkmcnt(0)" ::: "memory");

    // ---- m = softsign(acc2) -> LDS ----
    #pragma unroll
    for (int m = 0; m < 4; m++)
        #pragma unroll
        for (int n = 0; n < 4; n++)
            #pragma unroll
            for (int r = 0; r < 4; r++)
                sm[(m * 16 + gq * 4 + r) * MSTR + n * 16 + l15] = f2bf(ssgn_f(acc2[m][n][r]));
    asm volatile("s_waitcnt lgkmcnt(0)" ::: "memory");

    // ---- GEMM3 + phi ----
    f32x4 acc3[4][4];
    #pragma unroll
    for (int n = 0; n < 4; n++) {
        float bias = b_c1[n * 16 + l15];
        #pragma unroll
        for (int m = 0; m < 4; m++) acc3[m][n] = f32x4{bias, bias, bias, bias};
    }
    #pragma unroll
    for (int s = 0; s < 2; s++) {
        short8 afr[4];
        #pragma unroll
        for (int m = 0; m < 4; m++)
            afr[m] = *reinterpret_cast<const short8*>(sm + (m * 16 + l15) * MSTR + s * 32 + kg);
        __builtin_amdgcn_s_setprio(1);
        #pragma unroll
        for (int n = 0; n < 4; n++) {
            short8 bfr = pkc1[(s * 4 + n) * 64 + lane];
            #pragma unroll
            for (int m = 0; m < 4; m++)
                acc3[m][n] = __builtin_amdgcn_mfma_f32_16x16x32_bf16(afr[m], bfr, acc3[m][n], 0, 0, 0);
        }
        __builtin_amdgcn_s_setprio(0);
    }
    float wc2v[4];
    #pragma unroll
    for (int n = 0; n < 4; n++) wc2v[n] = w_c2[n * 16 + l15];
    #pragma unroll
    for (int m = 0; m < 4; m++)
        #pragma unroll
        for (int r = 0; r < 4; r++) {
            float v = 0.0f;
            #pragma unroll
            for (int n = 0; n < 4; n++) v = fmaf(silu_f(acc3[m][n][r]), wc2v[n], v);
            v += __shfl_xor(v, 1); v += __shfl_xor(v, 2);
            v += __shfl_xor(v, 4); v += __shfl_xor(v, 8);
            // phi -> spare slot of the m-tile (float idx E*36+32, byte E*144+128)
            if (l15 == 0) smf[(m * 16 + gq * 4 + r) * 36 + 32] = v;
        }
    asm volatile("s_waitcnt lgkmcnt(0)" ::: "memory");
    const float phiv = smf[lane * 36 + 32];
    asm volatile("s_waitcnt lgkmcnt(0)" ::: "memory");

    // ---- weighted coordinates into the spare slot (float4, 16B-aligned) ----
    const float smv = sm_p[0], omv = om_p[0];
    float4 wv;
    wv.x = (smv * xr.x + omv * xcx) * phiv;
    wv.y = (smv * xr.y + omv * xcy) * phiv;
    wv.z = (smv * xr.z + omv * xcz) * phiv;
    wv.w = (smv * xr.w + omv * xcw) * phiv;
    *reinterpret_cast<float4*>(smf + lane * 36 + 32) = wv;
    asm volatile("s_waitcnt lgkmcnt(0)" ::: "memory");

    // ---- ballot run-merged scatter ----
    int nrow = __shfl_down(row, 1);
    unsigned long long bmask = __ballot((lane == 63) || (row != nrow));
    float* aggb = agg + (size_t)b * NN * 64;
    float* xb   = xagg + (size_t)b * NN * 4;
    float mv = 0.0f, xv = 0.0f;
    #pragma unroll
    for (int e = 0; e < 64; e++) {
        mv += bf2f(sm[e * MSTR + lane]);
        float t = smf[e * 36 + 32 + (lane & 3)];
        xv += (lane < 4) ? t : 0.0f;
        if ((bmask >> e) & 1ull) {
            int re = __shfl(row, e);
            atomicAdd(aggb + (size_t)re * 64 + lane, mv);
            if (lane < 4) atomicAdd(xb + (size_t)re * 4 + lane, xv);
            mv = 0.0f; xv = 0.0f;
        }
    }
}

// ---------------------------------------------------------------------------
__global__ __launch_bounds__(256, 4) void node_kernel(
    const short* __restrict__ hb16, const float* __restrict__ x,
    const float* __restrict__ b_f1, const float* __restrict__ b_f2,
    const short* __restrict__ pk,
    const int* __restrict__ off,
    float* out_h, float* out_x)
{
    __shared__ short smem[4][64 * MSTR];
    const int wid  = threadIdx.x >> 6;
    const int lane = threadIdx.x & 63;
    short* sm = smem[wid];

    const int WN = (NN + 63) / 64;
    const int gw = blockIdx.x * 4 + wid;
    if (gw >= NB * WN) return;
    const int b  = gw / WN;
    const int n0 = (gw - b * WN) * 64;

    const int l15 = lane & 15;
    const int gq  = lane >> 4;
    const int kg  = gq * 8;

    const short* hbb  = hb16 + (size_t)b * NN * 64;
    const float* aggb = out_h + (size_t)b * NN * 64;

    f32x4 acc[4][4];
    #pragma unroll
    for (int n = 0; n < 4; n++) {
        float bias = b_f1[n * 16 + l15];
        #pragma unroll
        for (int m = 0; m < 4; m++) acc[m][n] = f32x4{bias, bias, bias, bias};
    }
    const short8* pkf1 = reinterpret_cast<const short8*>(pk + P_F1);
    #pragma unroll
    for (int s = 0; s < 4; s++) {
        short8 afr[4];
        #pragma unroll
        for (int m = 0; m < 4; m++) {
            int nd = n0 + m * 16 + l15;
            if (nd >= NN) nd = NN - 1;
            if (s < 2) {
                afr[m] = *reinterpret_cast<const short8*>(
                    hbb + (size_t)nd * 64 + s * 32 + kg);
            } else {
                const float* base = aggb + (size_t)nd * 64 + (s & 1) * 32 + kg;
                float4 lo = *reinterpret_cast<const float4*>(base);
                float4 hi = *reinterpret_cast<const float4*>(base + 4);
                afr[m] = pack8(lo, hi);
            }
        }
        __builtin_amdgcn_s_setprio(1);
        #pragma unroll
        for (int n = 0; n < 4; n++) {
            short8 bfr = pkf1[(s * 4 + n) * 64 + lane];
            #pragma unroll
            for (int m = 0; m < 4; m++)
                acc[m][n] = __builtin_amdgcn_mfma_f32_16x16x32_bf16(afr[m], bfr, acc[m][n], 0, 0, 0);
        }
        __builtin_amdgcn_s_setprio(0);
    }

    #pragma unroll
    for (int m = 0; m < 4; m++)
        #pragma unroll
        for (int n = 0; n < 4; n++)
            #pragma unroll
            for (int r = 0; r < 4; r++)
                sm[(m * 16 + gq * 4 + r) * MSTR + n * 16 + l15] = f2bf(silu_f(acc[m][n][r]));
    asm volatile("s_waitcnt lgkmcnt(0)" ::: "memory");

    f32x4 acc2[4][4];
    #pragma unroll
    for (int n = 0; n < 4; n++) {
        float bias = b_f2[n * 16 + l15];
        #pragma unroll
        for (int m = 0; m < 4; m++) acc2[m][n] = f32x4{bias, bias, bias, bias};
    }
    const short8* pkf2 = reinterpret_cast<const short8*>(pk + P_F2);
    #pragma unroll
    for (int s = 0; s < 2; s++) {
        short8 afr[4];
        #pragma unroll
        for (int m = 0; m < 4; m++)
            afr[m] = *reinterpret_cast<const short8*>(sm + (m * 16 + l15) * MSTR + s * 32 + kg);
        __builtin_amdgcn_s_setprio(1);
        #pragma unroll
        for (int n = 0; n < 4; n++) {
            short8 bfr = pkf2[(s * 4 + n) * 64 + lane];
            #pragma unroll
            for (int m = 0; m < 4; m++)
                acc2[m][n] = __builtin_amdgcn_mfma_f32_16x16x32_bf16(afr[m], bfr, acc2[m][n], 0, 0, 0);
        }
        __builtin_amdgcn_s_setprio(0);
    }

    float* ohb = out_h + (size_t)b * NN * 64;
    #pragma unroll
    for (int m = 0; m < 4; m++)
        #pragma unroll
        for (int r = 0; r < 4; r++) {
            int nd = n0 + m * 16 + gq * 4 + r;
            if (nd < NN) {
                #pragma unroll
                for (int n = 0; n < 4; n++)
                    ohb[(size_t)nd * 64 + n * 16 + l15] = ssgn_f(acc2[m][n][r]);
            }
        }

    const int node = n0 + lane;
    if (node < NN) {
        int c_i = off[node + 1] - off[node];
        float c = (float)(c_i < 1 ? 1 : c_i);
        float invc = fast_rcp(c);
        const float4 xv = *reinterpret_cast<const float4*>(x + ((size_t)b * NN + node) * 4);
        float* xop = out_x + ((size_t)b * NN + node) * 4;
        float4 xa = *reinterpret_cast<float4*>(xop);
        float4 r;
        r.x = xv.x + xa.x * invc;
        r.y = xv.y + xa.y * invc;
        r.z = xv.z + xa.z * invc;
        r.w = xv.w + xa.w * invc;
        *reinterpret_cast<float4*>(xop) = r;
    }
}

// ---------------------------------------------------------------------------
extern "C" void kernel_launch(void* const* d_in, const int* in_sizes, int n_in,
                              void* d_out, int out_size, void* d_ws, size_t ws_size,
                              hipStream_t stream) {
    const float* h    = (const float*)d_in[0];
    const float* x    = (const float*)d_in[1];
    const int*   ei   = (const int*)d_in[2];
    const float* ea   = (const float*)d_in[3];
    const float* w_e1 = (const float*)d_in[4];
    const float* b_e1 = (const float*)d_in[5];
    const float* w_e2 = (const float*)d_in[6];
    const float* b_e2 = (const float*)d_in[7];
    const float* w_f1 = (const float*)d_in[8];
    const float* b_f1 = (const float*)d_in[9];
    const float* w_f2 = (const float*)d_in[10];
    const float* b_f2 = (const float*)d_in[11];
    const float* w_c1 = (const float*)d_in[12];
    const float* b_c1 = (const float*)d_in[13];
    const float* w_c2 = (const float*)d_in[14];
    const float* smp  = (const float*)d_in[15];
    const float* omp  = (const float*)d_in[16];

    float* out   = (float*)d_out;
    float* agg   = out;
    float* out_x = out + (size_t)NB * NN * 64;

    char* ws = (char*)d_ws;
    int*   cnt_i = (int*)(ws + WS_CNT);
    int*   off   = (int*)(ws + WS_OFF);
    int*   cur   = (int*)(ws + WS_CUR);
    int*   eids  = (int*)(ws + WS_EIDS);
    short* pk    = (short*)(ws + WS_PK);
    short* hb16  = (short*)(ws + WS_HB);
    int*   rs    = (int*)(ws + WS_RS);
    int*   cs    = (int*)(ws + WS_CS);
    float* radS  = (float*)(ws + WS_RAD);
    short* xcS   = (short*)(ws + WS_XC);
    short* eaS   = (short*)(ws + WS_EAS);

    hipMemsetAsync(d_out, 0, (size_t)out_size * sizeof(float), stream);
    hipMemsetAsync(cnt_i, 0, (size_t)NN * sizeof(int), stream);

    pack_weights<<<15, 256, 0, stream>>>(w_e1, w_e2, w_c1, w_f1, w_f2, pk);
    conv_h<<<3125, 256, 0, stream>>>(h, hb16);

    const int eb = (EE + 255) / 256;
    hist_kernel<<<eb, 256, 0, stream>>>(ei, cnt_i);
    scan_kernel<<<1, 1024, 0, stream>>>(cnt_i, off, cur);
    scatter_kernel<<<eb, 256, 0, stream>>>(ei, cur, eids);
    pregather<<<eb, 256, 0, stream>>>(ei, x, ea, eids, rs, cs, radS, xcS, eaS);

    const int edge_waves = NB * (EE / 64);            // 31250
    const int edge_blocks = (edge_waves + 3) / 4;     // 7813
    edge_kernel<<<edge_blocks, 256, 0, stream>>>(
        hb16, x, rs, cs, radS, xcS, eaS,
        b_e1, b_e2, b_c1, w_c2, pk, smp, omp, agg, out_x);

    const int node_waves = NB * ((NN + 63) / 64);
    const int node_blocks = (node_waves + 3) / 4;
    node_kernel<<<node_blocks, 256, 0, stream>>>(
        hb16, x, b_f1, b_f2, pk, off, agg, out_x);
}

// Round 9
// 553.746 us; speedup vs baseline: 1.1780x; 1.1780x over previous
//
#include <hip/hip_runtime.h>
#include <hip/hip_bf16.h>
#include <cstdint>
#include <cstddef>

#define NN 50000     // nodes
#define EE 1000000   // edges
#define NB 2         // batch

#define MSTR 72      // tile stride (shorts): 144 B rows; cols 0..63 = m, 64..71 spare (phi/swv)

// packed-weight layout (shorts): B-fragment order [kstep][ntile][lane][8]
#define P_E1 0
#define P_E2 10240
#define P_C1 14336
#define P_F1 18432
#define P_F2 26624

// d_ws byte offsets
#define WS_CNT   0            // int[NN]
#define WS_OFF   200704       // int[NN+1]
#define WS_CUR   401408       // int[NN]
#define WS_EIDS  602112       // int[EE]
#define WS_PK    4602112      // short[30720]
#define WS_HB    4663552      // short[NB*NN*64]  (12.8 MB)

typedef __attribute__((ext_vector_type(8))) short short8;
typedef __attribute__((ext_vector_type(4))) float f32x4;

__device__ __forceinline__ float fast_rcp(float v) { return __builtin_amdgcn_rcpf(v); }
__device__ __forceinline__ float silu_f(float v) { return v * fast_rcp(1.0f + __expf(-v)); }
__device__ __forceinline__ float ssgn_f(float v) { return v * fast_rcp(1.0f + fabsf(v)); }

__device__ __forceinline__ short f2bf(float f) {
    __hip_bfloat16 h = __float2bfloat16(f);
    return *reinterpret_cast<short*>(&h);
}
__device__ __forceinline__ float bf2f(short s) {
    union { unsigned u; float f; } c; c.u = ((unsigned)(unsigned short)s) << 16; return c.f;
}
__device__ __forceinline__ short8 pack8(float4 a, float4 b) {
    short8 r;
    r[0] = f2bf(a.x); r[1] = f2bf(a.y); r[2] = f2bf(a.z); r[3] = f2bf(a.w);
    r[4] = f2bf(b.x); r[5] = f2bf(b.y); r[6] = f2bf(b.z); r[7] = f2bf(b.w);
    return r;
}

// ---------------------------------------------------------------------------
__global__ void conv_h(const float* __restrict__ h, short* __restrict__ hb16) {
    size_t i = ((size_t)blockIdx.x * 256 + threadIdx.x) * 8;
    float4 lo = *reinterpret_cast<const float4*>(h + i);
    float4 hi = *reinterpret_cast<const float4*>(h + i + 4);
    *reinterpret_cast<short8*>(hb16 + i) = pack8(lo, hi);
}

__global__ void hist_kernel(const int* __restrict__ ei, int* __restrict__ cnt_i) {
    int e = blockIdx.x * 256 + threadIdx.x;
    if (e < EE) atomicAdd(&cnt_i[ei[e]], 1);
}

__global__ void scan_kernel(const int* __restrict__ cnt_i,
                            int* __restrict__ off, int* __restrict__ cur) {
    __shared__ int part[1024];
    const int t = threadIdx.x;
    const int CH = (NN + 1023) / 1024;
    int base = t * CH;
    int s = 0;
    for (int j = 0; j < CH; j++) { int idx = base + j; if (idx < NN) s += cnt_i[idx]; }
    part[t] = s;
    __syncthreads();
    for (int d = 1; d < 1024; d <<= 1) {
        int v = (t >= d) ? part[t - d] : 0;
        __syncthreads();
        part[t] += v;
        __syncthreads();
    }
    int excl = (t == 0) ? 0 : part[t - 1];
    for (int j = 0; j < CH; j++) {
        int idx = base + j;
        if (idx < NN) { off[idx] = excl; cur[idx] = excl; excl += cnt_i[idx]; }
    }
    if (t == 1023) off[NN] = part[1023];
}

__global__ void scatter_kernel(const int* __restrict__ ei,
                               int* __restrict__ cur, int* __restrict__ eids) {
    int e = blockIdx.x * 256 + threadIdx.x;
    if (e < EE) {
        int p = atomicAdd(&cur[ei[e]], 1);
        eids[p] = e;
    }
}

__global__ void pack_weights(const float* __restrict__ w_e1,
                             const float* __restrict__ w_e2,
                             const float* __restrict__ w_c1,
                             const float* __restrict__ w_f1,
                             const float* __restrict__ w_f2,
                             short* __restrict__ pk)
{
    int g = blockIdx.x * 256 + threadIdx.x;
    const int G_E1 = 5 * 4 * 64, G_E2 = 2 * 4 * 64, G_C1 = 2 * 4 * 64;
    const int G_F1 = 4 * 4 * 64, G_F2 = 2 * 4 * 64;
    if (g >= G_E1 + G_E2 + G_C1 + G_F1 + G_F2) return;
    const float* W; int loc; int mat;
    if (g < G_E1)                        { W = w_e1; loc = g;                         mat = 0; }
    else if (g < G_E1+G_E2)              { W = w_e2; loc = g - G_E1;                  mat = 1; }
    else if (g < G_E1+G_E2+G_C1)         { W = w_c1; loc = g - G_E1 - G_E2;           mat = 2; }
    else if (g < G_E1+G_E2+G_C1+G_F1)    { W = w_f1; loc = g - G_E1 - G_E2 - G_C1;    mat = 3; }
    else                                 { W = w_f2; loc = g - G_E1-G_E2-G_C1-G_F1;   mat = 4; }
    int l = loc & 63, n = (loc >> 6) & 3, s = loc >> 8;
    short8 out;
    #pragma unroll
    for (int j = 0; j < 8; j++) {
        int kp = s * 32 + ((l >> 4) * 8) + j;
        int ko; bool valid;
        if (mat == 0) {
            if (kp < 128)      { ko = kp;     valid = true; }
            else if (kp < 144) { ko = kp + 1; valid = true; }   // ea rows (orig 129..144)
            else if (kp == 144){ ko = 128;    valid = true; }   // radial row
            else               { ko = 0;      valid = false; }
        } else if (mat == 3) { ko = kp; valid = kp < 128; }
        else                 { ko = kp; valid = kp < 64; }
        float v = valid ? W[ko * 64 + (n * 16 + (l & 15))] : 0.0f;
        out[j] = f2bf(v);
    }
    *reinterpret_cast<short8*>(pk + (size_t)g * 8) = out;
}

// ---------------------------------------------------------------------------
// Edge kernel: M=32 per wave (2 m-tiles). 4.6 KB LDS/wave -> high occupancy.
// ---------------------------------------------------------------------------
__global__ __launch_bounds__(256, 5) void edge_kernel(
    const short* __restrict__ hb16, const float* __restrict__ x,
    const int* __restrict__ ei, const float* __restrict__ ea,
    const int* __restrict__ eids,
    const float* __restrict__ b_e1, const float* __restrict__ b_e2,
    const float* __restrict__ b_c1, const float* __restrict__ w_c2,
    const short* __restrict__ pk,
    const float* __restrict__ sm_p, const float* __restrict__ om_p,
    float* __restrict__ agg, float* __restrict__ xagg)
{
    __shared__ short smem[4][32 * MSTR];   // 4608 B / wave, 18432 / block
    const int wid  = threadIdx.x >> 6;
    const int lane = threadIdx.x & 63;
    short* sm  = smem[wid];
    float* smf = reinterpret_cast<float*>(sm);

    // bijective XCD swizzle (m204)
    const int nwg = gridDim.x;
    const int q = nwg >> 3, r_ = nwg & 7;
    const int xcd = blockIdx.x & 7, kk = blockIdx.x >> 3;
    const int bswz = (xcd < r_ ? xcd * (q + 1) : r_ * (q + 1) + (xcd - r_) * q) + kk;

    const int WPB = EE / 32;               // 31250 waves per batch
    const int gw = bswz * 4 + wid;
    if (gw >= NB * WPB) return;            // no barriers anywhere: safe
    const int b  = gw / WPB;
    const int i0 = (gw - b * WPB) * 32;    // sorted position base (32 edges)

    const int l15 = lane & 15;
    const int gq  = lane >> 4;
    const int kg  = gq * 8;

    // per-edge scalars on lanes 0..31
    int eid = 0, row = 0, col = 0;
    float4 xr = float4{0, 0, 0, 0}, xc = float4{0, 0, 0, 0};
    float radial = 0.0f;
    if (lane < 32) {
        eid = eids[i0 + lane];
        row = ei[eid];
        col = ei[EE + eid];
        xr = *reinterpret_cast<const float4*>(x + ((size_t)b * NN + row) * 4);
        xc = *reinterpret_cast<const float4*>(x + ((size_t)b * NN + col) * 4);
        float d0 = xr.x - xc.x, d1 = xr.y - xc.y, d2 = xr.z - xc.z, d3 = xr.w - xc.w;
        radial = d1 * d1 + d2 * d2 + d3 * d3 - d0 * d0;
    }

    int rowm[2], colm[2], eidm[2];
    float radm[2];
    #pragma unroll
    for (int m = 0; m < 2; m++) {
        int src = m * 16 + l15;            // < 32
        rowm[m] = __shfl(row, src);
        colm[m] = __shfl(col, src);
        eidm[m] = __shfl(eid, src);
        radm[m] = __shfl(radial, src);
    }
    const short* hbb = hb16 + (size_t)b * NN * 64;
    const short8* pke1 = reinterpret_cast<const short8*>(pk + P_E1);
    const short8* pke2 = reinterpret_cast<const short8*>(pk + P_E2);
    const short8* pkc1 = reinterpret_cast<const short8*>(pk + P_C1);

    // ---- col fragments upfront (random gathers, longest latency) ----
    short8 colf[2][2];
    #pragma unroll
    for (int s2 = 0; s2 < 2; s2++)
        #pragma unroll
        for (int m = 0; m < 2; m++)
            colf[s2][m] = *reinterpret_cast<const short8*>(
                hbb + (size_t)colm[m] * 64 + s2 * 32 + kg);

    // ---- tail fragment: ea (random 32B) / radial ----
    short8 tail[2];
    #pragma unroll
    for (int m = 0; m < 2; m++) {
        short8 v = short8{0, 0, 0, 0, 0, 0, 0, 0};
        if (gq < 2) {
            const float* src = ea + ((size_t)b * EE + eidm[m]) * 16 + gq * 8;
            float4 lo = *reinterpret_cast<const float4*>(src);
            float4 hi = *reinterpret_cast<const float4*>(src + 4);
            v = pack8(lo, hi);
        } else if (gq == 2) {
            v[0] = f2bf(radm[m]);
        }
        tail[m] = v;
    }

    // ---- GEMM1 ----
    f32x4 acc[2][4];
    #pragma unroll
    for (int n = 0; n < 4; n++) {
        float bias = b_e1[n * 16 + l15];
        #pragma unroll
        for (int m = 0; m < 2; m++) acc[m][n] = f32x4{bias, bias, bias, bias};
    }
    // tail first
    __builtin_amdgcn_s_setprio(1);
    #pragma unroll
    for (int n = 0; n < 4; n++) {
        short8 bfr = pke1[(4 * 4 + n) * 64 + lane];
        #pragma unroll
        for (int m = 0; m < 2; m++)
            acc[m][n] = __builtin_amdgcn_mfma_f32_16x16x32_bf16(tail[m], bfr, acc[m][n], 0, 0, 0);
    }
    __builtin_amdgcn_s_setprio(0);
    // rows (run-repeated, L1-friendly)
    #pragma unroll
    for (int s = 0; s < 2; s++) {
        short8 afr[2];
        #pragma unroll
        for (int m = 0; m < 2; m++)
            afr[m] = *reinterpret_cast<const short8*>(
                hbb + (size_t)rowm[m] * 64 + s * 32 + kg);
        __builtin_amdgcn_s_setprio(1);
        #pragma unroll
        for (int n = 0; n < 4; n++) {
            short8 bfr = pke1[(s * 4 + n) * 64 + lane];
            #pragma unroll
            for (int m = 0; m < 2; m++)
                acc[m][n] = __builtin_amdgcn_mfma_f32_16x16x32_bf16(afr[m], bfr, acc[m][n], 0, 0, 0);
        }
        __builtin_amdgcn_s_setprio(0);
    }
    // cols (prefetched)
    #pragma unroll
    for (int s2 = 0; s2 < 2; s2++) {
        __builtin_amdgcn_s_setprio(1);
        #pragma unroll
        for (int n = 0; n < 4; n++) {
            short8 bfr = pke1[((2 + s2) * 4 + n) * 64 + lane];
            #pragma unroll
            for (int m = 0; m < 2; m++)
                acc[m][n] = __builtin_amdgcn_mfma_f32_16x16x32_bf16(colf[s2][m], bfr, acc[m][n], 0, 0, 0);
        }
        __builtin_amdgcn_s_setprio(0);
    }

    // ---- t1 = silu(acc) -> LDS ----
    #pragma unroll
    for (int m = 0; m < 2; m++)
        #pragma unroll
        for (int n = 0; n < 4; n++)
            #pragma unroll
            for (int r = 0; r < 4; r++)
                sm[(m * 16 + gq * 4 + r) * MSTR + n * 16 + l15] = f2bf(silu_f(acc[m][n][r]));
    asm volatile("s_waitcnt lgkmcnt(0)" ::: "memory");

    // ---- GEMM2 ----
    f32x4 acc2[2][4];
    #pragma unroll
    for (int n = 0; n < 4; n++) {
        float bias = b_e2[n * 16 + l15];
        #pragma unroll
        for (int m = 0; m < 2; m++) acc2[m][n] = f32x4{bias, bias, bias, bias};
    }
    #pragma unroll
    for (int s = 0; s < 2; s++) {
        short8 afr[2];
        #pragma unroll
        for (int m = 0; m < 2; m++)
            afr[m] = *reinterpret_cast<const short8*>(sm + (m * 16 + l15) * MSTR + s * 32 + kg);
        __builtin_amdgcn_s_setprio(1);
        #pragma unroll
        for (int n = 0; n < 4; n++) {
            short8 bfr = pke2[(s * 4 + n) * 64 + lane];
            #pragma unroll
            for (int m = 0; m < 2; m++)
                acc2[m][n] = __builtin_amdgcn_mfma_f32_16x16x32_bf16(afr[m], bfr, acc2[m][n], 0, 0, 0);
        }
        __builtin_amdgcn_s_setprio(0);
    }
    asm volatile("s_waitcnt lgkmcnt(0)" ::: "memory");

    // ---- m = softsign(acc2) -> LDS ----
    #pragma unroll
    for (int m = 0; m < 2; m++)
        #pragma unroll
        for (int n = 0; n < 4; n++)
            #pragma unroll
            for (int r = 0; r < 4; r++)
                sm[(m * 16 + gq * 4 + r) * MSTR + n * 16 + l15] = f2bf(ssgn_f(acc2[m][n][r]));
    asm volatile("s_waitcnt lgkmcnt(0)" ::: "memory");

    // ---- GEMM3 + phi ----
    f32x4 acc3[2][4];
    #pragma unroll
    for (int n = 0; n < 4; n++) {
        float bias = b_c1[n * 16 + l15];
        #pragma unroll
        for (int m = 0; m < 2; m++) acc3[m][n] = f32x4{bias, bias, bias, bias};
    }
    #pragma unroll
    for (int s = 0; s < 2; s++) {
        short8 afr[2];
        #pragma unroll
        for (int m = 0; m < 2; m++)
            afr[m] = *reinterpret_cast<const short8*>(sm + (m * 16 + l15) * MSTR + s * 32 + kg);
        __builtin_amdgcn_s_setprio(1);
        #pragma unroll
        for (int n = 0; n < 4; n++) {
            short8 bfr = pkc1[(s * 4 + n) * 64 + lane];
            #pragma unroll
            for (int m = 0; m < 2; m++)
                acc3[m][n] = __builtin_amdgcn_mfma_f32_16x16x32_bf16(afr[m], bfr, acc3[m][n], 0, 0, 0);
        }
        __builtin_amdgcn_s_setprio(0);
    }
    float wc2v[4];
    #pragma unroll
    for (int n = 0; n < 4; n++) wc2v[n] = w_c2[n * 16 + l15];
    #pragma unroll
    for (int m = 0; m < 2; m++)
        #pragma unroll
        for (int r = 0; r < 4; r++) {
            float v = 0.0f;
            #pragma unroll
            for (int n = 0; n < 4; n++) v = fmaf(silu_f(acc3[m][n][r]), wc2v[n], v);
            v += __shfl_xor(v, 1); v += __shfl_xor(v, 2);
            v += __shfl_xor(v, 4); v += __shfl_xor(v, 8);
            // phi -> spare slot (float idx E*36+32)
            if (l15 == 0) smf[(m * 16 + gq * 4 + r) * 36 + 32] = v;
        }
    asm volatile("s_waitcnt lgkmcnt(0)" ::: "memory");

    // ---- weighted coordinates into spare slots (lanes 0..31, one edge each) ----
    if (lane < 32) {
        const float phiv = smf[lane * 36 + 32];
        const float smv = sm_p[0], omv = om_p[0];
        float4 wv;
        wv.x = (smv * xr.x + omv * xc.x) * phiv;
        wv.y = (smv * xr.y + omv * xc.y) * phiv;
        wv.z = (smv * xr.z + omv * xc.z) * phiv;
        wv.w = (smv * xr.w + omv * xc.w) * phiv;
        *reinterpret_cast<float4*>(smf + lane * 36 + 32) = wv;
    }
    asm volatile("s_waitcnt lgkmcnt(0)" ::: "memory");

    // ---- ballot run-merged scatter over 32 edges ----
    int nrow = __shfl_down(row, 1);
    unsigned long long bmask = __ballot((lane == 31) || (lane < 31 && row != nrow));
    float* aggb = agg + (size_t)b * NN * 64;
    float* xb   = xagg + (size_t)b * NN * 4;
    float mv = 0.0f, xv = 0.0f;
    #pragma unroll
    for (int e = 0; e < 32; e++) {
        mv += bf2f(sm[e * MSTR + lane]);
        float t = smf[e * 36 + 32 + (lane & 3)];
        xv += (lane < 4) ? t : 0.0f;
        if ((bmask >> e) & 1ull) {
            int re = __shfl(row, e);
            atomicAdd(aggb + (size_t)re * 64 + lane, mv);
            if (lane < 4) atomicAdd(xb + (size_t)re * 4 + lane, xv);
            mv = 0.0f; xv = 0.0f;
        }
    }
}

// ---------------------------------------------------------------------------
__global__ __launch_bounds__(256, 4) void node_kernel(
    const short* __restrict__ hb16, const float* __restrict__ x,
    const float* __restrict__ b_f1, const float* __restrict__ b_f2,
    const short* __restrict__ pk,
    const int* __restrict__ off,
    float* out_h, float* out_x)
{
    __shared__ short smem[4][64 * MSTR];
    const int wid  = threadIdx.x >> 6;
    const int lane = threadIdx.x & 63;
    short* sm = smem[wid];

    const int WN = (NN + 63) / 64;
    const int gw = blockIdx.x * 4 + wid;
    if (gw >= NB * WN) return;
    const int b  = gw / WN;
    const int n0 = (gw - b * WN) * 64;

    const int l15 = lane & 15;
    const int gq  = lane >> 4;
    const int kg  = gq * 8;

    const short* hbb  = hb16 + (size_t)b * NN * 64;
    const float* aggb = out_h + (size_t)b * NN * 64;

    f32x4 acc[4][4];
    #pragma unroll
    for (int n = 0; n < 4; n++) {
        float bias = b_f1[n * 16 + l15];
        #pragma unroll
        for (int m = 0; m < 4; m++) acc[m][n] = f32x4{bias, bias, bias, bias};
    }
    const short8* pkf1 = reinterpret_cast<const short8*>(pk + P_F1);
    #pragma unroll
    for (int s = 0; s < 4; s++) {
        short8 afr[4];
        #pragma unroll
        for (int m = 0; m < 4; m++) {
            int nd = n0 + m * 16 + l15;
            if (nd >= NN) nd = NN - 1;
            if (s < 2) {
                afr[m] = *reinterpret_cast<const short8*>(
                    hbb + (size_t)nd * 64 + s * 32 + kg);
            } else {
                const float* base = aggb + (size_t)nd * 64 + (s & 1) * 32 + kg;
                float4 lo = *reinterpret_cast<const float4*>(base);
                float4 hi = *reinterpret_cast<const float4*>(base + 4);
                afr[m] = pack8(lo, hi);
            }
        }
        __builtin_amdgcn_s_setprio(1);
        #pragma unroll
        for (int n = 0; n < 4; n++) {
            short8 bfr = pkf1[(s * 4 + n) * 64 + lane];
            #pragma unroll
            for (int m = 0; m < 4; m++)
                acc[m][n] = __builtin_amdgcn_mfma_f32_16x16x32_bf16(afr[m], bfr, acc[m][n], 0, 0, 0);
        }
        __builtin_amdgcn_s_setprio(0);
    }

    #pragma unroll
    for (int m = 0; m < 4; m++)
        #pragma unroll
        for (int n = 0; n < 4; n++)
            #pragma unroll
            for (int r = 0; r < 4; r++)
                sm[(m * 16 + gq * 4 + r) * MSTR + n * 16 + l15] = f2bf(silu_f(acc[m][n][r]));
    asm volatile("s_waitcnt lgkmcnt(0)" ::: "memory");

    f32x4 acc2[4][4];
    #pragma unroll
    for (int n = 0; n < 4; n++) {
        float bias = b_f2[n * 16 + l15];
        #pragma unroll
        for (int m = 0; m < 4; m++) acc2[m][n] = f32x4{bias, bias, bias, bias};
    }
    const short8* pkf2 = reinterpret_cast<const short8*>(pk + P_F2);
    #pragma unroll
    for (int s = 0; s < 2; s++) {
        short8 afr[4];
        #pragma unroll
        for (int m = 0; m < 4; m++)
            afr[m] = *reinterpret_cast<const short8*>(sm + (m * 16 + l15) * MSTR + s * 32 + kg);
        __builtin_amdgcn_s_setprio(1);
        #pragma unroll
        for (int n = 0; n < 4; n++) {
            short8 bfr = pkf2[(s * 4 + n) * 64 + lane];
            #pragma unroll
            for (int m = 0; m < 4; m++)
                acc2[m][n] = __builtin_amdgcn_mfma_f32_16x16x32_bf16(afr[m], bfr, acc2[m][n], 0, 0, 0);
        }
        __builtin_amdgcn_s_setprio(0);
    }

    float* ohb = out_h + (size_t)b * NN * 64;
    #pragma unroll
    for (int m = 0; m < 4; m++)
        #pragma unroll
        for (int r = 0; r < 4; r++) {
            int nd = n0 + m * 16 + gq * 4 + r;
            if (nd < NN) {
                #pragma unroll
                for (int n = 0; n < 4; n++)
                    ohb[(size_t)nd * 64 + n * 16 + l15] = ssgn_f(acc2[m][n][r]);
            }
        }

    const int node = n0 + lane;
    if (node < NN) {
        int c_i = off[node + 1] - off[node];
        float c = (float)(c_i < 1 ? 1 : c_i);
        float invc = fast_rcp(c);
        const float4 xv = *reinterpret_cast<const float4*>(x + ((size_t)b * NN + node) * 4);
        float* xop = out_x + ((size_t)b * NN + node) * 4;
        float4 xa = *reinterpret_cast<float4*>(xop);
        float4 r;
        r.x = xv.x + xa.x * invc;
        r.y = xv.y + xa.y * invc;
        r.z = xv.z + xa.z * invc;
        r.w = xv.w + xa.w * invc;
        *reinterpret_cast<float4*>(xop) = r;
    }
}

// ---------------------------------------------------------------------------
extern "C" void kernel_launch(void* const* d_in, const int* in_sizes, int n_in,
                              void* d_out, int out_size, void* d_ws, size_t ws_size,
                              hipStream_t stream) {
    const float* h    = (const float*)d_in[0];
    const float* x    = (const float*)d_in[1];
    const int*   ei   = (const int*)d_in[2];
    const float* ea   = (const float*)d_in[3];
    const float* w_e1 = (const float*)d_in[4];
    const float* b_e1 = (const float*)d_in[5];
    const float* w_e2 = (const float*)d_in[6];
    const float* b_e2 = (const float*)d_in[7];
    const float* w_f1 = (const float*)d_in[8];
    const float* b_f1 = (const float*)d_in[9];
    const float* w_f2 = (const float*)d_in[10];
    const float* b_f2 = (const float*)d_in[11];
    const float* w_c1 = (const float*)d_in[12];
    const float* b_c1 = (const float*)d_in[13];
    const float* w_c2 = (const float*)d_in[14];
    const float* smp  = (const float*)d_in[15];
    const float* omp  = (const float*)d_in[16];

    float* out   = (float*)d_out;
    float* agg   = out;
    float* out_x = out + (size_t)NB * NN * 64;

    char* ws = (char*)d_ws;
    int*   cnt_i = (int*)(ws + WS_CNT);
    int*   off   = (int*)(ws + WS_OFF);
    int*   cur   = (int*)(ws + WS_CUR);
    int*   eids  = (int*)(ws + WS_EIDS);
    short* pk    = (short*)(ws + WS_PK);
    short* hb16  = (short*)(ws + WS_HB);

    hipMemsetAsync(d_out, 0, (size_t)out_size * sizeof(float), stream);
    hipMemsetAsync(cnt_i, 0, (size_t)NN * sizeof(int), stream);

    pack_weights<<<15, 256, 0, stream>>>(w_e1, w_e2, w_c1, w_f1, w_f2, pk);
    conv_h<<<3125, 256, 0, stream>>>(h, hb16);

    const int eb = (EE + 255) / 256;
    hist_kernel<<<eb, 256, 0, stream>>>(ei, cnt_i);
    scan_kernel<<<1, 1024, 0, stream>>>(cnt_i, off, cur);
    scatter_kernel<<<eb, 256, 0, stream>>>(ei, cur, eids);

    const int edge_waves = NB * (EE / 32);            // 62500
    const int edge_blocks = edge_waves / 4;           // 15625
    edge_kernel<<<edge_blocks, 256, 0, stream>>>(
        hb16, x, ei, ea, eids, b_e1, b_e2, b_c1, w_c2, pk,
        smp, omp, agg, out_x);

    const int node_waves = NB * ((NN + 63) / 64);
    const int node_blocks = (node_waves + 3) / 4;
    node_kernel<<<node_blocks, 256, 0, stream>>>(
        hb16, x, b_f1, b_f2, pk, off, agg, out_x);
}

// Round 10
// 532.582 us; speedup vs baseline: 1.2248x; 1.0397x over previous
//
#include <hip/hip_runtime.h>
#include <hip/hip_bf16.h>
#include <cstdint>
#include <cstddef>

#define NN 50000     // nodes
#define EE 1000000   // edges
#define NB 2         // batch

#define MSTR 72      // tile stride (shorts): 144 B rows; cols 0..63 = m, 64..71 spare (phi/swv)
#define TILE (32 * MSTR)   // one batch m-tile, shorts (2304)

// packed-weight layout (shorts): B-fragment order [kstep][ntile][lane][8]
#define P_E1 0
#define P_E2 10240
#define P_C1 14336
#define P_F1 18432
#define P_F2 26624

// d_ws byte offsets
#define WS_CNT   0            // int[NN]
#define WS_OFF   200704       // int[NN+1]
#define WS_CUR   401408       // int[NN]
#define WS_EIDS  602112       // int[EE]
#define WS_PK    4602112      // short[30720]
#define WS_HB    4663552      // short[NB*NN*64]  (12.8 MB)

typedef __attribute__((ext_vector_type(8))) short short8;
typedef __attribute__((ext_vector_type(4))) float f32x4;

__device__ __forceinline__ float fast_rcp(float v) { return __builtin_amdgcn_rcpf(v); }
__device__ __forceinline__ float silu_f(float v) { return v * fast_rcp(1.0f + __expf(-v)); }
__device__ __forceinline__ float ssgn_f(float v) { return v * fast_rcp(1.0f + fabsf(v)); }

__device__ __forceinline__ short f2bf(float f) {
    __hip_bfloat16 h = __float2bfloat16(f);
    return *reinterpret_cast<short*>(&h);
}
__device__ __forceinline__ float bf2f(short s) {
    union { unsigned u; float f; } c; c.u = ((unsigned)(unsigned short)s) << 16; return c.f;
}
__device__ __forceinline__ short8 pack8(float4 a, float4 b) {
    short8 r;
    r[0] = f2bf(a.x); r[1] = f2bf(a.y); r[2] = f2bf(a.z); r[3] = f2bf(a.w);
    r[4] = f2bf(b.x); r[5] = f2bf(b.y); r[6] = f2bf(b.z); r[7] = f2bf(b.w);
    return r;
}

// ---------------------------------------------------------------------------
__global__ void conv_h(const float* __restrict__ h, short* __restrict__ hb16) {
    size_t i = ((size_t)blockIdx.x * 256 + threadIdx.x) * 8;
    float4 lo = *reinterpret_cast<const float4*>(h + i);
    float4 hi = *reinterpret_cast<const float4*>(h + i + 4);
    *reinterpret_cast<short8*>(hb16 + i) = pack8(lo, hi);
}

__global__ void hist_kernel(const int* __restrict__ ei, int* __restrict__ cnt_i) {
    int e = blockIdx.x * 256 + threadIdx.x;
    if (e < EE) atomicAdd(&cnt_i[ei[e]], 1);
}

__global__ void scan_kernel(const int* __restrict__ cnt_i,
                            int* __restrict__ off, int* __restrict__ cur) {
    __shared__ int part[1024];
    const int t = threadIdx.x;
    const int CH = (NN + 1023) / 1024;
    int base = t * CH;
    int s = 0;
    for (int j = 0; j < CH; j++) { int idx = base + j; if (idx < NN) s += cnt_i[idx]; }
    part[t] = s;
    __syncthreads();
    for (int d = 1; d < 1024; d <<= 1) {
        int v = (t >= d) ? part[t - d] : 0;
        __syncthreads();
        part[t] += v;
        __syncthreads();
    }
    int excl = (t == 0) ? 0 : part[t - 1];
    for (int j = 0; j < CH; j++) {
        int idx = base + j;
        if (idx < NN) { off[idx] = excl; cur[idx] = excl; excl += cnt_i[idx]; }
    }
    if (t == 1023) off[NN] = part[1023];
}

__global__ void scatter_kernel(const int* __restrict__ ei,
                               int* __restrict__ cur, int* __restrict__ eids) {
    int e = blockIdx.x * 256 + threadIdx.x;
    if (e < EE) {
        int p = atomicAdd(&cur[ei[e]], 1);
        eids[p] = e;
    }
}

__global__ void pack_weights(const float* __restrict__ w_e1,
                             const float* __restrict__ w_e2,
                             const float* __restrict__ w_c1,
                             const float* __restrict__ w_f1,
                             const float* __restrict__ w_f2,
                             short* __restrict__ pk)
{
    int g = blockIdx.x * 256 + threadIdx.x;
    const int G_E1 = 5 * 4 * 64, G_E2 = 2 * 4 * 64, G_C1 = 2 * 4 * 64;
    const int G_F1 = 4 * 4 * 64, G_F2 = 2 * 4 * 64;
    if (g >= G_E1 + G_E2 + G_C1 + G_F1 + G_F2) return;
    const float* W; int loc; int mat;
    if (g < G_E1)                        { W = w_e1; loc = g;                         mat = 0; }
    else if (g < G_E1+G_E2)              { W = w_e2; loc = g - G_E1;                  mat = 1; }
    else if (g < G_E1+G_E2+G_C1)         { W = w_c1; loc = g - G_E1 - G_E2;           mat = 2; }
    else if (g < G_E1+G_E2+G_C1+G_F1)    { W = w_f1; loc = g - G_E1 - G_E2 - G_C1;    mat = 3; }
    else                                 { W = w_f2; loc = g - G_E1-G_E2-G_C1-G_F1;   mat = 4; }
    int l = loc & 63, n = (loc >> 6) & 3, s = loc >> 8;
    short8 out;
    #pragma unroll
    for (int j = 0; j < 8; j++) {
        int kp = s * 32 + ((l >> 4) * 8) + j;
        int ko; bool valid;
        if (mat == 0) {
            if (kp < 128)      { ko = kp;     valid = true; }
            else if (kp < 144) { ko = kp + 1; valid = true; }   // ea rows (orig 129..144)
            else if (kp == 144){ ko = 128;    valid = true; }   // radial row
            else               { ko = 0;      valid = false; }
        } else if (mat == 3) { ko = kp; valid = kp < 128; }
        else                 { ko = kp; valid = kp < 64; }
        float v = valid ? W[ko * 64 + (n * 16 + (l & 15))] : 0.0f;
        out[j] = f2bf(v);
    }
    *reinterpret_cast<short8*>(pk + (size_t)g * 8) = out;
}

// ---------------------------------------------------------------------------
// Edge kernel: one wave = 32 sorted edges x BOTH batches. Weight B-frags,
// index loads, ballot and scatter control shared across the batch pair.
// ---------------------------------------------------------------------------
__global__ __launch_bounds__(256, 3) void edge_kernel(
    const short* __restrict__ hb16, const float* __restrict__ x,
    const int* __restrict__ ei, const float* __restrict__ ea,
    const int* __restrict__ eids,
    const float* __restrict__ b_e1, const float* __restrict__ b_e2,
    const float* __restrict__ b_c1, const float* __restrict__ w_c2,
    const short* __restrict__ pk,
    const float* __restrict__ sm_p, const float* __restrict__ om_p,
    float* __restrict__ agg, float* __restrict__ xagg)
{
    __shared__ short smem[4][2 * TILE];    // 9216 B / wave (2 batch tiles)
    const int wid  = threadIdx.x >> 6;
    const int lane = threadIdx.x & 63;
    short* sm  = smem[wid];                // batch0 tile; batch1 at sm + TILE
    float* smf = reinterpret_cast<float*>(sm);

    // bijective XCD swizzle (m204)
    const int nwg = gridDim.x;
    const int q = nwg >> 3, r_ = nwg & 7;
    const int xcd = blockIdx.x & 7, kk = blockIdx.x >> 3;
    const int bswz = (xcd < r_ ? xcd * (q + 1) : r_ * (q + 1) + (xcd - r_) * q) + kk;

    const int WPB = EE / 32;               // 31250 edge windows
    const int gw = bswz * 4 + wid;
    if (gw >= WPB) return;                 // no barriers anywhere: safe
    const int i0 = gw * 32;

    const int l15 = lane & 15;
    const int gq  = lane >> 4;
    const int kg  = gq * 8;

    // per-edge scalars on lanes 0..31 (shared across batches)
    int eid = 0, row = 0, col = 0;
    float4 xr0 = float4{0,0,0,0}, xc0 = float4{0,0,0,0};
    float4 xr1 = float4{0,0,0,0}, xc1 = float4{0,0,0,0};
    float rad0 = 0.0f, rad1 = 0.0f;
    if (lane < 32) {
        eid = eids[i0 + lane];
        row = ei[eid];
        col = ei[EE + eid];
        xr0 = *reinterpret_cast<const float4*>(x + (size_t)row * 4);
        xc0 = *reinterpret_cast<const float4*>(x + (size_t)col * 4);
        xr1 = *reinterpret_cast<const float4*>(x + ((size_t)NN + row) * 4);
        xc1 = *reinterpret_cast<const float4*>(x + ((size_t)NN + col) * 4);
        {
            float d0 = xr0.x - xc0.x, d1 = xr0.y - xc0.y, d2 = xr0.z - xc0.z, d3 = xr0.w - xc0.w;
            rad0 = d1 * d1 + d2 * d2 + d3 * d3 - d0 * d0;
            d0 = xr1.x - xc1.x; d1 = xr1.y - xc1.y; d2 = xr1.z - xc1.z; d3 = xr1.w - xc1.w;
            rad1 = d1 * d1 + d2 * d2 + d3 * d3 - d0 * d0;
        }
    }

    int rowm[2], colm[2], eidm[2];
    float radm[2][2];
    #pragma unroll
    for (int m = 0; m < 2; m++) {
        int src = m * 16 + l15;            // < 32
        rowm[m] = __shfl(row, src);
        colm[m] = __shfl(col, src);
        eidm[m] = __shfl(eid, src);
        radm[0][m] = __shfl(rad0, src);
        radm[1][m] = __shfl(rad1, src);
    }
    const short* hbb[2] = { hb16, hb16 + (size_t)NN * 64 };
    const short8* pke1 = reinterpret_cast<const short8*>(pk + P_E1);
    const short8* pke2 = reinterpret_cast<const short8*>(pk + P_E2);
    const short8* pkc1 = reinterpret_cast<const short8*>(pk + P_C1);

    // ---- tail fragments (ea random 32B + radial), both batches ----
    short8 tail[2][2];
    #pragma unroll
    for (int b = 0; b < 2; b++)
        #pragma unroll
        for (int m = 0; m < 2; m++) {
            short8 v = short8{0, 0, 0, 0, 0, 0, 0, 0};
            if (gq < 2) {
                const float* src = ea + ((size_t)b * EE + eidm[m]) * 16 + gq * 8;
                float4 lo = *reinterpret_cast<const float4*>(src);
                float4 hi = *reinterpret_cast<const float4*>(src + 4);
                v = pack8(lo, hi);
            } else if (gq == 2) {
                v[0] = f2bf(radm[b][m]);
            }
            tail[b][m] = v;
        }

    // ---- GEMM1: acc[b][m][n] ----
    f32x4 acc[2][2][4];
    #pragma unroll
    for (int n = 0; n < 4; n++) {
        float bias = b_e1[n * 16 + l15];
        #pragma unroll
        for (int b = 0; b < 2; b++)
            #pragma unroll
            for (int m = 0; m < 2; m++) acc[b][m][n] = f32x4{bias, bias, bias, bias};
    }
    // tail first
    __builtin_amdgcn_s_setprio(1);
    #pragma unroll
    for (int n = 0; n < 4; n++) {
        short8 bfr = pke1[(4 * 4 + n) * 64 + lane];
        #pragma unroll
        for (int b = 0; b < 2; b++)
            #pragma unroll
            for (int m = 0; m < 2; m++)
                acc[b][m][n] = __builtin_amdgcn_mfma_f32_16x16x32_bf16(tail[b][m], bfr, acc[b][m][n], 0, 0, 0);
    }
    __builtin_amdgcn_s_setprio(0);
    // h rows (run-repeated, cache-friendly)
    #pragma unroll
    for (int s = 0; s < 2; s++) {
        short8 afr[2][2];
        #pragma unroll
        for (int b = 0; b < 2; b++)
            #pragma unroll
            for (int m = 0; m < 2; m++)
                afr[b][m] = *reinterpret_cast<const short8*>(
                    hbb[b] + (size_t)rowm[m] * 64 + s * 32 + kg);
        __builtin_amdgcn_s_setprio(1);
        #pragma unroll
        for (int n = 0; n < 4; n++) {
            short8 bfr = pke1[(s * 4 + n) * 64 + lane];
            #pragma unroll
            for (int b = 0; b < 2; b++)
                #pragma unroll
                for (int m = 0; m < 2; m++)
                    acc[b][m][n] = __builtin_amdgcn_mfma_f32_16x16x32_bf16(afr[b][m], bfr, acc[b][m][n], 0, 0, 0);
        }
        __builtin_amdgcn_s_setprio(0);
    }
    // h cols (random gathers)
    #pragma unroll
    for (int s2 = 0; s2 < 2; s2++) {
        short8 afr[2][2];
        #pragma unroll
        for (int b = 0; b < 2; b++)
            #pragma unroll
            for (int m = 0; m < 2; m++)
                afr[b][m] = *reinterpret_cast<const short8*>(
                    hbb[b] + (size_t)colm[m] * 64 + s2 * 32 + kg);
        __builtin_amdgcn_s_setprio(1);
        #pragma unroll
        for (int n = 0; n < 4; n++) {
            short8 bfr = pke1[((2 + s2) * 4 + n) * 64 + lane];
            #pragma unroll
            for (int b = 0; b < 2; b++)
                #pragma unroll
                for (int m = 0; m < 2; m++)
                    acc[b][m][n] = __builtin_amdgcn_mfma_f32_16x16x32_bf16(afr[b][m], bfr, acc[b][m][n], 0, 0, 0);
        }
        __builtin_amdgcn_s_setprio(0);
    }

    // ---- t1 = silu(acc) -> LDS (both batch tiles) ----
    #pragma unroll
    for (int b = 0; b < 2; b++)
        #pragma unroll
        for (int m = 0; m < 2; m++)
            #pragma unroll
            for (int n = 0; n < 4; n++)
                #pragma unroll
                for (int r = 0; r < 4; r++)
                    sm[b * TILE + (m * 16 + gq * 4 + r) * MSTR + n * 16 + l15] =
                        f2bf(silu_f(acc[b][m][n][r]));
    asm volatile("s_waitcnt lgkmcnt(0)" ::: "memory");

    // ---- GEMM2 ----
    f32x4 acc2[2][2][4];
    #pragma unroll
    for (int n = 0; n < 4; n++) {
        float bias = b_e2[n * 16 + l15];
        #pragma unroll
        for (int b = 0; b < 2; b++)
            #pragma unroll
            for (int m = 0; m < 2; m++) acc2[b][m][n] = f32x4{bias, bias, bias, bias};
    }
    #pragma unroll
    for (int s = 0; s < 2; s++) {
        short8 afr[2][2];
        #pragma unroll
        for (int b = 0; b < 2; b++)
            #pragma unroll
            for (int m = 0; m < 2; m++)
                afr[b][m] = *reinterpret_cast<const short8*>(
                    sm + b * TILE + (m * 16 + l15) * MSTR + s * 32 + kg);
        __builtin_amdgcn_s_setprio(1);
        #pragma unroll
        for (int n = 0; n < 4; n++) {
            short8 bfr = pke2[(s * 4 + n) * 64 + lane];
            #pragma unroll
            for (int b = 0; b < 2; b++)
                #pragma unroll
                for (int m = 0; m < 2; m++)
                    acc2[b][m][n] = __builtin_amdgcn_mfma_f32_16x16x32_bf16(afr[b][m], bfr, acc2[b][m][n], 0, 0, 0);
        }
        __builtin_amdgcn_s_setprio(0);
    }
    asm volatile("s_waitcnt lgkmcnt(0)" ::: "memory");

    // ---- m = softsign(acc2) -> LDS ----
    #pragma unroll
    for (int b = 0; b < 2; b++)
        #pragma unroll
        for (int m = 0; m < 2; m++)
            #pragma unroll
            for (int n = 0; n < 4; n++)
                #pragma unroll
                for (int r = 0; r < 4; r++)
                    sm[b * TILE + (m * 16 + gq * 4 + r) * MSTR + n * 16 + l15] =
                        f2bf(ssgn_f(acc2[b][m][n][r]));
    asm volatile("s_waitcnt lgkmcnt(0)" ::: "memory");

    // ---- GEMM3 + phi ----
    f32x4 acc3[2][2][4];
    #pragma unroll
    for (int n = 0; n < 4; n++) {
        float bias = b_c1[n * 16 + l15];
        #pragma unroll
        for (int b = 0; b < 2; b++)
            #pragma unroll
            for (int m = 0; m < 2; m++) acc3[b][m][n] = f32x4{bias, bias, bias, bias};
    }
    #pragma unroll
    for (int s = 0; s < 2; s++) {
        short8 afr[2][2];
        #pragma unroll
        for (int b = 0; b < 2; b++)
            #pragma unroll
            for (int m = 0; m < 2; m++)
                afr[b][m] = *reinterpret_cast<const short8*>(
                    sm + b * TILE + (m * 16 + l15) * MSTR + s * 32 + kg);
        __builtin_amdgcn_s_setprio(1);
        #pragma unroll
        for (int n = 0; n < 4; n++) {
            short8 bfr = pkc1[(s * 4 + n) * 64 + lane];
            #pragma unroll
            for (int b = 0; b < 2; b++)
                #pragma unroll
                for (int m = 0; m < 2; m++)
                    acc3[b][m][n] = __builtin_amdgcn_mfma_f32_16x16x32_bf16(afr[b][m], bfr, acc3[b][m][n], 0, 0, 0);
        }
        __builtin_amdgcn_s_setprio(0);
    }
    float wc2v[4];
    #pragma unroll
    for (int n = 0; n < 4; n++) wc2v[n] = w_c2[n * 16 + l15];
    #pragma unroll
    for (int b = 0; b < 2; b++)
        #pragma unroll
        for (int m = 0; m < 2; m++)
            #pragma unroll
            for (int r = 0; r < 4; r++) {
                float v = 0.0f;
                #pragma unroll
                for (int n = 0; n < 4; n++) v = fmaf(silu_f(acc3[b][m][n][r]), wc2v[n], v);
                v += __shfl_xor(v, 1); v += __shfl_xor(v, 2);
                v += __shfl_xor(v, 4); v += __shfl_xor(v, 8);
                if (l15 == 0) smf[b * (TILE / 2) + (m * 16 + gq * 4 + r) * 36 + 32] = v;
            }
    asm volatile("s_waitcnt lgkmcnt(0)" ::: "memory");

    // ---- weighted coordinates into spare slots (lanes 0..31) ----
    if (lane < 32) {
        const float smv = sm_p[0], omv = om_p[0];
        float phi0 = smf[lane * 36 + 32];
        float phi1 = smf[(TILE / 2) + lane * 36 + 32];
        float4 wv0, wv1;
        wv0.x = (smv * xr0.x + omv * xc0.x) * phi0;
        wv0.y = (smv * xr0.y + omv * xc0.y) * phi0;
        wv0.z = (smv * xr0.z + omv * xc0.z) * phi0;
        wv0.w = (smv * xr0.w + omv * xc0.w) * phi0;
        wv1.x = (smv * xr1.x + omv * xc1.x) * phi1;
        wv1.y = (smv * xr1.y + omv * xc1.y) * phi1;
        wv1.z = (smv * xr1.z + omv * xc1.z) * phi1;
        wv1.w = (smv * xr1.w + omv * xc1.w) * phi1;
        *reinterpret_cast<float4*>(smf + lane * 36 + 32) = wv0;
        *reinterpret_cast<float4*>(smf + (TILE / 2) + lane * 36 + 32) = wv1;
    }
    asm volatile("s_waitcnt lgkmcnt(0)" ::: "memory");

    // ---- shared ballot run-merged scatter over 32 edges, both batches ----
    int nrow = __shfl_down(row, 1);
    unsigned long long bmask = __ballot((lane == 31) || (lane < 31 && row != nrow));
    float* aggb0 = agg;
    float* aggb1 = agg + (size_t)NN * 64;
    float* xb    = xagg + (size_t)((lane >> 2) & 1) * NN * 4;   // lanes 0-3 -> b0, 4-7 -> b1
    const int xsel = ((lane >> 2) & 1) * (TILE / 2) + (lane & 3);
    float mv0 = 0.0f, mv1 = 0.0f, xv = 0.0f;
    #pragma unroll
    for (int e = 0; e < 32; e++) {
        mv0 += bf2f(sm[e * MSTR + lane]);
        mv1 += bf2f(sm[TILE + e * MSTR + lane]);
        float t = smf[e * 36 + 32 + xsel];
        xv += (lane < 8) ? t : 0.0f;
        if ((bmask >> e) & 1ull) {
            int re = __shfl(row, e);
            atomicAdd(aggb0 + (size_t)re * 64 + lane, mv0);
            atomicAdd(aggb1 + (size_t)re * 64 + lane, mv1);
            if (lane < 8) atomicAdd(xb + (size_t)re * 4 + (lane & 3), xv);
            mv0 = 0.0f; mv1 = 0.0f; xv = 0.0f;
        }
    }
}

// ---------------------------------------------------------------------------
__global__ __launch_bounds__(256, 4) void node_kernel(
    const short* __restrict__ hb16, const float* __restrict__ x,
    const float* __restrict__ b_f1, const float* __restrict__ b_f2,
    const short* __restrict__ pk,
    const int* __restrict__ off,
    float* out_h, float* out_x)
{
    __shared__ short smem[4][64 * MSTR];
    const int wid  = threadIdx.x >> 6;
    const int lane = threadIdx.x & 63;
    short* sm = smem[wid];

    const int WN = (NN + 63) / 64;
    const int gw = blockIdx.x * 4 + wid;
    if (gw >= NB * WN) return;
    const int b  = gw / WN;
    const int n0 = (gw - b * WN) * 64;

    const int l15 = lane & 15;
    const int gq  = lane >> 4;
    const int kg  = gq * 8;

    const short* hbb  = hb16 + (size_t)b * NN * 64;
    const float* aggb = out_h + (size_t)b * NN * 64;

    f32x4 acc[4][4];
    #pragma unroll
    for (int n = 0; n < 4; n++) {
        float bias = b_f1[n * 16 + l15];
        #pragma unroll
        for (int m = 0; m < 4; m++) acc[m][n] = f32x4{bias, bias, bias, bias};
    }
    const short8* pkf1 = reinterpret_cast<const short8*>(pk + P_F1);
    #pragma unroll
    for (int s = 0; s < 4; s++) {
        short8 afr[4];
        #pragma unroll
        for (int m = 0; m < 4; m++) {
            int nd = n0 + m * 16 + l15;
            if (nd >= NN) nd = NN - 1;
            if (s < 2) {
                afr[m] = *reinterpret_cast<const short8*>(
                    hbb + (size_t)nd * 64 + s * 32 + kg);
            } else {
                const float* base = aggb + (size_t)nd * 64 + (s & 1) * 32 + kg;
                float4 lo = *reinterpret_cast<const float4*>(base);
                float4 hi = *reinterpret_cast<const float4*>(base + 4);
                afr[m] = pack8(lo, hi);
            }
        }
        __builtin_amdgcn_s_setprio(1);
        #pragma unroll
        for (int n = 0; n < 4; n++) {
            short8 bfr = pkf1[(s * 4 + n) * 64 + lane];
            #pragma unroll
            for (int m = 0; m < 4; m++)
                acc[m][n] = __builtin_amdgcn_mfma_f32_16x16x32_bf16(afr[m], bfr, acc[m][n], 0, 0, 0);
        }
        __builtin_amdgcn_s_setprio(0);
    }

    #pragma unroll
    for (int m = 0; m < 4; m++)
        #pragma unroll
        for (int n = 0; n < 4; n++)
            #pragma unroll
            for (int r = 0; r < 4; r++)
                sm[(m * 16 + gq * 4 + r) * MSTR + n * 16 + l15] = f2bf(silu_f(acc[m][n][r]));
    asm volatile("s_waitcnt lgkmcnt(0)" ::: "memory");

    f32x4 acc2[4][4];
    #pragma unroll
    for (int n = 0; n < 4; n++) {
        float bias = b_f2[n * 16 + l15];
        #pragma unroll
        for (int m = 0; m < 4; m++) acc2[m][n] = f32x4{bias, bias, bias, bias};
    }
    const short8* pkf2 = reinterpret_cast<const short8*>(pk + P_F2);
    #pragma unroll
    for (int s = 0; s < 2; s++) {
        short8 afr[4];
        #pragma unroll
        for (int m = 0; m < 4; m++)
            afr[m] = *reinterpret_cast<const short8*>(sm + (m * 16 + l15) * MSTR + s * 32 + kg);
        __builtin_amdgcn_s_setprio(1);
        #pragma unroll
        for (int n = 0; n < 4; n++) {
            short8 bfr = pkf2[(s * 4 + n) * 64 + lane];
            #pragma unroll
            for (int m = 0; m < 4; m++)
                acc2[m][n] = __builtin_amdgcn_mfma_f32_16x16x32_bf16(afr[m], bfr, acc2[m][n], 0, 0, 0);
        }
        __builtin_amdgcn_s_setprio(0);
    }

    float* ohb = out_h + (size_t)b * NN * 64;
    #pragma unroll
    for (int m = 0; m < 4; m++)
        #pragma unroll
        for (int r = 0; r < 4; r++) {
            int nd = n0 + m * 16 + gq * 4 + r;
            if (nd < NN) {
                #pragma unroll
                for (int n = 0; n < 4; n++)
                    ohb[(size_t)nd * 64 + n * 16 + l15] = ssgn_f(acc2[m][n][r]);
            }
        }

    const int node = n0 + lane;
    if (node < NN) {
        int c_i = off[node + 1] - off[node];
        float c = (float)(c_i < 1 ? 1 : c_i);
        float invc = fast_rcp(c);
        const float4 xv = *reinterpret_cast<const float4*>(x + ((size_t)b * NN + node) * 4);
        float* xop = out_x + ((size_t)b * NN + node) * 4;
        float4 xa = *reinterpret_cast<float4*>(xop);
        float4 r;
        r.x = xv.x + xa.x * invc;
        r.y = xv.y + xa.y * invc;
        r.z = xv.z + xa.z * invc;
        r.w = xv.w + xa.w * invc;
        *reinterpret_cast<float4*>(xop) = r;
    }
}

// ---------------------------------------------------------------------------
extern "C" void kernel_launch(void* const* d_in, const int* in_sizes, int n_in,
                              void* d_out, int out_size, void* d_ws, size_t ws_size,
                              hipStream_t stream) {
    const float* h    = (const float*)d_in[0];
    const float* x    = (const float*)d_in[1];
    const int*   ei   = (const int*)d_in[2];
    const float* ea   = (const float*)d_in[3];
    const float* w_e1 = (const float*)d_in[4];
    const float* b_e1 = (const float*)d_in[5];
    const float* w_e2 = (const float*)d_in[6];
    const float* b_e2 = (const float*)d_in[7];
    const float* w_f1 = (const float*)d_in[8];
    const float* b_f1 = (const float*)d_in[9];
    const float* w_f2 = (const float*)d_in[10];
    const float* b_f2 = (const float*)d_in[11];
    const float* w_c1 = (const float*)d_in[12];
    const float* b_c1 = (const float*)d_in[13];
    const float* w_c2 = (const float*)d_in[14];
    const float* smp  = (const float*)d_in[15];
    const float* omp  = (const float*)d_in[16];

    float* out   = (float*)d_out;
    float* agg   = out;
    float* out_x = out + (size_t)NB * NN * 64;

    char* ws = (char*)d_ws;
    int*   cnt_i = (int*)(ws + WS_CNT);
    int*   off   = (int*)(ws + WS_OFF);
    int*   cur   = (int*)(ws + WS_CUR);
    int*   eids  = (int*)(ws + WS_EIDS);
    short* pk    = (short*)(ws + WS_PK);
    short* hb16  = (short*)(ws + WS_HB);

    hipMemsetAsync(d_out, 0, (size_t)out_size * sizeof(float), stream);
    hipMemsetAsync(cnt_i, 0, (size_t)NN * sizeof(int), stream);

    pack_weights<<<15, 256, 0, stream>>>(w_e1, w_e2, w_c1, w_f1, w_f2, pk);
    conv_h<<<3125, 256, 0, stream>>>(h, hb16);

    const int eb = (EE + 255) / 256;
    hist_kernel<<<eb, 256, 0, stream>>>(ei, cnt_i);
    scan_kernel<<<1, 1024, 0, stream>>>(cnt_i, off, cur);
    scatter_kernel<<<eb, 256, 0, stream>>>(ei, cur, eids);

    const int edge_waves = EE / 32;                   // 31250 (batch-paired)
    const int edge_blocks = (edge_waves + 3) / 4;     // 7813
    edge_kernel<<<edge_blocks, 256, 0, stream>>>(
        hb16, x, ei, ea, eids, b_e1, b_e2, b_c1, w_c2, pk,
        smp, omp, agg, out_x);

    const int node_waves = NB * ((NN + 63) / 64);
    const int node_blocks = (node_waves + 3) / 4;
    node_kernel<<<node_blocks, 256, 0, stream>>>(
        hb16, x, b_f1, b_f2, pk, off, agg, out_x);
}

// Round 11
// 527.293 us; speedup vs baseline: 1.2371x; 1.0100x over previous
//
#include <hip/hip_runtime.h>
#include <hip/hip_bf16.h>
#include <cstdint>
#include <cstddef>

#define NN 50000     // nodes
#define EE 1000000   // edges
#define NB 2         // batch

#define MSTR 72      // tile stride (shorts): 144 B rows; cols 0..63 = m, 64..71 spare (phi/swv)
#define TILE (32 * MSTR)   // one batch m-tile, shorts (2304)

// packed-weight layout (shorts): B-fragment order [kstep][ntile][lane][8]
// edge weights (e1,e2,c1) are the first 18432 shorts = 36 frags, contiguous.
#define P_E1 0
#define P_E2 10240
#define P_C1 14336
#define P_F1 18432
#define P_F2 26624
#define EDGE_PK_SHORTS 18432     // 36,864 B staged to LDS per block

// d_ws byte offsets
#define WS_CNT   0            // int[NN]
#define WS_OFF   200704       // int[NN+1]
#define WS_CUR   401408       // int[NN]
#define WS_ECS   602112       // int4[EE]  (16 MB)
#define WS_PK    16602112     // short[30720]
#define WS_HB    16663552     // short[NB*NN*64]  (12.8 MB)

typedef __attribute__((ext_vector_type(8))) short short8;
typedef __attribute__((ext_vector_type(4))) float f32x4;

__device__ __forceinline__ float fast_rcp(float v) { return __builtin_amdgcn_rcpf(v); }
__device__ __forceinline__ float silu_f(float v) { return v * fast_rcp(1.0f + __expf(-v)); }
__device__ __forceinline__ float ssgn_f(float v) { return v * fast_rcp(1.0f + fabsf(v)); }

__device__ __forceinline__ short f2bf(float f) {
    __hip_bfloat16 h = __float2bfloat16(f);
    return *reinterpret_cast<short*>(&h);
}
__device__ __forceinline__ float bf2f(short s) {
    union { unsigned u; float f; } c; c.u = ((unsigned)(unsigned short)s) << 16; return c.f;
}
__device__ __forceinline__ short8 pack8(float4 a, float4 b) {
    short8 r;
    r[0] = f2bf(a.x); r[1] = f2bf(a.y); r[2] = f2bf(a.z); r[3] = f2bf(a.w);
    r[4] = f2bf(b.x); r[5] = f2bf(b.y); r[6] = f2bf(b.z); r[7] = f2bf(b.w);
    return r;
}

// ---------------------------------------------------------------------------
// Fused prep: conv_h (blocks 0..3124) | pack_weights (3125..3139) | hist (3140..)
// ---------------------------------------------------------------------------
#define PREP_CONV 3125
#define PREP_PACK 15
#define PREP_HIST 3907

__global__ void prep_kernel(const float* __restrict__ h, short* __restrict__ hb16,
                            const float* __restrict__ w_e1, const float* __restrict__ w_e2,
                            const float* __restrict__ w_c1, const float* __restrict__ w_f1,
                            const float* __restrict__ w_f2, short* __restrict__ pk,
                            const int* __restrict__ ei, int* __restrict__ cnt_i)
{
    const int bid = blockIdx.x;
    if (bid < PREP_CONV) {
        size_t i = ((size_t)bid * 256 + threadIdx.x) * 8;
        float4 lo = *reinterpret_cast<const float4*>(h + i);
        float4 hi = *reinterpret_cast<const float4*>(h + i + 4);
        *reinterpret_cast<short8*>(hb16 + i) = pack8(lo, hi);
    } else if (bid < PREP_CONV + PREP_PACK) {
        int g = (bid - PREP_CONV) * 256 + threadIdx.x;
        const int G_E1 = 5 * 4 * 64, G_E2 = 2 * 4 * 64, G_C1 = 2 * 4 * 64;
        const int G_F1 = 4 * 4 * 64, G_F2 = 2 * 4 * 64;
        if (g >= G_E1 + G_E2 + G_C1 + G_F1 + G_F2) return;
        const float* W; int loc; int mat;
        if (g < G_E1)                        { W = w_e1; loc = g;                         mat = 0; }
        else if (g < G_E1+G_E2)              { W = w_e2; loc = g - G_E1;                  mat = 1; }
        else if (g < G_E1+G_E2+G_C1)         { W = w_c1; loc = g - G_E1 - G_E2;           mat = 2; }
        else if (g < G_E1+G_E2+G_C1+G_F1)    { W = w_f1; loc = g - G_E1 - G_E2 - G_C1;    mat = 3; }
        else                                 { W = w_f2; loc = g - G_E1-G_E2-G_C1-G_F1;   mat = 4; }
        int l = loc & 63, n = (loc >> 6) & 3, s = loc >> 8;
        short8 out;
        #pragma unroll
        for (int j = 0; j < 8; j++) {
            int kp = s * 32 + ((l >> 4) * 8) + j;
            int ko; bool valid;
            if (mat == 0) {
                if (kp < 128)      { ko = kp;     valid = true; }
                else if (kp < 144) { ko = kp + 1; valid = true; }   // ea rows (orig 129..144)
                else if (kp == 144){ ko = 128;    valid = true; }   // radial row
                else               { ko = 0;      valid = false; }
            } else if (mat == 3) { ko = kp; valid = kp < 128; }
            else                 { ko = kp; valid = kp < 64; }
            float v = valid ? W[ko * 64 + (n * 16 + (l & 15))] : 0.0f;
            out[j] = f2bf(v);
        }
        *reinterpret_cast<short8*>(pk + (size_t)g * 8) = out;
    } else {
        int e = (bid - PREP_CONV - PREP_PACK) * 256 + threadIdx.x;
        if (e < EE) atomicAdd(&cnt_i[ei[e]], 1);
    }
}

// ---------------------------------------------------------------------------
__global__ void scan_kernel(const int* __restrict__ cnt_i,
                            int* __restrict__ off, int* __restrict__ cur) {
    __shared__ int part[1024];
    const int t = threadIdx.x;
    const int CH = (NN + 1023) / 1024;
    int base = t * CH;
    int s = 0;
    for (int j = 0; j < CH; j++) { int idx = base + j; if (idx < NN) s += cnt_i[idx]; }
    part[t] = s;
    __syncthreads();
    for (int d = 1; d < 1024; d <<= 1) {
        int v = (t >= d) ? part[t - d] : 0;
        __syncthreads();
        part[t] += v;
        __syncthreads();
    }
    int excl = (t == 0) ? 0 : part[t - 1];
    for (int j = 0; j < CH; j++) {
        int idx = base + j;
        if (idx < NN) { off[idx] = excl; cur[idx] = excl; excl += cnt_i[idx]; }
    }
    if (t == 1023) off[NN] = part[1023];
}

// scatter: emits {eid,row,col} per sorted position (16B random write, same
// line count as the old 4B write; removes 64 random ei gathers/wave in edge)
__global__ void scatter_kernel(const int* __restrict__ ei,
                               int* __restrict__ cur, int4* __restrict__ ecs) {
    int e = blockIdx.x * 256 + threadIdx.x;
    if (e < EE) {
        int r = ei[e], c = ei[EE + e];
        int p = atomicAdd(&cur[r], 1);
        ecs[p] = make_int4(e, r, c, 0);
    }
}

// ---------------------------------------------------------------------------
// Edge kernel: 32 sorted edges x both batches per wave; edge weights staged
// to block-shared LDS (B-frag reads -> LDS pipe, off the texture pipe).
// ---------------------------------------------------------------------------
__global__ __launch_bounds__(256, 2) void edge_kernel(
    const short* __restrict__ hb16, const float* __restrict__ x,
    const float* __restrict__ ea, const int4* __restrict__ ecs,
    const float* __restrict__ b_e1, const float* __restrict__ b_e2,
    const float* __restrict__ b_c1, const float* __restrict__ w_c2,
    const short* __restrict__ pk,
    const float* __restrict__ sm_p, const float* __restrict__ om_p,
    float* __restrict__ agg, float* __restrict__ xagg)
{
    __shared__ short wlds[EDGE_PK_SHORTS];   // 36,864 B: e1/e2/c1 B-frags
    __shared__ short smem[4][2 * TILE];      // 9216 B / wave
    const int wid  = threadIdx.x >> 6;
    const int lane = threadIdx.x & 63;
    short* sm  = smem[wid];
    float* smf = reinterpret_cast<float*>(sm);

    // ---- stage edge weights to LDS (whole block, before any exit) ----
    {
        short8* dst = reinterpret_cast<short8*>(wlds);
        const short8* src = reinterpret_cast<const short8*>(pk);
        #pragma unroll
        for (int i = 0; i < EDGE_PK_SHORTS / 8 / 256; i++)   // 9 iters
            dst[i * 256 + threadIdx.x] = src[i * 256 + threadIdx.x];
    }
    __syncthreads();

    // bijective XCD swizzle (m204)
    const int nwg = gridDim.x;
    const int q = nwg >> 3, r_ = nwg & 7;
    const int xcd = blockIdx.x & 7, kk = blockIdx.x >> 3;
    const int bswz = (xcd < r_ ? xcd * (q + 1) : r_ * (q + 1) + (xcd - r_) * q) + kk;

    const int WPB = EE / 32;               // 31250 edge windows
    const int gw = bswz * 4 + wid;
    if (gw >= WPB) return;                 // after the only barrier: safe
    const int i0 = gw * 32;

    const int l15 = lane & 15;
    const int gq  = lane >> 4;
    const int kg  = gq * 8;

    // per-edge scalars on lanes 0..31 (shared across batches)
    int eid = 0, row = 0, col = 0;
    float4 xr0 = float4{0,0,0,0}, xc0 = float4{0,0,0,0};
    float4 xr1 = float4{0,0,0,0}, xc1 = float4{0,0,0,0};
    float rad0 = 0.0f, rad1 = 0.0f;
    if (lane < 32) {
        int4 ec = ecs[i0 + lane];          // coalesced 16B
        eid = ec.x; row = ec.y; col = ec.z;
        xr0 = *reinterpret_cast<const float4*>(x + (size_t)row * 4);
        xc0 = *reinterpret_cast<const float4*>(x + (size_t)col * 4);
        xr1 = *reinterpret_cast<const float4*>(x + ((size_t)NN + row) * 4);
        xc1 = *reinterpret_cast<const float4*>(x + ((size_t)NN + col) * 4);
        {
            float d0 = xr0.x - xc0.x, d1 = xr0.y - xc0.y, d2 = xr0.z - xc0.z, d3 = xr0.w - xc0.w;
            rad0 = d1 * d1 + d2 * d2 + d3 * d3 - d0 * d0;
            d0 = xr1.x - xc1.x; d1 = xr1.y - xc1.y; d2 = xr1.z - xc1.z; d3 = xr1.w - xc1.w;
            rad1 = d1 * d1 + d2 * d2 + d3 * d3 - d0 * d0;
        }
    }

    int rowm[2], colm[2], eidm[2];
    float radm[2][2];
    #pragma unroll
    for (int m = 0; m < 2; m++) {
        int src = m * 16 + l15;            // < 32
        rowm[m] = __shfl(row, src);
        colm[m] = __shfl(col, src);
        eidm[m] = __shfl(eid, src);
        radm[0][m] = __shfl(rad0, src);
        radm[1][m] = __shfl(rad1, src);
    }
    const short* hbb[2] = { hb16, hb16 + (size_t)NN * 64 };
    const short8* pke1 = reinterpret_cast<const short8*>(wlds + P_E1);
    const short8* pke2 = reinterpret_cast<const short8*>(wlds + P_E2);
    const short8* pkc1 = reinterpret_cast<const short8*>(wlds + P_C1);

    // ---- tail fragments (ea random 64B-row + radial), both batches ----
    short8 tail[2][2];
    #pragma unroll
    for (int b = 0; b < 2; b++)
        #pragma unroll
        for (int m = 0; m < 2; m++) {
            short8 v = short8{0, 0, 0, 0, 0, 0, 0, 0};
            if (gq < 2) {
                const float* src = ea + ((size_t)b * EE + eidm[m]) * 16 + gq * 8;
                float4 lo = *reinterpret_cast<const float4*>(src);
                float4 hi = *reinterpret_cast<const float4*>(src + 4);
                v = pack8(lo, hi);
            } else if (gq == 2) {
                v[0] = f2bf(radm[b][m]);
            }
            tail[b][m] = v;
        }

    // ---- GEMM1: acc[b][m][n] ----
    f32x4 acc[2][2][4];
    #pragma unroll
    for (int n = 0; n < 4; n++) {
        float bias = b_e1[n * 16 + l15];
        #pragma unroll
        for (int b = 0; b < 2; b++)
            #pragma unroll
            for (int m = 0; m < 2; m++) acc[b][m][n] = f32x4{bias, bias, bias, bias};
    }
    // tail first
    __builtin_amdgcn_s_setprio(1);
    #pragma unroll
    for (int n = 0; n < 4; n++) {
        short8 bfr = pke1[(4 * 4 + n) * 64 + lane];
        #pragma unroll
        for (int b = 0; b < 2; b++)
            #pragma unroll
            for (int m = 0; m < 2; m++)
                acc[b][m][n] = __builtin_amdgcn_mfma_f32_16x16x32_bf16(tail[b][m], bfr, acc[b][m][n], 0, 0, 0);
    }
    __builtin_amdgcn_s_setprio(0);
    // h rows (run-repeated, cache-friendly)
    #pragma unroll
    for (int s = 0; s < 2; s++) {
        short8 afr[2][2];
        #pragma unroll
        for (int b = 0; b < 2; b++)
            #pragma unroll
            for (int m = 0; m < 2; m++)
                afr[b][m] = *reinterpret_cast<const short8*>(
                    hbb[b] + (size_t)rowm[m] * 64 + s * 32 + kg);
        __builtin_amdgcn_s_setprio(1);
        #pragma unroll
        for (int n = 0; n < 4; n++) {
            short8 bfr = pke1[(s * 4 + n) * 64 + lane];
            #pragma unroll
            for (int b = 0; b < 2; b++)
                #pragma unroll
                for (int m = 0; m < 2; m++)
                    acc[b][m][n] = __builtin_amdgcn_mfma_f32_16x16x32_bf16(afr[b][m], bfr, acc[b][m][n], 0, 0, 0);
        }
        __builtin_amdgcn_s_setprio(0);
    }
    // h cols (random gathers)
    #pragma unroll
    for (int s2 = 0; s2 < 2; s2++) {
        short8 afr[2][2];
        #pragma unroll
        for (int b = 0; b < 2; b++)
            #pragma unroll
            for (int m = 0; m < 2; m++)
                afr[b][m] = *reinterpret_cast<const short8*>(
                    hbb[b] + (size_t)colm[m] * 64 + s2 * 32 + kg);
        __builtin_amdgcn_s_setprio(1);
        #pragma unroll
        for (int n = 0; n < 4; n++) {
            short8 bfr = pke1[((2 + s2) * 4 + n) * 64 + lane];
            #pragma unroll
            for (int b = 0; b < 2; b++)
                #pragma unroll
                for (int m = 0; m < 2; m++)
                    acc[b][m][n] = __builtin_amdgcn_mfma_f32_16x16x32_bf16(afr[b][m], bfr, acc[b][m][n], 0, 0, 0);
        }
        __builtin_amdgcn_s_setprio(0);
    }

    // ---- t1 = silu(acc) -> LDS (both batch tiles) ----
    #pragma unroll
    for (int b = 0; b < 2; b++)
        #pragma unroll
        for (int m = 0; m < 2; m++)
            #pragma unroll
            for (int n = 0; n < 4; n++)
                #pragma unroll
                for (int r = 0; r < 4; r++)
                    sm[b * TILE + (m * 16 + gq * 4 + r) * MSTR + n * 16 + l15] =
                        f2bf(silu_f(acc[b][m][n][r]));
    asm volatile("s_waitcnt lgkmcnt(0)" ::: "memory");

    // ---- GEMM2 ----
    f32x4 acc2[2][2][4];
    #pragma unroll
    for (int n = 0; n < 4; n++) {
        float bias = b_e2[n * 16 + l15];
        #pragma unroll
        for (int b = 0; b < 2; b++)
            #pragma unroll
            for (int m = 0; m < 2; m++) acc2[b][m][n] = f32x4{bias, bias, bias, bias};
    }
    #pragma unroll
    for (int s = 0; s < 2; s++) {
        short8 afr[2][2];
        #pragma unroll
        for (int b = 0; b < 2; b++)
            #pragma unroll
            for (int m = 0; m < 2; m++)
                afr[b][m] = *reinterpret_cast<const short8*>(
                    sm + b * TILE + (m * 16 + l15) * MSTR + s * 32 + kg);
        __builtin_amdgcn_s_setprio(1);
        #pragma unroll
        for (int n = 0; n < 4; n++) {
            short8 bfr = pke2[(s * 4 + n) * 64 + lane];
            #pragma unroll
            for (int b = 0; b < 2; b++)
                #pragma unroll
                for (int m = 0; m < 2; m++)
                    acc2[b][m][n] = __builtin_amdgcn_mfma_f32_16x16x32_bf16(afr[b][m], bfr, acc2[b][m][n], 0, 0, 0);
        }
        __builtin_amdgcn_s_setprio(0);
    }
    asm volatile("s_waitcnt lgkmcnt(0)" ::: "memory");

    // ---- m = softsign(acc2) -> LDS ----
    #pragma unroll
    for (int b = 0; b < 2; b++)
        #pragma unroll
        for (int m = 0; m < 2; m++)
            #pragma unroll
            for (int n = 0; n < 4; n++)
                #pragma unroll
                for (int r = 0; r < 4; r++)
                    sm[b * TILE + (m * 16 + gq * 4 + r) * MSTR + n * 16 + l15] =
                        f2bf(ssgn_f(acc2[b][m][n][r]));
    asm volatile("s_waitcnt lgkmcnt(0)" ::: "memory");

    // ---- GEMM3 + phi ----
    f32x4 acc3[2][2][4];
    #pragma unroll
    for (int n = 0; n < 4; n++) {
        float bias = b_c1[n * 16 + l15];
        #pragma unroll
        for (int b = 0; b < 2; b++)
            #pragma unroll
            for (int m = 0; m < 2; m++) acc3[b][m][n] = f32x4{bias, bias, bias, bias};
    }
    #pragma unroll
    for (int s = 0; s < 2; s++) {
        short8 afr[2][2];
        #pragma unroll
        for (int b = 0; b < 2; b++)
            #pragma unroll
            for (int m = 0; m < 2; m++)
                afr[b][m] = *reinterpret_cast<const short8*>(
                    sm + b * TILE + (m * 16 + l15) * MSTR + s * 32 + kg);
        __builtin_amdgcn_s_setprio(1);
        #pragma unroll
        for (int n = 0; n < 4; n++) {
            short8 bfr = pkc1[(s * 4 + n) * 64 + lane];
            #pragma unroll
            for (int b = 0; b < 2; b++)
                #pragma unroll
                for (int m = 0; m < 2; m++)
                    acc3[b][m][n] = __builtin_amdgcn_mfma_f32_16x16x32_bf16(afr[b][m], bfr, acc3[b][m][n], 0, 0, 0);
        }
        __builtin_amdgcn_s_setprio(0);
    }
    float wc2v[4];
    #pragma unroll
    for (int n = 0; n < 4; n++) wc2v[n] = w_c2[n * 16 + l15];
    #pragma unroll
    for (int b = 0; b < 2; b++)
        #pragma unroll
        for (int m = 0; m < 2; m++)
            #pragma unroll
            for (int r = 0; r < 4; r++) {
                float v = 0.0f;
                #pragma unroll
                for (int n = 0; n < 4; n++) v = fmaf(silu_f(acc3[b][m][n][r]), wc2v[n], v);
                v += __shfl_xor(v, 1); v += __shfl_xor(v, 2);
                v += __shfl_xor(v, 4); v += __shfl_xor(v, 8);
                if (l15 == 0) smf[b * (TILE / 2) + (m * 16 + gq * 4 + r) * 36 + 32] = v;
            }
    asm volatile("s_waitcnt lgkmcnt(0)" ::: "memory");

    // ---- weighted coordinates into spare slots (lanes 0..31) ----
    if (lane < 32) {
        const float smv = sm_p[0], omv = om_p[0];
        float phi0 = smf[lane * 36 + 32];
        float phi1 = smf[(TILE / 2) + lane * 36 + 32];
        float4 wv0, wv1;
        wv0.x = (smv * xr0.x + omv * xc0.x) * phi0;
        wv0.y = (smv * xr0.y + omv * xc0.y) * phi0;
        wv0.z = (smv * xr0.z + omv * xc0.z) * phi0;
        wv0.w = (smv * xr0.w + omv * xc0.w) * phi0;
        wv1.x = (smv * xr1.x + omv * xc1.x) * phi1;
        wv1.y = (smv * xr1.y + omv * xc1.y) * phi1;
        wv1.z = (smv * xr1.z + omv * xc1.z) * phi1;
        wv1.w = (smv * xr1.w + omv * xc1.w) * phi1;
        *reinterpret_cast<float4*>(smf + lane * 36 + 32) = wv0;
        *reinterpret_cast<float4*>(smf + (TILE / 2) + lane * 36 + 32) = wv1;
    }
    asm volatile("s_waitcnt lgkmcnt(0)" ::: "memory");

    // ---- shared ballot run-merged scatter over 32 edges, both batches ----
    int nrow = __shfl_down(row, 1);
    unsigned long long bmask = __ballot((lane == 31) || (lane < 31 && row != nrow));
    float* aggb0 = agg;
    float* aggb1 = agg + (size_t)NN * 64;
    float* xb    = xagg + (size_t)((lane >> 2) & 1) * NN * 4;   // lanes 0-3 b0, 4-7 b1
    const int xsel = ((lane >> 2) & 1) * (TILE / 2) + (lane & 3);
    float mv0 = 0.0f, mv1 = 0.0f, xv = 0.0f;
    #pragma unroll
    for (int e = 0; e < 32; e++) {
        mv0 += bf2f(sm[e * MSTR + lane]);
        mv1 += bf2f(sm[TILE + e * MSTR + lane]);
        float t = smf[e * 36 + 32 + xsel];
        xv += (lane < 8) ? t : 0.0f;
        if ((bmask >> e) & 1ull) {
            int re = __shfl(row, e);
            atomicAdd(aggb0 + (size_t)re * 64 + lane, mv0);
            atomicAdd(aggb1 + (size_t)re * 64 + lane, mv1);
            if (lane < 8) atomicAdd(xb + (size_t)re * 4 + (lane & 3), xv);
            mv0 = 0.0f; mv1 = 0.0f; xv = 0.0f;
        }
    }
}

// ---------------------------------------------------------------------------
__global__ __launch_bounds__(256, 4) void node_kernel(
    const short* __restrict__ hb16, const float* __restrict__ x,
    const float* __restrict__ b_f1, const float* __restrict__ b_f2,
    const short* __restrict__ pk,
    const int* __restrict__ off,
    float* out_h, float* out_x)
{
    __shared__ short smem[4][64 * MSTR];
    const int wid  = threadIdx.x >> 6;
    const int lane = threadIdx.x & 63;
    short* sm = smem[wid];

    const int WN = (NN + 63) / 64;
    const int gw = blockIdx.x * 4 + wid;
    if (gw >= NB * WN) return;
    const int b  = gw / WN;
    const int n0 = (gw - b * WN) * 64;

    const int l15 = lane & 15;
    const int gq  = lane >> 4;
    const int kg  = gq * 8;

    const short* hbb  = hb16 + (size_t)b * NN * 64;
    const float* aggb = out_h + (size_t)b * NN * 64;

    f32x4 acc[4][4];
    #pragma unroll
    for (int n = 0; n < 4; n++) {
        float bias = b_f1[n * 16 + l15];
        #pragma unroll
        for (int m = 0; m < 4; m++) acc[m][n] = f32x4{bias, bias, bias, bias};
    }
    const short8* pkf1 = reinterpret_cast<const short8*>(pk + P_F1);
    #pragma unroll
    for (int s = 0; s < 4; s++) {
        short8 afr[4];
        #pragma unroll
        for (int m = 0; m < 4; m++) {
            int nd = n0 + m * 16 + l15;
            if (nd >= NN) nd = NN - 1;
            if (s < 2) {
                afr[m] = *reinterpret_cast<const short8*>(
                    hbb + (size_t)nd * 64 + s * 32 + kg);
            } else {
                const float* base = aggb + (size_t)nd * 64 + (s & 1) * 32 + kg;
                float4 lo = *reinterpret_cast<const float4*>(base);
                float4 hi = *reinterpret_cast<const float4*>(base + 4);
                afr[m] = pack8(lo, hi);
            }
        }
        __builtin_amdgcn_s_setprio(1);
        #pragma unroll
        for (int n = 0; n < 4; n++) {
            short8 bfr = pkf1[(s * 4 + n) * 64 + lane];
            #pragma unroll
            for (int m = 0; m < 4; m++)
                acc[m][n] = __builtin_amdgcn_mfma_f32_16x16x32_bf16(afr[m], bfr, acc[m][n], 0, 0, 0);
        }
        __builtin_amdgcn_s_setprio(0);
    }

    #pragma unroll
    for (int m = 0; m < 4; m++)
        #pragma unroll
        for (int n = 0; n < 4; n++)
            #pragma unroll
            for (int r = 0; r < 4; r++)
                sm[(m * 16 + gq * 4 + r) * MSTR + n * 16 + l15] = f2bf(silu_f(acc[m][n][r]));
    asm volatile("s_waitcnt lgkmcnt(0)" ::: "memory");

    f32x4 acc2[4][4];
    #pragma unroll
    for (int n = 0; n < 4; n++) {
        float bias = b_f2[n * 16 + l15];
        #pragma unroll
        for (int m = 0; m < 4; m++) acc2[m][n] = f32x4{bias, bias, bias, bias};
    }
    const short8* pkf2 = reinterpret_cast<const short8*>(pk + P_F2);
    #pragma unroll
    for (int s = 0; s < 2; s++) {
        short8 afr[4];
        #pragma unroll
        for (int m = 0; m < 4; m++)
            afr[m] = *reinterpret_cast<const short8*>(sm + (m * 16 + l15) * MSTR + s * 32 + kg);
        __builtin_amdgcn_s_setprio(1);
        #pragma unroll
        for (int n = 0; n < 4; n++) {
            short8 bfr = pkf2[(s * 4 + n) * 64 + lane];
            #pragma unroll
            for (int m = 0; m < 4; m++)
                acc2[m][n] = __builtin_amdgcn_mfma_f32_16x16x32_bf16(afr[m], bfr, acc2[m][n], 0, 0, 0);
        }
        __builtin_amdgcn_s_setprio(0);
    }

    float* ohb = out_h + (size_t)b * NN * 64;
    #pragma unroll
    for (int m = 0; m < 4; m++)
        #pragma unroll
        for (int r = 0; r < 4; r++) {
            int nd = n0 + m * 16 + gq * 4 + r;
            if (nd < NN) {
                #pragma unroll
                for (int n = 0; n < 4; n++)
                    ohb[(size_t)nd * 64 + n * 16 + l15] = ssgn_f(acc2[m][n][r]);
            }
        }

    const int node = n0 + lane;
    if (node < NN) {
        int c_i = off[node + 1] - off[node];
        float c = (float)(c_i < 1 ? 1 : c_i);
        float invc = fast_rcp(c);
        const float4 xv = *reinterpret_cast<const float4*>(x + ((size_t)b * NN + node) * 4);
        float* xop = out_x + ((size_t)b * NN + node) * 4;
        float4 xa = *reinterpret_cast<float4*>(xop);
        float4 r;
        r.x = xv.x + xa.x * invc;
        r.y = xv.y + xa.y * invc;
        r.z = xv.z + xa.z * invc;
        r.w = xv.w + xa.w * invc;
        *reinterpret_cast<float4*>(xop) = r;
    }
}

// ---------------------------------------------------------------------------
extern "C" void kernel_launch(void* const* d_in, const int* in_sizes, int n_in,
                              void* d_out, int out_size, void* d_ws, size_t ws_size,
                              hipStream_t stream) {
    const float* h    = (const float*)d_in[0];
    const float* x    = (const float*)d_in[1];
    const int*   ei   = (const int*)d_in[2];
    const float* ea   = (const float*)d_in[3];
    const float* w_e1 = (const float*)d_in[4];
    const float* b_e1 = (const float*)d_in[5];
    const float* w_e2 = (const float*)d_in[6];
    const float* b_e2 = (const float*)d_in[7];
    const float* w_f1 = (const float*)d_in[8];
    const float* b_f1 = (const float*)d_in[9];
    const float* w_f2 = (const float*)d_in[10];
    const float* b_f2 = (const float*)d_in[11];
    const float* w_c1 = (const float*)d_in[12];
    const float* b_c1 = (const float*)d_in[13];
    const float* w_c2 = (const float*)d_in[14];
    const float* smp  = (const float*)d_in[15];
    const float* omp  = (const float*)d_in[16];

    float* out   = (float*)d_out;
    float* agg   = out;
    float* out_x = out + (size_t)NB * NN * 64;

    char* ws = (char*)d_ws;
    int*   cnt_i = (int*)(ws + WS_CNT);
    int*   off   = (int*)(ws + WS_OFF);
    int*   cur   = (int*)(ws + WS_CUR);
    int4*  ecs   = (int4*)(ws + WS_ECS);
    short* pk    = (short*)(ws + WS_PK);
    short* hb16  = (short*)(ws + WS_HB);

    hipMemsetAsync(d_out, 0, (size_t)out_size * sizeof(float), stream);
    hipMemsetAsync(cnt_i, 0, (size_t)NN * sizeof(int), stream);

    prep_kernel<<<PREP_CONV + PREP_PACK + PREP_HIST, 256, 0, stream>>>(
        h, hb16, w_e1, w_e2, w_c1, w_f1, w_f2, pk, ei, cnt_i);
    scan_kernel<<<1, 1024, 0, stream>>>(cnt_i, off, cur);
    scatter_kernel<<<(EE + 255) / 256, 256, 0, stream>>>(ei, cur, ecs);

    const int edge_waves = EE / 32;                   // 31250 (batch-paired)
    const int edge_blocks = (edge_waves + 3) / 4;     // 7813
    edge_kernel<<<edge_blocks, 256, 0, stream>>>(
        hb16, x, ea, ecs, b_e1, b_e2, b_c1, w_c2, pk,
        smp, omp, agg, out_x);

    const int node_waves = NB * ((NN + 63) / 64);
    const int node_blocks = (node_waves + 3) / 4;
    node_kernel<<<node_blocks, 256, 0, stream>>>(
        hb16, x, b_f1, b_f2, pk, off, agg, out_x);
}

// Round 12
// 488.046 us; speedup vs baseline: 1.3366x; 1.0804x over previous
//
#include <hip/hip_runtime.h>
#include <hip/hip_bf16.h>
#include <cstdint>
#include <cstddef>

#define NN 50000     // nodes
#define EE 1000000   // edges
#define NB 2         // batch

#define MSTR 72      // tile stride (shorts): 144 B rows; cols 0..63 = m, 64..71 spare (phi/swv)
#define TILE (32 * MSTR)   // one batch m-tile, shorts (2304)

// packed-weight layout (shorts): B-fragment order [kstep][ntile][lane][8]
#define P_E1 0
#define P_E2 10240
#define P_C1 14336
#define P_F1 18432
#define P_F2 26624
#define E1_MAIN_SHORTS 8192      // e1 s=0..3 (16 frags, 16,384 B) staged to LDS

// d_ws byte offsets
#define WS_CNT   0            // int[NN]
#define WS_OFF   200704       // int[NN+1]
#define WS_CUR   401408       // int[NN]
#define WS_ECS   602112       // int4[EE]  (16 MB)
#define WS_PK    16602112     // short[30720]
#define WS_HB    16663552     // short[NB*NN*64]  (12.8 MB)

typedef __attribute__((ext_vector_type(8))) short short8;
typedef __attribute__((ext_vector_type(4))) float f32x4;

__device__ __forceinline__ float fast_rcp(float v) { return __builtin_amdgcn_rcpf(v); }
__device__ __forceinline__ float silu_f(float v) { return v * fast_rcp(1.0f + __expf(-v)); }
__device__ __forceinline__ float ssgn_f(float v) { return v * fast_rcp(1.0f + fabsf(v)); }

__device__ __forceinline__ short f2bf(float f) {
    __hip_bfloat16 h = __float2bfloat16(f);
    return *reinterpret_cast<short*>(&h);
}
__device__ __forceinline__ float bf2f(short s) {
    union { unsigned u; float f; } c; c.u = ((unsigned)(unsigned short)s) << 16; return c.f;
}
__device__ __forceinline__ short8 pack8(float4 a, float4 b) {
    short8 r;
    r[0] = f2bf(a.x); r[1] = f2bf(a.y); r[2] = f2bf(a.z); r[3] = f2bf(a.w);
    r[4] = f2bf(b.x); r[5] = f2bf(b.y); r[6] = f2bf(b.z); r[7] = f2bf(b.w);
    return r;
}

// ---------------------------------------------------------------------------
// Fused prep: conv_h | pack_weights | hist
// ---------------------------------------------------------------------------
#define PREP_CONV 3125
#define PREP_PACK 15
#define PREP_HIST 3907

__global__ void prep_kernel(const float* __restrict__ h, short* __restrict__ hb16,
                            const float* __restrict__ w_e1, const float* __restrict__ w_e2,
                            const float* __restrict__ w_c1, const float* __restrict__ w_f1,
                            const float* __restrict__ w_f2, short* __restrict__ pk,
                            const int* __restrict__ ei, int* __restrict__ cnt_i)
{
    const int bid = blockIdx.x;
    if (bid < PREP_CONV) {
        size_t i = ((size_t)bid * 256 + threadIdx.x) * 8;
        float4 lo = *reinterpret_cast<const float4*>(h + i);
        float4 hi = *reinterpret_cast<const float4*>(h + i + 4);
        *reinterpret_cast<short8*>(hb16 + i) = pack8(lo, hi);
    } else if (bid < PREP_CONV + PREP_PACK) {
        int g = (bid - PREP_CONV) * 256 + threadIdx.x;
        const int G_E1 = 5 * 4 * 64, G_E2 = 2 * 4 * 64, G_C1 = 2 * 4 * 64;
        const int G_F1 = 4 * 4 * 64, G_F2 = 2 * 4 * 64;
        if (g >= G_E1 + G_E2 + G_C1 + G_F1 + G_F2) return;
        const float* W; int loc; int mat;
        if (g < G_E1)                        { W = w_e1; loc = g;                         mat = 0; }
        else if (g < G_E1+G_E2)              { W = w_e2; loc = g - G_E1;                  mat = 1; }
        else if (g < G_E1+G_E2+G_C1)         { W = w_c1; loc = g - G_E1 - G_E2;           mat = 2; }
        else if (g < G_E1+G_E2+G_C1+G_F1)    { W = w_f1; loc = g - G_E1 - G_E2 - G_C1;    mat = 3; }
        else                                 { W = w_f2; loc = g - G_E1-G_E2-G_C1-G_F1;   mat = 4; }
        int l = loc & 63, n = (loc >> 6) & 3, s = loc >> 8;
        short8 out;
        #pragma unroll
        for (int j = 0; j < 8; j++) {
            int kp = s * 32 + ((l >> 4) * 8) + j;
            int ko; bool valid;
            if (mat == 0) {
                if (kp < 128)      { ko = kp;     valid = true; }
                else if (kp < 144) { ko = kp + 1; valid = true; }   // ea rows (orig 129..144)
                else if (kp == 144){ ko = 128;    valid = true; }   // radial row
                else               { ko = 0;      valid = false; }
            } else if (mat == 3) { ko = kp; valid = kp < 128; }
            else                 { ko = kp; valid = kp < 64; }
            float v = valid ? W[ko * 64 + (n * 16 + (l & 15))] : 0.0f;
            out[j] = f2bf(v);
        }
        *reinterpret_cast<short8*>(pk + (size_t)g * 8) = out;
    } else {
        int e = (bid - PREP_CONV - PREP_PACK) * 256 + threadIdx.x;
        if (e < EE) atomicAdd(&cnt_i[ei[e]], 1);
    }
}

// ---------------------------------------------------------------------------
__global__ void scan_kernel(const int* __restrict__ cnt_i,
                            int* __restrict__ off, int* __restrict__ cur) {
    __shared__ int part[1024];
    const int t = threadIdx.x;
    const int CH = (NN + 1023) / 1024;
    int base = t * CH;
    int s = 0;
    for (int j = 0; j < CH; j++) { int idx = base + j; if (idx < NN) s += cnt_i[idx]; }
    part[t] = s;
    __syncthreads();
    for (int d = 1; d < 1024; d <<= 1) {
        int v = (t >= d) ? part[t - d] : 0;
        __syncthreads();
        part[t] += v;
        __syncthreads();
    }
    int excl = (t == 0) ? 0 : part[t - 1];
    for (int j = 0; j < CH; j++) {
        int idx = base + j;
        if (idx < NN) { off[idx] = excl; cur[idx] = excl; excl += cnt_i[idx]; }
    }
    if (t == 1023) off[NN] = part[1023];
}

__global__ void scatter_kernel(const int* __restrict__ ei,
                               int* __restrict__ cur, int4* __restrict__ ecs) {
    int e = blockIdx.x * 256 + threadIdx.x;
    if (e < EE) {
        int r = ei[e], c = ei[EE + e];
        int p = atomicAdd(&cur[r], 1);
        ecs[p] = make_int4(e, r, c, 0);
    }
}

// ---------------------------------------------------------------------------
// Edge kernel: 32 sorted edges x both batches per wave; e1 main weights
// (16 frags) staged to block LDS; block LDS 53,248 B -> 3 blocks/CU.
// ---------------------------------------------------------------------------
__global__ __launch_bounds__(256, 3) void edge_kernel(
    const short* __restrict__ hb16, const float* __restrict__ x,
    const float* __restrict__ ea, const int4* __restrict__ ecs,
    const float* __restrict__ b_e1, const float* __restrict__ b_e2,
    const float* __restrict__ b_c1, const float* __restrict__ w_c2,
    const short* __restrict__ pk,
    const float* __restrict__ sm_p, const float* __restrict__ om_p,
    float* __restrict__ agg, float* __restrict__ xagg)
{
    __shared__ short wlds[E1_MAIN_SHORTS];   // 16,384 B: e1 s=0..3 B-frags
    __shared__ short smem[4][2 * TILE];      // 36,864 B (4 waves x 2 batch tiles)
    const int wid  = threadIdx.x >> 6;
    const int lane = threadIdx.x & 63;
    short* sm  = smem[wid];
    float* smf = reinterpret_cast<float*>(sm);

    // ---- stage e1 main weights to LDS (whole block, before any exit) ----
    {
        short8* dst = reinterpret_cast<short8*>(wlds);
        const short8* src = reinterpret_cast<const short8*>(pk);
        #pragma unroll
        for (int i = 0; i < E1_MAIN_SHORTS / 8 / 256; i++)   // 4 iters
            dst[i * 256 + threadIdx.x] = src[i * 256 + threadIdx.x];
    }
    __syncthreads();

    // bijective XCD swizzle (m204)
    const int nwg = gridDim.x;
    const int q = nwg >> 3, r_ = nwg & 7;
    const int xcd = blockIdx.x & 7, kk = blockIdx.x >> 3;
    const int bswz = (xcd < r_ ? xcd * (q + 1) : r_ * (q + 1) + (xcd - r_) * q) + kk;

    const int WPB = EE / 32;               // 31250 edge windows
    const int gw = bswz * 4 + wid;
    if (gw >= WPB) return;                 // after the only barrier: safe
    const int i0 = gw * 32;

    const int l15 = lane & 15;
    const int gq  = lane >> 4;
    const int kg  = gq * 8;

    // per-edge scalars on lanes 0..31 (shared across batches)
    int eid = 0, row = 0, col = 0;
    float4 xr0 = float4{0,0,0,0}, xc0 = float4{0,0,0,0};
    float4 xr1 = float4{0,0,0,0}, xc1 = float4{0,0,0,0};
    float rad0 = 0.0f, rad1 = 0.0f;
    if (lane < 32) {
        int4 ec = ecs[i0 + lane];          // coalesced 16B
        eid = ec.x; row = ec.y; col = ec.z;
        xr0 = *reinterpret_cast<const float4*>(x + (size_t)row * 4);
        xc0 = *reinterpret_cast<const float4*>(x + (size_t)col * 4);
        xr1 = *reinterpret_cast<const float4*>(x + ((size_t)NN + row) * 4);
        xc1 = *reinterpret_cast<const float4*>(x + ((size_t)NN + col) * 4);
        {
            float d0 = xr0.x - xc0.x, d1 = xr0.y - xc0.y, d2 = xr0.z - xc0.z, d3 = xr0.w - xc0.w;
            rad0 = d1 * d1 + d2 * d2 + d3 * d3 - d0 * d0;
            d0 = xr1.x - xc1.x; d1 = xr1.y - xc1.y; d2 = xr1.z - xc1.z; d3 = xr1.w - xc1.w;
            rad1 = d1 * d1 + d2 * d2 + d3 * d3 - d0 * d0;
        }
    }

    int rowm[2], colm[2], eidm[2];
    float radm[2][2];
    #pragma unroll
    for (int m = 0; m < 2; m++) {
        int src = m * 16 + l15;            // < 32
        rowm[m] = __shfl(row, src);
        colm[m] = __shfl(col, src);
        eidm[m] = __shfl(eid, src);
        radm[0][m] = __shfl(rad0, src);
        radm[1][m] = __shfl(rad1, src);
    }
    const short* hbb[2] = { hb16, hb16 + (size_t)NN * 64 };
    const short8* pke1L = reinterpret_cast<const short8*>(wlds);       // s=0..3 (LDS)
    const short8* pke1G = reinterpret_cast<const short8*>(pk + P_E1);  // s=4 tail (global)
    const short8* pke2  = reinterpret_cast<const short8*>(pk + P_E2);
    const short8* pkc1  = reinterpret_cast<const short8*>(pk + P_C1);

    // ---- tail fragments (ea random + radial), both batches ----
    short8 tail[2][2];
    #pragma unroll
    for (int b = 0; b < 2; b++)
        #pragma unroll
        for (int m = 0; m < 2; m++) {
            short8 v = short8{0, 0, 0, 0, 0, 0, 0, 0};
            if (gq < 2) {
                const float* src = ea + ((size_t)b * EE + eidm[m]) * 16 + gq * 8;
                float4 lo = *reinterpret_cast<const float4*>(src);
                float4 hi = *reinterpret_cast<const float4*>(src + 4);
                v = pack8(lo, hi);
            } else if (gq == 2) {
                v[0] = f2bf(radm[b][m]);
            }
            tail[b][m] = v;
        }

    // ---- GEMM1: acc[b][m][n] ----
    f32x4 acc[2][2][4];
    #pragma unroll
    for (int n = 0; n < 4; n++) {
        float bias = b_e1[n * 16 + l15];
        #pragma unroll
        for (int b = 0; b < 2; b++)
            #pragma unroll
            for (int m = 0; m < 2; m++) acc[b][m][n] = f32x4{bias, bias, bias, bias};
    }
    // tail first (global B-frags)
    __builtin_amdgcn_s_setprio(1);
    #pragma unroll
    for (int n = 0; n < 4; n++) {
        short8 bfr = pke1G[(4 * 4 + n) * 64 + lane];
        #pragma unroll
        for (int b = 0; b < 2; b++)
            #pragma unroll
            for (int m = 0; m < 2; m++)
                acc[b][m][n] = __builtin_amdgcn_mfma_f32_16x16x32_bf16(tail[b][m], bfr, acc[b][m][n], 0, 0, 0);
    }
    __builtin_amdgcn_s_setprio(0);
    // h rows (run-repeated, cache-friendly; B-frags from LDS)
    #pragma unroll
    for (int s = 0; s < 2; s++) {
        short8 afr[2][2];
        #pragma unroll
        for (int b = 0; b < 2; b++)
            #pragma unroll
            for (int m = 0; m < 2; m++)
                afr[b][m] = *reinterpret_cast<const short8*>(
                    hbb[b] + (size_t)rowm[m] * 64 + s * 32 + kg);
        __builtin_amdgcn_s_setprio(1);
        #pragma unroll
        for (int n = 0; n < 4; n++) {
            short8 bfr = pke1L[(s * 4 + n) * 64 + lane];
            #pragma unroll
            for (int b = 0; b < 2; b++)
                #pragma unroll
                for (int m = 0; m < 2; m++)
                    acc[b][m][n] = __builtin_amdgcn_mfma_f32_16x16x32_bf16(afr[b][m], bfr, acc[b][m][n], 0, 0, 0);
        }
        __builtin_amdgcn_s_setprio(0);
    }
    // h cols (random gathers; B-frags from LDS)
    #pragma unroll
    for (int s2 = 0; s2 < 2; s2++) {
        short8 afr[2][2];
        #pragma unroll
        for (int b = 0; b < 2; b++)
            #pragma unroll
            for (int m = 0; m < 2; m++)
                afr[b][m] = *reinterpret_cast<const short8*>(
                    hbb[b] + (size_t)colm[m] * 64 + s2 * 32 + kg);
        __builtin_amdgcn_s_setprio(1);
        #pragma unroll
        for (int n = 0; n < 4; n++) {
            short8 bfr = pke1L[((2 + s2) * 4 + n) * 64 + lane];
            #pragma unroll
            for (int b = 0; b < 2; b++)
                #pragma unroll
                for (int m = 0; m < 2; m++)
                    acc[b][m][n] = __builtin_amdgcn_mfma_f32_16x16x32_bf16(afr[b][m], bfr, acc[b][m][n], 0, 0, 0);
        }
        __builtin_amdgcn_s_setprio(0);
    }

    // ---- t1 = silu(acc) -> LDS (both batch tiles) ----
    #pragma unroll
    for (int b = 0; b < 2; b++)
        #pragma unroll
        for (int m = 0; m < 2; m++)
            #pragma unroll
            for (int n = 0; n < 4; n++)
                #pragma unroll
                for (int r = 0; r < 4; r++)
                    sm[b * TILE + (m * 16 + gq * 4 + r) * MSTR + n * 16 + l15] =
                        f2bf(silu_f(acc[b][m][n][r]));
    asm volatile("s_waitcnt lgkmcnt(0)" ::: "memory");

    // ---- GEMM2 ----
    f32x4 acc2[2][2][4];
    #pragma unroll
    for (int n = 0; n < 4; n++) {
        float bias = b_e2[n * 16 + l15];
        #pragma unroll
        for (int b = 0; b < 2; b++)
            #pragma unroll
            for (int m = 0; m < 2; m++) acc2[b][m][n] = f32x4{bias, bias, bias, bias};
    }
    #pragma unroll
    for (int s = 0; s < 2; s++) {
        short8 afr[2][2];
        #pragma unroll
        for (int b = 0; b < 2; b++)
            #pragma unroll
            for (int m = 0; m < 2; m++)
                afr[b][m] = *reinterpret_cast<const short8*>(
                    sm + b * TILE + (m * 16 + l15) * MSTR + s * 32 + kg);
        __builtin_amdgcn_s_setprio(1);
        #pragma unroll
        for (int n = 0; n < 4; n++) {
            short8 bfr = pke2[(s * 4 + n) * 64 + lane];
            #pragma unroll
            for (int b = 0; b < 2; b++)
                #pragma unroll
                for (int m = 0; m < 2; m++)
                    acc2[b][m][n] = __builtin_amdgcn_mfma_f32_16x16x32_bf16(afr[b][m], bfr, acc2[b][m][n], 0, 0, 0);
        }
        __builtin_amdgcn_s_setprio(0);
    }
    asm volatile("s_waitcnt lgkmcnt(0)" ::: "memory");

    // ---- m = softsign(acc2) -> LDS ----
    #pragma unroll
    for (int b = 0; b < 2; b++)
        #pragma unroll
        for (int m = 0; m < 2; m++)
            #pragma unroll
            for (int n = 0; n < 4; n++)
                #pragma unroll
                for (int r = 0; r < 4; r++)
                    sm[b * TILE + (m * 16 + gq * 4 + r) * MSTR + n * 16 + l15] =
                        f2bf(ssgn_f(acc2[b][m][n][r]));
    asm volatile("s_waitcnt lgkmcnt(0)" ::: "memory");

    // ---- GEMM3 + phi ----
    f32x4 acc3[2][2][4];
    #pragma unroll
    for (int n = 0; n < 4; n++) {
        float bias = b_c1[n * 16 + l15];
        #pragma unroll
        for (int b = 0; b < 2; b++)
            #pragma unroll
            for (int m = 0; m < 2; m++) acc3[b][m][n] = f32x4{bias, bias, bias, bias};
    }
    #pragma unroll
    for (int s = 0; s < 2; s++) {
        short8 afr[2][2];
        #pragma unroll
        for (int b = 0; b < 2; b++)
            #pragma unroll
            for (int m = 0; m < 2; m++)
                afr[b][m] = *reinterpret_cast<const short8*>(
                    sm + b * TILE + (m * 16 + l15) * MSTR + s * 32 + kg);
        __builtin_amdgcn_s_setprio(1);
        #pragma unroll
        for (int n = 0; n < 4; n++) {
            short8 bfr = pkc1[(s * 4 + n) * 64 + lane];
            #pragma unroll
            for (int b = 0; b < 2; b++)
                #pragma unroll
                for (int m = 0; m < 2; m++)
                    acc3[b][m][n] = __builtin_amdgcn_mfma_f32_16x16x32_bf16(afr[b][m], bfr, acc3[b][m][n], 0, 0, 0);
        }
        __builtin_amdgcn_s_setprio(0);
    }
    float wc2v[4];
    #pragma unroll
    for (int n = 0; n < 4; n++) wc2v[n] = w_c2[n * 16 + l15];
    #pragma unroll
    for (int b = 0; b < 2; b++)
        #pragma unroll
        for (int m = 0; m < 2; m++)
            #pragma unroll
            for (int r = 0; r < 4; r++) {
                float v = 0.0f;
                #pragma unroll
                for (int n = 0; n < 4; n++) v = fmaf(silu_f(acc3[b][m][n][r]), wc2v[n], v);
                v += __shfl_xor(v, 1); v += __shfl_xor(v, 2);
                v += __shfl_xor(v, 4); v += __shfl_xor(v, 8);
                if (l15 == 0) smf[b * (TILE / 2) + (m * 16 + gq * 4 + r) * 36 + 32] = v;
            }
    asm volatile("s_waitcnt lgkmcnt(0)" ::: "memory");

    // ---- weighted coordinates into spare slots (lanes 0..31) ----
    if (lane < 32) {
        const float smv = sm_p[0], omv = om_p[0];
        float phi0 = smf[lane * 36 + 32];
        float phi1 = smf[(TILE / 2) + lane * 36 + 32];
        float4 wv0, wv1;
        wv0.x = (smv * xr0.x + omv * xc0.x) * phi0;
        wv0.y = (smv * xr0.y + omv * xc0.y) * phi0;
        wv0.z = (smv * xr0.z + omv * xc0.z) * phi0;
        wv0.w = (smv * xr0.w + omv * xc0.w) * phi0;
        wv1.x = (smv * xr1.x + omv * xc1.x) * phi1;
        wv1.y = (smv * xr1.y + omv * xc1.y) * phi1;
        wv1.z = (smv * xr1.z + omv * xc1.z) * phi1;
        wv1.w = (smv * xr1.w + omv * xc1.w) * phi1;
        *reinterpret_cast<float4*>(smf + lane * 36 + 32) = wv0;
        *reinterpret_cast<float4*>(smf + (TILE / 2) + lane * 36 + 32) = wv1;
    }
    asm volatile("s_waitcnt lgkmcnt(0)" ::: "memory");

    // ---- shared ballot run-merged scatter over 32 edges, both batches ----
    int nrow = __shfl_down(row, 1);
    unsigned long long bmask = __ballot((lane == 31) || (lane < 31 && row != nrow));
    float* aggb0 = agg;
    float* aggb1 = agg + (size_t)NN * 64;
    float* xb    = xagg + (size_t)((lane >> 2) & 1) * NN * 4;   // lanes 0-3 b0, 4-7 b1
    const int xsel = ((lane >> 2) & 1) * (TILE / 2) + (lane & 3);
    float mv0 = 0.0f, mv1 = 0.0f, xv = 0.0f;
    #pragma unroll
    for (int e = 0; e < 32; e++) {
        mv0 += bf2f(sm[e * MSTR + lane]);
        mv1 += bf2f(sm[TILE + e * MSTR + lane]);
        float t = smf[e * 36 + 32 + xsel];
        xv += (lane < 8) ? t : 0.0f;
        if ((bmask >> e) & 1ull) {
            int re = __shfl(row, e);
            atomicAdd(aggb0 + (size_t)re * 64 + lane, mv0);
            atomicAdd(aggb1 + (size_t)re * 64 + lane, mv1);
            if (lane < 8) atomicAdd(xb + (size_t)re * 4 + (lane & 3), xv);
            mv0 = 0.0f; mv1 = 0.0f; xv = 0.0f;
        }
    }
}

// ---------------------------------------------------------------------------
__global__ __launch_bounds__(256, 4) void node_kernel(
    const short* __restrict__ hb16, const float* __restrict__ x,
    const float* __restrict__ b_f1, const float* __restrict__ b_f2,
    const short* __restrict__ pk,
    const int* __restrict__ off,
    float* out_h, float* out_x)
{
    __shared__ short smem[4][64 * MSTR];
    const int wid  = threadIdx.x >> 6;
    const int lane = threadIdx.x & 63;
    short* sm = smem[wid];

    const int WN = (NN + 63) / 64;
    const int gw = blockIdx.x * 4 + wid;
    if (gw >= NB * WN) return;
    const int b  = gw / WN;
    const int n0 = (gw - b * WN) * 64;

    const int l15 = lane & 15;
    const int gq  = lane >> 4;
    const int kg  = gq * 8;

    const short* hbb  = hb16 + (size_t)b * NN * 64;
    const float* aggb = out_h + (size_t)b * NN * 64;

    f32x4 acc[4][4];
    #pragma unroll
    for (int n = 0; n < 4; n++) {
        float bias = b_f1[n * 16 + l15];
        #pragma unroll
        for (int m = 0; m < 4; m++) acc[m][n] = f32x4{bias, bias, bias, bias};
    }
    const short8* pkf1 = reinterpret_cast<const short8*>(pk + P_F1);
    #pragma unroll
    for (int s = 0; s < 4; s++) {
        short8 afr[4];
        #pragma unroll
        for (int m = 0; m < 4; m++) {
            int nd = n0 + m * 16 + l15;
            if (nd >= NN) nd = NN - 1;
            if (s < 2) {
                afr[m] = *reinterpret_cast<const short8*>(
                    hbb + (size_t)nd * 64 + s * 32 + kg);
            } else {
                const float* base = aggb + (size_t)nd * 64 + (s & 1) * 32 + kg;
                float4 lo = *reinterpret_cast<const float4*>(base);
                float4 hi = *reinterpret_cast<const float4*>(base + 4);
                afr[m] = pack8(lo, hi);
            }
        }
        __builtin_amdgcn_s_setprio(1);
        #pragma unroll
        for (int n = 0; n < 4; n++) {
            short8 bfr = pkf1[(s * 4 + n) * 64 + lane];
            #pragma unroll
            for (int m = 0; m < 4; m++)
                acc[m][n] = __builtin_amdgcn_mfma_f32_16x16x32_bf16(afr[m], bfr, acc[m][n], 0, 0, 0);
        }
        __builtin_amdgcn_s_setprio(0);
    }

    #pragma unroll
    for (int m = 0; m < 4; m++)
        #pragma unroll
        for (int n = 0; n < 4; n++)
            #pragma unroll
            for (int r = 0; r < 4; r++)
                sm[(m * 16 + gq * 4 + r) * MSTR + n * 16 + l15] = f2bf(silu_f(acc[m][n][r]));
    asm volatile("s_waitcnt lgkmcnt(0)" ::: "memory");

    f32x4 acc2[4][4];
    #pragma unroll
    for (int n = 0; n < 4; n++) {
        float bias = b_f2[n * 16 + l15];
        #pragma unroll
        for (int m = 0; m < 4; m++) acc2[m][n] = f32x4{bias, bias, bias, bias};
    }
    const short8* pkf2 = reinterpret_cast<const short8*>(pk + P_F2);
    #pragma unroll
    for (int s = 0; s < 2; s++) {
        short8 afr[4];
        #pragma unroll
        for (int m = 0; m < 4; m++)
            afr[m] = *reinterpret_cast<const short8*>(sm + (m * 16 + l15) * MSTR + s * 32 + kg);
        __builtin_amdgcn_s_setprio(1);
        #pragma unroll
        for (int n = 0; n < 4; n++) {
            short8 bfr = pkf2[(s * 4 + n) * 64 + lane];
            #pragma unroll
            for (int m = 0; m < 4; m++)
                acc2[m][n] = __builtin_amdgcn_mfma_f32_16x16x32_bf16(afr[m], bfr, acc2[m][n], 0, 0, 0);
        }
        __builtin_amdgcn_s_setprio(0);
    }

    float* ohb = out_h + (size_t)b * NN * 64;
    #pragma unroll
    for (int m = 0; m < 4; m++)
        #pragma unroll
        for (int r = 0; r < 4; r++) {
            int nd = n0 + m * 16 + gq * 4 + r;
            if (nd < NN) {
                #pragma unroll
                for (int n = 0; n < 4; n++)
                    ohb[(size_t)nd * 64 + n * 16 + l15] = ssgn_f(acc2[m][n][r]);
            }
        }

    const int node = n0 + lane;
    if (node < NN) {
        int c_i = off[node + 1] - off[node];
        float c = (float)(c_i < 1 ? 1 : c_i);
        float invc = fast_rcp(c);
        const float4 xv = *reinterpret_cast<const float4*>(x + ((size_t)b * NN + node) * 4);
        float* xop = out_x + ((size_t)b * NN + node) * 4;
        float4 xa = *reinterpret_cast<float4*>(xop);
        float4 r;
        r.x = xv.x + xa.x * invc;
        r.y = xv.y + xa.y * invc;
        r.z = xv.z + xa.z * invc;
        r.w = xv.w + xa.w * invc;
        *reinterpret_cast<float4*>(xop) = r;
    }
}

// ---------------------------------------------------------------------------
extern "C" void kernel_launch(void* const* d_in, const int* in_sizes, int n_in,
                              void* d_out, int out_size, void* d_ws, size_t ws_size,
                              hipStream_t stream) {
    const float* h    = (const float*)d_in[0];
    const float* x    = (const float*)d_in[1];
    const int*   ei   = (const int*)d_in[2];
    const float* ea   = (const float*)d_in[3];
    const float* w_e1 = (const float*)d_in[4];
    const float* b_e1 = (const float*)d_in[5];
    const float* w_e2 = (const float*)d_in[6];
    const float* b_e2 = (const float*)d_in[7];
    const float* w_f1 = (const float*)d_in[8];
    const float* b_f1 = (const float*)d_in[9];
    const float* w_f2 = (const float*)d_in[10];
    const float* b_f2 = (const float*)d_in[11];
    const float* w_c1 = (const float*)d_in[12];
    const float* b_c1 = (const float*)d_in[13];
    const float* w_c2 = (const float*)d_in[14];
    const float* smp  = (const float*)d_in[15];
    const float* omp  = (const float*)d_in[16];

    float* out   = (float*)d_out;
    float* agg   = out;
    float* out_x = out + (size_t)NB * NN * 64;

    char* ws = (char*)d_ws;
    int*   cnt_i = (int*)(ws + WS_CNT);
    int*   off   = (int*)(ws + WS_OFF);
    int*   cur   = (int*)(ws + WS_CUR);
    int4*  ecs   = (int4*)(ws + WS_ECS);
    short* pk    = (short*)(ws + WS_PK);
    short* hb16  = (short*)(ws + WS_HB);

    hipMemsetAsync(d_out, 0, (size_t)out_size * sizeof(float), stream);
    hipMemsetAsync(cnt_i, 0, (size_t)NN * sizeof(int), stream);

    prep_kernel<<<PREP_CONV + PREP_PACK + PREP_HIST, 256, 0, stream>>>(
        h, hb16, w_e1, w_e2, w_c1, w_f1, w_f2, pk, ei, cnt_i);
    scan_kernel<<<1, 1024, 0, stream>>>(cnt_i, off, cur);
    scatter_kernel<<<(EE + 255) / 256, 256, 0, stream>>>(ei, cur, ecs);

    const int edge_waves = EE / 32;                   // 31250 (batch-paired)
    const int edge_blocks = (edge_waves + 3) / 4;     // 7813
    edge_kernel<<<edge_blocks, 256, 0, stream>>>(
        hb16, x, ea, ecs, b_e1, b_e2, b_c1, w_c2, pk,
        smp, omp, agg, out_x);

    const int node_waves = NB * ((NN + 63) / 64);
    const int node_blocks = (node_waves + 3) / 4;
    node_kernel<<<node_blocks, 256, 0, stream>>>(
        hb16, x, b_f1, b_f2, pk, off, agg, out_x);
}

// Round 13
// 484.102 us; speedup vs baseline: 1.3474x; 1.0081x over previous
//
#include <hip/hip_runtime.h>
#include <hip/hip_bf16.h>
#include <cstdint>
#include <cstddef>

#define NN 50000     // nodes
#define EE 1000000   // edges
#define NB 2         // batch

#define MSTR 72      // tile stride (shorts): 144 B rows; cols 0..63 = m, 64..71 spare (phi/swv)
#define TILE (32 * MSTR)   // one batch m-tile, shorts (2304 = 4608 B)

// packed-weight layout (shorts): B-fragment order [kstep][ntile][lane][8]
#define P_E1 0
#define P_E2 10240
#define P_C1 14336
#define P_F1 18432
#define P_F2 26624
// staged-to-LDS edge weights: e1 s0..3 (8192) + e2 (4096) + c1 (4096) shorts
#define WL_E1 0
#define WL_E2 8192
#define WL_C1 12288
#define WL_TOTAL 16384   // 32,768 B

// d_ws byte offsets
#define WS_CNT   0            // int[NN]
#define WS_OFF   200704       // int[NN+1]
#define WS_CUR   401408       // int[NN]
#define WS_ECS   602112       // int4[EE]  (16 MB)
#define WS_PK    16602112     // short[30720]
#define WS_HB    16663552     // short[NB*NN*64]  (12.8 MB)

typedef __attribute__((ext_vector_type(8))) short short8;
typedef __attribute__((ext_vector_type(4))) float f32x4;

__device__ __forceinline__ float fast_rcp(float v) { return __builtin_amdgcn_rcpf(v); }
__device__ __forceinline__ float silu_f(float v) { return v * fast_rcp(1.0f + __expf(-v)); }
__device__ __forceinline__ float ssgn_f(float v) { return v * fast_rcp(1.0f + fabsf(v)); }

__device__ __forceinline__ short f2bf(float f) {
    __hip_bfloat16 h = __float2bfloat16(f);
    return *reinterpret_cast<short*>(&h);
}
__device__ __forceinline__ float bf2f(short s) {
    union { unsigned u; float f; } c; c.u = ((unsigned)(unsigned short)s) << 16; return c.f;
}
__device__ __forceinline__ short8 pack8(float4 a, float4 b) {
    short8 r;
    r[0] = f2bf(a.x); r[1] = f2bf(a.y); r[2] = f2bf(a.z); r[3] = f2bf(a.w);
    r[4] = f2bf(b.x); r[5] = f2bf(b.y); r[6] = f2bf(b.z); r[7] = f2bf(b.w);
    return r;
}

// ---------------------------------------------------------------------------
// Fused prep: conv_h | pack_weights | hist
// ---------------------------------------------------------------------------
#define PREP_CONV 3125
#define PREP_PACK 15
#define PREP_HIST 3907

__global__ void prep_kernel(const float* __restrict__ h, short* __restrict__ hb16,
                            const float* __restrict__ w_e1, const float* __restrict__ w_e2,
                            const float* __restrict__ w_c1, const float* __restrict__ w_f1,
                            const float* __restrict__ w_f2, short* __restrict__ pk,
                            const int* __restrict__ ei, int* __restrict__ cnt_i)
{
    const int bid = blockIdx.x;
    if (bid < PREP_CONV) {
        size_t i = ((size_t)bid * 256 + threadIdx.x) * 8;
        float4 lo = *reinterpret_cast<const float4*>(h + i);
        float4 hi = *reinterpret_cast<const float4*>(h + i + 4);
        *reinterpret_cast<short8*>(hb16 + i) = pack8(lo, hi);
    } else if (bid < PREP_CONV + PREP_PACK) {
        int g = (bid - PREP_CONV) * 256 + threadIdx.x;
        const int G_E1 = 5 * 4 * 64, G_E2 = 2 * 4 * 64, G_C1 = 2 * 4 * 64;
        const int G_F1 = 4 * 4 * 64, G_F2 = 2 * 4 * 64;
        if (g >= G_E1 + G_E2 + G_C1 + G_F1 + G_F2) return;
        const float* W; int loc; int mat;
        if (g < G_E1)                        { W = w_e1; loc = g;                         mat = 0; }
        else if (g < G_E1+G_E2)              { W = w_e2; loc = g - G_E1;                  mat = 1; }
        else if (g < G_E1+G_E2+G_C1)         { W = w_c1; loc = g - G_E1 - G_E2;           mat = 2; }
        else if (g < G_E1+G_E2+G_C1+G_F1)    { W = w_f1; loc = g - G_E1 - G_E2 - G_C1;    mat = 3; }
        else                                 { W = w_f2; loc = g - G_E1-G_E2-G_C1-G_F1;   mat = 4; }
        int l = loc & 63, n = (loc >> 6) & 3, s = loc >> 8;
        short8 out;
        #pragma unroll
        for (int j = 0; j < 8; j++) {
            int kp = s * 32 + ((l >> 4) * 8) + j;
            int ko; bool valid;
            if (mat == 0) {
                if (kp < 128)      { ko = kp;     valid = true; }
                else if (kp < 144) { ko = kp + 1; valid = true; }   // ea rows (orig 129..144)
                else if (kp == 144){ ko = 128;    valid = true; }   // radial row
                else               { ko = 0;      valid = false; }
            } else if (mat == 3) { ko = kp; valid = kp < 128; }
            else                 { ko = kp; valid = kp < 64; }
            float v = valid ? W[ko * 64 + (n * 16 + (l & 15))] : 0.0f;
            out[j] = f2bf(v);
        }
        *reinterpret_cast<short8*>(pk + (size_t)g * 8) = out;
    } else {
        int e = (bid - PREP_CONV - PREP_PACK) * 256 + threadIdx.x;
        if (e < EE) atomicAdd(&cnt_i[ei[e]], 1);
    }
}

// ---------------------------------------------------------------------------
__global__ void scan_kernel(const int* __restrict__ cnt_i,
                            int* __restrict__ off, int* __restrict__ cur) {
    __shared__ int part[1024];
    const int t = threadIdx.x;
    const int CH = (NN + 1023) / 1024;
    int base = t * CH;
    int s = 0;
    for (int j = 0; j < CH; j++) { int idx = base + j; if (idx < NN) s += cnt_i[idx]; }
    part[t] = s;
    __syncthreads();
    for (int d = 1; d < 1024; d <<= 1) {
        int v = (t >= d) ? part[t - d] : 0;
        __syncthreads();
        part[t] += v;
        __syncthreads();
    }
    int excl = (t == 0) ? 0 : part[t - 1];
    for (int j = 0; j < CH; j++) {
        int idx = base + j;
        if (idx < NN) { off[idx] = excl; cur[idx] = excl; excl += cnt_i[idx]; }
    }
    if (t == 1023) off[NN] = part[1023];
}

__global__ void scatter_kernel(const int* __restrict__ ei,
                               int* __restrict__ cur, int4* __restrict__ ecs) {
    int e = blockIdx.x * 256 + threadIdx.x;
    if (e < EE) {
        int r = ei[e], c = ei[EE + e];
        int p = atomicAdd(&cur[r], 1);
        ecs[p] = make_int4(e, r, c, 0);
    }
}

// ---------------------------------------------------------------------------
// Edge kernel: 32 sorted edges x both batches per wave. ALL steady-state edge
// weights (e1 main + e2 + c1 = 32 frags) staged to block LDS; single-batch
// activation tile per wave, GEMM2/3+scatter per batch sequentially.
// Block LDS 51,200 B -> 3 blocks/CU.
// ---------------------------------------------------------------------------
__global__ __launch_bounds__(256, 3) void edge_kernel(
    const short* __restrict__ hb16, const float* __restrict__ x,
    const float* __restrict__ ea, const int4* __restrict__ ecs,
    const float* __restrict__ b_e1, const float* __restrict__ b_e2,
    const float* __restrict__ b_c1, const float* __restrict__ w_c2,
    const short* __restrict__ pk,
    const float* __restrict__ sm_p, const float* __restrict__ om_p,
    float* __restrict__ agg, float* __restrict__ xagg)
{
    __shared__ short wlds[WL_TOTAL];         // 32,768 B: e1 main + e2 + c1
    __shared__ short smem[4][TILE];          // 18,432 B (4 waves x 1 batch tile)
    const int wid  = threadIdx.x >> 6;
    const int lane = threadIdx.x & 63;
    short* sm  = smem[wid];
    float* smf = reinterpret_cast<float*>(sm);

    // ---- stage edge weights to LDS (whole block, before any exit) ----
    {
        short8* dst = reinterpret_cast<short8*>(wlds);
        const short8* s1 = reinterpret_cast<const short8*>(pk + P_E1);
        const short8* s2 = reinterpret_cast<const short8*>(pk + P_E2);
        const short8* s3 = reinterpret_cast<const short8*>(pk + P_C1);
        #pragma unroll
        for (int i = 0; i < 4; i++)          // e1 s0..3: 1024 short8
            dst[i * 256 + threadIdx.x] = s1[i * 256 + threadIdx.x];
        #pragma unroll
        for (int i = 0; i < 2; i++)          // e2: 512 short8
            dst[1024 + i * 256 + threadIdx.x] = s2[i * 256 + threadIdx.x];
        #pragma unroll
        for (int i = 0; i < 2; i++)          // c1: 512 short8
            dst[1536 + i * 256 + threadIdx.x] = s3[i * 256 + threadIdx.x];
    }
    __syncthreads();

    // bijective XCD swizzle (m204)
    const int nwg = gridDim.x;
    const int q = nwg >> 3, r_ = nwg & 7;
    const int xcd = blockIdx.x & 7, kk = blockIdx.x >> 3;
    const int bswz = (xcd < r_ ? xcd * (q + 1) : r_ * (q + 1) + (xcd - r_) * q) + kk;

    const int WPB = EE / 32;               // 31250 edge windows
    const int gw = bswz * 4 + wid;
    if (gw >= WPB) return;                 // after the only barrier: safe
    const int i0 = gw * 32;

    const int l15 = lane & 15;
    const int gq  = lane >> 4;
    const int kg  = gq * 8;

    // per-edge scalars on lanes 0..31 (shared across batches)
    int eid = 0, row = 0, col = 0;
    float4 xrv[2], xcv[2];
    float rad[2] = {0.0f, 0.0f};
    xrv[0] = float4{0,0,0,0}; xrv[1] = float4{0,0,0,0};
    xcv[0] = float4{0,0,0,0}; xcv[1] = float4{0,0,0,0};
    if (lane < 32) {
        int4 ec = ecs[i0 + lane];          // coalesced 16B
        eid = ec.x; row = ec.y; col = ec.z;
        #pragma unroll
        for (int b = 0; b < 2; b++) {
            xrv[b] = *reinterpret_cast<const float4*>(x + ((size_t)b * NN + row) * 4);
            xcv[b] = *reinterpret_cast<const float4*>(x + ((size_t)b * NN + col) * 4);
            float d0 = xrv[b].x - xcv[b].x, d1 = xrv[b].y - xcv[b].y;
            float d2 = xrv[b].z - xcv[b].z, d3 = xrv[b].w - xcv[b].w;
            rad[b] = d1 * d1 + d2 * d2 + d3 * d3 - d0 * d0;
        }
    }

    int rowm[2], colm[2], eidm[2];
    float radm[2][2];
    #pragma unroll
    for (int m = 0; m < 2; m++) {
        int src = m * 16 + l15;            // < 32
        rowm[m] = __shfl(row, src);
        colm[m] = __shfl(col, src);
        eidm[m] = __shfl(eid, src);
        radm[0][m] = __shfl(rad[0], src);
        radm[1][m] = __shfl(rad[1], src);
    }
    const short* hbb[2] = { hb16, hb16 + (size_t)NN * 64 };
    const short8* pke1L = reinterpret_cast<const short8*>(wlds + WL_E1);
    const short8* pke2L = reinterpret_cast<const short8*>(wlds + WL_E2);
    const short8* pkc1L = reinterpret_cast<const short8*>(wlds + WL_C1);
    const short8* pke1G = reinterpret_cast<const short8*>(pk + P_E1);  // s=4 tail only

    // ---- tail fragments (ea random + radial), both batches ----
    short8 tail[2][2];
    #pragma unroll
    for (int b = 0; b < 2; b++)
        #pragma unroll
        for (int m = 0; m < 2; m++) {
            short8 v = short8{0, 0, 0, 0, 0, 0, 0, 0};
            if (gq < 2) {
                const float* src = ea + ((size_t)b * EE + eidm[m]) * 16 + gq * 8;
                float4 lo = *reinterpret_cast<const float4*>(src);
                float4 hi = *reinterpret_cast<const float4*>(src + 4);
                v = pack8(lo, hi);
            } else if (gq == 2) {
                v[0] = f2bf(radm[b][m]);
            }
            tail[b][m] = v;
        }

    // ---- GEMM1: acc[b][m][n] (batch-paired: weights read once) ----
    f32x4 acc[2][2][4];
    #pragma unroll
    for (int n = 0; n < 4; n++) {
        float bias = b_e1[n * 16 + l15];
        #pragma unroll
        for (int b = 0; b < 2; b++)
            #pragma unroll
            for (int m = 0; m < 2; m++) acc[b][m][n] = f32x4{bias, bias, bias, bias};
    }
    // tail first (global B-frags, only 4 global weight segments left)
    __builtin_amdgcn_s_setprio(1);
    #pragma unroll
    for (int n = 0; n < 4; n++) {
        short8 bfr = pke1G[(4 * 4 + n) * 64 + lane];
        #pragma unroll
        for (int b = 0; b < 2; b++)
            #pragma unroll
            for (int m = 0; m < 2; m++)
                acc[b][m][n] = __builtin_amdgcn_mfma_f32_16x16x32_bf16(tail[b][m], bfr, acc[b][m][n], 0, 0, 0);
    }
    __builtin_amdgcn_s_setprio(0);
    // h rows (run-repeated, cache-friendly; B-frags from LDS)
    #pragma unroll
    for (int s = 0; s < 2; s++) {
        short8 afr[2][2];
        #pragma unroll
        for (int b = 0; b < 2; b++)
            #pragma unroll
            for (int m = 0; m < 2; m++)
                afr[b][m] = *reinterpret_cast<const short8*>(
                    hbb[b] + (size_t)rowm[m] * 64 + s * 32 + kg);
        __builtin_amdgcn_s_setprio(1);
        #pragma unroll
        for (int n = 0; n < 4; n++) {
            short8 bfr = pke1L[(s * 4 + n) * 64 + lane];
            #pragma unroll
            for (int b = 0; b < 2; b++)
                #pragma unroll
                for (int m = 0; m < 2; m++)
                    acc[b][m][n] = __builtin_amdgcn_mfma_f32_16x16x32_bf16(afr[b][m], bfr, acc[b][m][n], 0, 0, 0);
        }
        __builtin_amdgcn_s_setprio(0);
    }
    // h cols (random gathers; B-frags from LDS)
    #pragma unroll
    for (int s2 = 0; s2 < 2; s2++) {
        short8 afr[2][2];
        #pragma unroll
        for (int b = 0; b < 2; b++)
            #pragma unroll
            for (int m = 0; m < 2; m++)
                afr[b][m] = *reinterpret_cast<const short8*>(
                    hbb[b] + (size_t)colm[m] * 64 + s2 * 32 + kg);
        __builtin_amdgcn_s_setprio(1);
        #pragma unroll
        for (int n = 0; n < 4; n++) {
            short8 bfr = pke1L[((2 + s2) * 4 + n) * 64 + lane];
            #pragma unroll
            for (int b = 0; b < 2; b++)
                #pragma unroll
                for (int m = 0; m < 2; m++)
                    acc[b][m][n] = __builtin_amdgcn_mfma_f32_16x16x32_bf16(afr[b][m], bfr, acc[b][m][n], 0, 0, 0);
        }
        __builtin_amdgcn_s_setprio(0);
    }

    // ---- shared ballot for the run-merged scatters ----
    int nrow = __shfl_down(row, 1);
    unsigned long long bmask = __ballot((lane == 31) || (lane < 31 && row != nrow));
    const float smv = sm_p[0], omv = om_p[0];
    float wc2v[4];
    #pragma unroll
    for (int n = 0; n < 4; n++) wc2v[n] = w_c2[n * 16 + l15];

    // ---- per batch: GEMM2/3 + phi + swv + scatter, reusing ONE tile ----
    #pragma unroll
    for (int b = 0; b < 2; b++) {
        // t1 = silu(acc[b]) -> tile
        #pragma unroll
        for (int m = 0; m < 2; m++)
            #pragma unroll
            for (int n = 0; n < 4; n++)
                #pragma unroll
                for (int r = 0; r < 4; r++)
                    sm[(m * 16 + gq * 4 + r) * MSTR + n * 16 + l15] =
                        f2bf(silu_f(acc[b][m][n][r]));
        asm volatile("s_waitcnt lgkmcnt(0)" ::: "memory");

        // GEMM2
        f32x4 acc2[2][4];
        #pragma unroll
        for (int n = 0; n < 4; n++) {
            float bias = b_e2[n * 16 + l15];
            #pragma unroll
            for (int m = 0; m < 2; m++) acc2[m][n] = f32x4{bias, bias, bias, bias};
        }
        #pragma unroll
        for (int s = 0; s < 2; s++) {
            short8 afr[2];
            #pragma unroll
            for (int m = 0; m < 2; m++)
                afr[m] = *reinterpret_cast<const short8*>(
                    sm + (m * 16 + l15) * MSTR + s * 32 + kg);
            __builtin_amdgcn_s_setprio(1);
            #pragma unroll
            for (int n = 0; n < 4; n++) {
                short8 bfr = pke2L[(s * 4 + n) * 64 + lane];
                #pragma unroll
                for (int m = 0; m < 2; m++)
                    acc2[m][n] = __builtin_amdgcn_mfma_f32_16x16x32_bf16(afr[m], bfr, acc2[m][n], 0, 0, 0);
            }
            __builtin_amdgcn_s_setprio(0);
        }
        asm volatile("s_waitcnt lgkmcnt(0)" ::: "memory");

        // m = softsign(acc2) -> tile (overwrites t1)
        #pragma unroll
        for (int m = 0; m < 2; m++)
            #pragma unroll
            for (int n = 0; n < 4; n++)
                #pragma unroll
                for (int r = 0; r < 4; r++)
                    sm[(m * 16 + gq * 4 + r) * MSTR + n * 16 + l15] =
                        f2bf(ssgn_f(acc2[m][n][r]));
        asm volatile("s_waitcnt lgkmcnt(0)" ::: "memory");

        // GEMM3 + phi
        f32x4 acc3[2][4];
        #pragma unroll
        for (int n = 0; n < 4; n++) {
            float bias = b_c1[n * 16 + l15];
            #pragma unroll
            for (int m = 0; m < 2; m++) acc3[m][n] = f32x4{bias, bias, bias, bias};
        }
        #pragma unroll
        for (int s = 0; s < 2; s++) {
            short8 afr[2];
            #pragma unroll
            for (int m = 0; m < 2; m++)
                afr[m] = *reinterpret_cast<const short8*>(
                    sm + (m * 16 + l15) * MSTR + s * 32 + kg);
            __builtin_amdgcn_s_setprio(1);
            #pragma unroll
            for (int n = 0; n < 4; n++) {
                short8 bfr = pkc1L[(s * 4 + n) * 64 + lane];
                #pragma unroll
                for (int m = 0; m < 2; m++)
                    acc3[m][n] = __builtin_amdgcn_mfma_f32_16x16x32_bf16(afr[m], bfr, acc3[m][n], 0, 0, 0);
            }
            __builtin_amdgcn_s_setprio(0);
        }
        #pragma unroll
        for (int m = 0; m < 2; m++)
            #pragma unroll
            for (int r = 0; r < 4; r++) {
                float v = 0.0f;
                #pragma unroll
                for (int n = 0; n < 4; n++) v = fmaf(silu_f(acc3[m][n][r]), wc2v[n], v);
                v += __shfl_xor(v, 1); v += __shfl_xor(v, 2);
                v += __shfl_xor(v, 4); v += __shfl_xor(v, 8);
                if (l15 == 0) smf[(m * 16 + gq * 4 + r) * 36 + 32] = v;
            }
        asm volatile("s_waitcnt lgkmcnt(0)" ::: "memory");

        // weighted coordinates into spare slots (lanes 0..31)
        if (lane < 32) {
            float phiv = smf[lane * 36 + 32];
            float4 wv;
            wv.x = (smv * xrv[b].x + omv * xcv[b].x) * phiv;
            wv.y = (smv * xrv[b].y + omv * xcv[b].y) * phiv;
            wv.z = (smv * xrv[b].z + omv * xcv[b].z) * phiv;
            wv.w = (smv * xrv[b].w + omv * xcv[b].w) * phiv;
            *reinterpret_cast<float4*>(smf + lane * 36 + 32) = wv;
        }
        asm volatile("s_waitcnt lgkmcnt(0)" ::: "memory");

        // run-merged scatter for batch b
        float* aggb = agg + (size_t)b * NN * 64;
        float* xb   = xagg + (size_t)b * NN * 4;
        float mv = 0.0f, xv = 0.0f;
        #pragma unroll
        for (int e = 0; e < 32; e++) {
            mv += bf2f(sm[e * MSTR + lane]);
            float t = smf[e * 36 + 32 + (lane & 3)];
            xv += (lane < 4) ? t : 0.0f;
            if ((bmask >> e) & 1ull) {
                int re = __shfl(row, e);
                atomicAdd(aggb + (size_t)re * 64 + lane, mv);
                if (lane < 4) atomicAdd(xb + (size_t)re * 4 + lane, xv);
                mv = 0.0f; xv = 0.0f;
            }
        }
        asm volatile("s_waitcnt lgkmcnt(0)" ::: "memory");
    }
}

// ---------------------------------------------------------------------------
__global__ __launch_bounds__(256, 4) void node_kernel(
    const short* __restrict__ hb16, const float* __restrict__ x,
    const float* __restrict__ b_f1, const float* __restrict__ b_f2,
    const short* __restrict__ pk,
    const int* __restrict__ off,
    float* out_h, float* out_x)
{
    __shared__ short smem[4][64 * MSTR];
    const int wid  = threadIdx.x >> 6;
    const int lane = threadIdx.x & 63;
    short* sm = smem[wid];

    const int WN = (NN + 63) / 64;
    const int gw = blockIdx.x * 4 + wid;
    if (gw >= NB * WN) return;
    const int b  = gw / WN;
    const int n0 = (gw - b * WN) * 64;

    const int l15 = lane & 15;
    const int gq  = lane >> 4;
    const int kg  = gq * 8;

    const short* hbb  = hb16 + (size_t)b * NN * 64;
    const float* aggb = out_h + (size_t)b * NN * 64;

    f32x4 acc[4][4];
    #pragma unroll
    for (int n = 0; n < 4; n++) {
        float bias = b_f1[n * 16 + l15];
        #pragma unroll
        for (int m = 0; m < 4; m++) acc[m][n] = f32x4{bias, bias, bias, bias};
    }
    const short8* pkf1 = reinterpret_cast<const short8*>(pk + P_F1);
    #pragma unroll
    for (int s = 0; s < 4; s++) {
        short8 afr[4];
        #pragma unroll
        for (int m = 0; m < 4; m++) {
            int nd = n0 + m * 16 + l15;
            if (nd >= NN) nd = NN - 1;
            if (s < 2) {
                afr[m] = *reinterpret_cast<const short8*>(
                    hbb + (size_t)nd * 64 + s * 32 + kg);
            } else {
                const float* base = aggb + (size_t)nd * 64 + (s & 1) * 32 + kg;
                float4 lo = *reinterpret_cast<const float4*>(base);
                float4 hi = *reinterpret_cast<const float4*>(base + 4);
                afr[m] = pack8(lo, hi);
            }
        }
        __builtin_amdgcn_s_setprio(1);
        #pragma unroll
        for (int n = 0; n < 4; n++) {
            short8 bfr = pkf1[(s * 4 + n) * 64 + lane];
            #pragma unroll
            for (int m = 0; m < 4; m++)
                acc[m][n] = __builtin_amdgcn_mfma_f32_16x16x32_bf16(afr[m], bfr, acc[m][n], 0, 0, 0);
        }
        __builtin_amdgcn_s_setprio(0);
    }

    #pragma unroll
    for (int m = 0; m < 4; m++)
        #pragma unroll
        for (int n = 0; n < 4; n++)
            #pragma unroll
            for (int r = 0; r < 4; r++)
                sm[(m * 16 + gq * 4 + r) * MSTR + n * 16 + l15] = f2bf(silu_f(acc[m][n][r]));
    asm volatile("s_waitcnt lgkmcnt(0)" ::: "memory");

    f32x4 acc2[4][4];
    #pragma unroll
    for (int n = 0; n < 4; n++) {
        float bias = b_f2[n * 16 + l15];
        #pragma unroll
        for (int m = 0; m < 4; m++) acc2[m][n] = f32x4{bias, bias, bias, bias};
    }
    const short8* pkf2 = reinterpret_cast<const short8*>(pk + P_F2);
    #pragma unroll
    for (int s = 0; s < 2; s++) {
        short8 afr[4];
        #pragma unroll
        for (int m = 0; m < 4; m++)
            afr[m] = *reinterpret_cast<const short8*>(sm + (m * 16 + l15) * MSTR + s * 32 + kg);
        __builtin_amdgcn_s_setprio(1);
        #pragma unroll
        for (int n = 0; n < 4; n++) {
            short8 bfr = pkf2[(s * 4 + n) * 64 + lane];
            #pragma unroll
            for (int m = 0; m < 4; m++)
                acc2[m][n] = __builtin_amdgcn_mfma_f32_16x16x32_bf16(afr[m], bfr, acc2[m][n], 0, 0, 0);
        }
        __builtin_amdgcn_s_setprio(0);
    }

    float* ohb = out_h + (size_t)b * NN * 64;
    #pragma unroll
    for (int m = 0; m < 4; m++)
        #pragma unroll
        for (int r = 0; r < 4; r++) {
            int nd = n0 + m * 16 + gq * 4 + r;
            if (nd < NN) {
                #pragma unroll
                for (int n = 0; n < 4; n++)
                    ohb[(size_t)nd * 64 + n * 16 + l15] = ssgn_f(acc2[m][n][r]);
            }
        }

    const int node = n0 + lane;
    if (node < NN) {
        int c_i = off[node + 1] - off[node];
        float c = (float)(c_i < 1 ? 1 : c_i);
        float invc = fast_rcp(c);
        const float4 xv = *reinterpret_cast<const float4*>(x + ((size_t)b * NN + node) * 4);
        float* xop = out_x + ((size_t)b * NN + node) * 4;
        float4 xa = *reinterpret_cast<float4*>(xop);
        float4 r;
        r.x = xv.x + xa.x * invc;
        r.y = xv.y + xa.y * invc;
        r.z = xv.z + xa.z * invc;
        r.w = xv.w + xa.w * invc;
        *reinterpret_cast<float4*>(xop) = r;
    }
}

// ---------------------------------------------------------------------------
extern "C" void kernel_launch(void* const* d_in, const int* in_sizes, int n_in,
                              void* d_out, int out_size, void* d_ws, size_t ws_size,
                              hipStream_t stream) {
    const float* h    = (const float*)d_in[0];
    const float* x    = (const float*)d_in[1];
    const int*   ei   = (const int*)d_in[2];
    const float* ea   = (const float*)d_in[3];
    const float* w_e1 = (const float*)d_in[4];
    const float* b_e1 = (const float*)d_in[5];
    const float* w_e2 = (const float*)d_in[6];
    const float* b_e2 = (const float*)d_in[7];
    const float* w_f1 = (const float*)d_in[8];
    const float* b_f1 = (const float*)d_in[9];
    const float* w_f2 = (const float*)d_in[10];
    const float* b_f2 = (const float*)d_in[11];
    const float* w_c1 = (const float*)d_in[12];
    const float* b_c1 = (const float*)d_in[13];
    const float* w_c2 = (const float*)d_in[14];
    const float* smp  = (const float*)d_in[15];
    const float* omp  = (const float*)d_in[16];

    float* out   = (float*)d_out;
    float* agg   = out;
    float* out_x = out + (size_t)NB * NN * 64;

    char* ws = (char*)d_ws;
    int*   cnt_i = (int*)(ws + WS_CNT);
    int*   off   = (int*)(ws + WS_OFF);
    int*   cur   = (int*)(ws + WS_CUR);
    int4*  ecs   = (int4*)(ws + WS_ECS);
    short* pk    = (short*)(ws + WS_PK);
    short* hb16  = (short*)(ws + WS_HB);

    hipMemsetAsync(d_out, 0, (size_t)out_size * sizeof(float), stream);
    hipMemsetAsync(cnt_i, 0, (size_t)NN * sizeof(int), stream);

    prep_kernel<<<PREP_CONV + PREP_PACK + PREP_HIST, 256, 0, stream>>>(
        h, hb16, w_e1, w_e2, w_c1, w_f1, w_f2, pk, ei, cnt_i);
    scan_kernel<<<1, 1024, 0, stream>>>(cnt_i, off, cur);
    scatter_kernel<<<(EE + 255) / 256, 256, 0, stream>>>(ei, cur, ecs);

    const int edge_waves = EE / 32;                   // 31250 (batch-paired)
    const int edge_blocks = (edge_waves + 3) / 4;     // 7813
    edge_kernel<<<edge_blocks, 256, 0, stream>>>(
        hb16, x, ea, ecs, b_e1, b_e2, b_c1, w_c2, pk,
        smp, omp, agg, out_x);

    const int node_waves = NB * ((NN + 63) / 64);
    const int node_blocks = (node_waves + 3) / 4;
    node_kernel<<<node_blocks, 256, 0, stream>>>(
        hb16, x, b_f1, b_f2, pk, off, agg, out_x);
}

// Round 14
// 447.553 us; speedup vs baseline: 1.4575x; 1.0817x over previous
//
#include <hip/hip_runtime.h>
#include <hip/hip_bf16.h>
#include <cstdint>
#include <cstddef>

#define NN 50000     // nodes
#define EE 1000000   // edges
#define NB 2         // batch
#define OUT_ELEMS (NB * NN * 64 + NB * NN * 4)   // 6,800,000 floats

#define MSTR 72      // tile stride (shorts): 144 B rows; cols 0..63 = m, 64..71 spare
#define TILE (32 * MSTR)   // one batch m-tile, shorts (2304)

// packed-weight layout (shorts): B-fragment order [kstep][ntile][lane][8]
#define P_E1 0
#define P_E2 10240
#define P_C1 14336
#define P_F1 18432
#define P_F2 26624
#define E1_MAIN_SHORTS 8192      // e1 s=0..3 staged to LDS (16,384 B)

// d_ws byte offsets
#define WS_CNT   0            // int[NN]
#define WS_OFF   200704       // int[NN+1]
#define WS_CUR   401408       // int[NN]
#define WS_ECS   602112       // int4[EE]  (16 MB)
#define WS_PK    16602112     // short[30720]
#define WS_HB    16663552     // short[NB*NN*64]  (12.8 MB)
#define WS_LIN   29463552     // short8[EE] lin streams (16 MB)

typedef __attribute__((ext_vector_type(8))) short short8;
typedef __attribute__((ext_vector_type(4))) float f32x4;

__device__ __forceinline__ float fast_rcp(float v) { return __builtin_amdgcn_rcpf(v); }
__device__ __forceinline__ float silu_f(float v) { return v * fast_rcp(1.0f + __expf(-v)); }
__device__ __forceinline__ float ssgn_f(float v) { return v * fast_rcp(1.0f + fabsf(v)); }

__device__ __forceinline__ short f2bf(float f) {
    __hip_bfloat16 h = __float2bfloat16(f);
    return *reinterpret_cast<short*>(&h);
}
__device__ __forceinline__ float bf2f(short s) {
    union { unsigned u; float f; } c; c.u = ((unsigned)(unsigned short)s) << 16; return c.f;
}
__device__ __forceinline__ short8 pack8(float4 a, float4 b) {
    short8 r;
    r[0] = f2bf(a.x); r[1] = f2bf(a.y); r[2] = f2bf(a.z); r[3] = f2bf(a.w);
    r[4] = f2bf(b.x); r[5] = f2bf(b.y); r[6] = f2bf(b.z); r[7] = f2bf(b.w);
    return r;
}

// ---------------------------------------------------------------------------
// Fused prep: conv_h | pack_weights | hist | zero d_out
// ---------------------------------------------------------------------------
#define PREP_CONV 3125
#define PREP_PACK 15
#define PREP_HIST 3907
#define PREP_ZERO 3321

__global__ void prep_kernel(const float* __restrict__ h, short* __restrict__ hb16,
                            const float* __restrict__ w_e1, const float* __restrict__ w_e2,
                            const float* __restrict__ w_c1, const float* __restrict__ w_f1,
                            const float* __restrict__ w_f2, short* __restrict__ pk,
                            const int* __restrict__ ei, int* __restrict__ cnt_i,
                            float* __restrict__ out)
{
    const int bid = blockIdx.x;
    if (bid < PREP_CONV) {
        size_t i = ((size_t)bid * 256 + threadIdx.x) * 8;
        float4 lo = *reinterpret_cast<const float4*>(h + i);
        float4 hi = *reinterpret_cast<const float4*>(h + i + 4);
        *reinterpret_cast<short8*>(hb16 + i) = pack8(lo, hi);
    } else if (bid < PREP_CONV + PREP_PACK) {
        int g = (bid - PREP_CONV) * 256 + threadIdx.x;
        const int G_E1 = 5 * 4 * 64, G_E2 = 2 * 4 * 64, G_C1 = 2 * 4 * 64;
        const int G_F1 = 4 * 4 * 64, G_F2 = 2 * 4 * 64;
        if (g >= G_E1 + G_E2 + G_C1 + G_F1 + G_F2) return;
        const float* W; int loc; int mat;
        if (g < G_E1)                        { W = w_e1; loc = g;                         mat = 0; }
        else if (g < G_E1+G_E2)              { W = w_e2; loc = g - G_E1;                  mat = 1; }
        else if (g < G_E1+G_E2+G_C1)         { W = w_c1; loc = g - G_E1 - G_E2;           mat = 2; }
        else if (g < G_E1+G_E2+G_C1+G_F1)    { W = w_f1; loc = g - G_E1 - G_E2 - G_C1;    mat = 3; }
        else                                 { W = w_f2; loc = g - G_E1-G_E2-G_C1-G_F1;   mat = 4; }
        int l = loc & 63, n = (loc >> 6) & 3, s = loc >> 8;
        short8 out8;
        #pragma unroll
        for (int j = 0; j < 8; j++) {
            int kp = s * 32 + ((l >> 4) * 8) + j;
            int ko; bool valid;
            if (mat == 0) {
                if (kp < 128)      { ko = kp;     valid = true; }
                else if (kp < 144) { ko = kp + 1; valid = true; }   // ea rows (orig 129..144)
                else if (kp == 144){ ko = 128;    valid = true; }   // radial row
                else               { ko = 0;      valid = false; }
            } else if (mat == 3) { ko = kp; valid = kp < 128; }
            else                 { ko = kp; valid = kp < 64; }
            float v = valid ? W[ko * 64 + (n * 16 + (l & 15))] : 0.0f;
            out8[j] = f2bf(v);
        }
        *reinterpret_cast<short8*>(pk + (size_t)g * 8) = out8;
    } else if (bid < PREP_CONV + PREP_PACK + PREP_HIST) {
        int e = (bid - PREP_CONV - PREP_PACK) * 256 + threadIdx.x;
        if (e < EE) atomicAdd(&cnt_i[ei[e]], 1);
    } else {
        size_t i = ((size_t)(bid - PREP_CONV - PREP_PACK - PREP_HIST) * 256 + threadIdx.x) * 8;
        if (i < OUT_ELEMS) {
            float4 z = float4{0, 0, 0, 0};
            *reinterpret_cast<float4*>(out + i)     = z;
            *reinterpret_cast<float4*>(out + i + 4) = z;
        }
    }
}

// ---------------------------------------------------------------------------
__global__ void scan_kernel(const int* __restrict__ cnt_i,
                            int* __restrict__ off, int* __restrict__ cur) {
    __shared__ int part[1024];
    const int t = threadIdx.x;
    const int CH = (NN + 1023) / 1024;
    int base = t * CH;
    int s = 0;
    for (int j = 0; j < CH; j++) { int idx = base + j; if (idx < NN) s += cnt_i[idx]; }
    part[t] = s;
    __syncthreads();
    for (int d = 1; d < 1024; d <<= 1) {
        int v = (t >= d) ? part[t - d] : 0;
        __syncthreads();
        part[t] += v;
        __syncthreads();
    }
    int excl = (t == 0) ? 0 : part[t - 1];
    for (int j = 0; j < CH; j++) {
        int idx = base + j;
        if (idx < NN) { off[idx] = excl; cur[idx] = excl; excl += cnt_i[idx]; }
    }
    if (t == 1023) off[NN] = part[1023];
}

// scatter: emits {eid,row,col,radpair} + lin streams per sorted position.
// x is L2-resident (1.6 MB) -> cheap gathers here; removes them from edge.
__global__ void scatter_kernel(const int* __restrict__ ei, const float* __restrict__ x,
                               const float* __restrict__ sm_p, const float* __restrict__ om_p,
                               int* __restrict__ cur, int4* __restrict__ ecs,
                               short* __restrict__ lins) {
    int e = blockIdx.x * 256 + threadIdx.x;
    if (e >= EE) return;
    int r = ei[e], c = ei[EE + e];
    int p = atomicAdd(&cur[r], 1);
    const float smv = sm_p[0], omv = om_p[0];
    short rp[2];
    short8 lv;
    #pragma unroll
    for (int b = 0; b < 2; b++) {
        float4 xr = *reinterpret_cast<const float4*>(x + ((size_t)b * NN + r) * 4);
        float4 xc = *reinterpret_cast<const float4*>(x + ((size_t)b * NN + c) * 4);
        float d0 = xr.x - xc.x, d1 = xr.y - xc.y, d2 = xr.z - xc.z, d3 = xr.w - xc.w;
        rp[b] = f2bf(d1 * d1 + d2 * d2 + d3 * d3 - d0 * d0);
        lv[b * 4 + 0] = f2bf(smv * xr.x + omv * xc.x);
        lv[b * 4 + 1] = f2bf(smv * xr.y + omv * xc.y);
        lv[b * 4 + 2] = f2bf(smv * xr.z + omv * xc.z);
        lv[b * 4 + 3] = f2bf(smv * xr.w + omv * xc.w);
    }
    int radpair = (int)(unsigned short)rp[0] | ((int)(unsigned short)rp[1] << 16);
    ecs[p] = make_int4(e, r, c, radpair);
    *reinterpret_cast<short8*>(lins + (size_t)p * 8) = lv;
}

// ---------------------------------------------------------------------------
// Edge kernel (r12 structure): 32 sorted edges x both batches per wave;
// e1 main weights staged to LDS (residual weights L1-resident); no x reads.
// Block LDS 53,248 B -> 3 blocks/CU.
// ---------------------------------------------------------------------------
__global__ __launch_bounds__(256, 3) void edge_kernel(
    const short* __restrict__ hb16,
    const float* __restrict__ ea, const int4* __restrict__ ecs,
    const short* __restrict__ lins,
    const float* __restrict__ b_e1, const float* __restrict__ b_e2,
    const float* __restrict__ b_c1, const float* __restrict__ w_c2,
    const short* __restrict__ pk,
    float* __restrict__ agg, float* __restrict__ xagg)
{
    __shared__ short wlds[E1_MAIN_SHORTS];   // 16,384 B: e1 s=0..3 B-frags
    __shared__ short smem[4][2 * TILE];      // 36,864 B (4 waves x 2 batch tiles)
    const int wid  = threadIdx.x >> 6;
    const int lane = threadIdx.x & 63;
    short* sm  = smem[wid];
    float* smf = reinterpret_cast<float*>(sm);

    // ---- stage e1 main weights to LDS (whole block, before any exit) ----
    {
        short8* dst = reinterpret_cast<short8*>(wlds);
        const short8* src = reinterpret_cast<const short8*>(pk);
        #pragma unroll
        for (int i = 0; i < E1_MAIN_SHORTS / 8 / 256; i++)   // 4 iters
            dst[i * 256 + threadIdx.x] = src[i * 256 + threadIdx.x];
    }
    __syncthreads();

    // bijective XCD swizzle (m204)
    const int nwg = gridDim.x;
    const int q = nwg >> 3, r_ = nwg & 7;
    const int xcd = blockIdx.x & 7, kk = blockIdx.x >> 3;
    const int bswz = (xcd < r_ ? xcd * (q + 1) : r_ * (q + 1) + (xcd - r_) * q) + kk;

    const int WPB = EE / 32;               // 31250 edge windows
    const int gw = bswz * 4 + wid;
    if (gw >= WPB) return;                 // after the only barrier: safe
    const int i0 = gw * 32;

    const int l15 = lane & 15;
    const int gq  = lane >> 4;
    const int kg  = gq * 8;

    // per-edge scalars on lanes 0..31 (shared across batches)
    int eid = 0, row = 0, col = 0, radpair = 0;
    short8 lv = short8{0, 0, 0, 0, 0, 0, 0, 0};
    if (lane < 32) {
        int4 ec = ecs[i0 + lane];          // coalesced 16B
        eid = ec.x; row = ec.y; col = ec.z; radpair = ec.w;
        lv = *reinterpret_cast<const short8*>(lins + (size_t)(i0 + lane) * 8);
    }

    int rowm[2], colm[2], eidm[2], radpm[2];
    #pragma unroll
    for (int m = 0; m < 2; m++) {
        int src = m * 16 + l15;            // < 32
        rowm[m] = __shfl(row, src);
        colm[m] = __shfl(col, src);
        eidm[m] = __shfl(eid, src);
        radpm[m] = __shfl(radpair, src);
    }
    const short* hbb[2] = { hb16, hb16 + (size_t)NN * 64 };
    const short8* pke1L = reinterpret_cast<const short8*>(wlds);       // s=0..3 (LDS)
    const short8* pke1G = reinterpret_cast<const short8*>(pk + P_E1);  // s=4 tail (global)
    const short8* pke2  = reinterpret_cast<const short8*>(pk + P_E2);
    const short8* pkc1  = reinterpret_cast<const short8*>(pk + P_C1);

    // ---- tail fragments (ea random + radial from stream), both batches ----
    short8 tail[2][2];
    #pragma unroll
    for (int b = 0; b < 2; b++)
        #pragma unroll
        for (int m = 0; m < 2; m++) {
            short8 v = short8{0, 0, 0, 0, 0, 0, 0, 0};
            if (gq < 2) {
                const float* src = ea + ((size_t)b * EE + eidm[m]) * 16 + gq * 8;
                float4 lo = *reinterpret_cast<const float4*>(src);
                float4 hi = *reinterpret_cast<const float4*>(src + 4);
                v = pack8(lo, hi);
            } else if (gq == 2) {
                v[0] = (short)((b == 0) ? (radpm[m] & 0xffff) : ((unsigned)radpm[m] >> 16));
            }
            tail[b][m] = v;
        }

    // ---- GEMM1: acc[b][m][n] (batch-paired) ----
    f32x4 acc[2][2][4];
    #pragma unroll
    for (int n = 0; n < 4; n++) {
        float bias = b_e1[n * 16 + l15];
        #pragma unroll
        for (int b = 0; b < 2; b++)
            #pragma unroll
            for (int m = 0; m < 2; m++) acc[b][m][n] = f32x4{bias, bias, bias, bias};
    }
    // tail first (global B-frags)
    __builtin_amdgcn_s_setprio(1);
    #pragma unroll
    for (int n = 0; n < 4; n++) {
        short8 bfr = pke1G[(4 * 4 + n) * 64 + lane];
        #pragma unroll
        for (int b = 0; b < 2; b++)
            #pragma unroll
            for (int m = 0; m < 2; m++)
                acc[b][m][n] = __builtin_amdgcn_mfma_f32_16x16x32_bf16(tail[b][m], bfr, acc[b][m][n], 0, 0, 0);
    }
    __builtin_amdgcn_s_setprio(0);
    // h rows (run-repeated; B-frags from LDS)
    #pragma unroll
    for (int s = 0; s < 2; s++) {
        short8 afr[2][2];
        #pragma unroll
        for (int b = 0; b < 2; b++)
            #pragma unroll
            for (int m = 0; m < 2; m++)
                afr[b][m] = *reinterpret_cast<const short8*>(
                    hbb[b] + (size_t)rowm[m] * 64 + s * 32 + kg);
        __builtin_amdgcn_s_setprio(1);
        #pragma unroll
        for (int n = 0; n < 4; n++) {
            short8 bfr = pke1L[(s * 4 + n) * 64 + lane];
            #pragma unroll
            for (int b = 0; b < 2; b++)
                #pragma unroll
                for (int m = 0; m < 2; m++)
                    acc[b][m][n] = __builtin_amdgcn_mfma_f32_16x16x32_bf16(afr[b][m], bfr, acc[b][m][n], 0, 0, 0);
        }
        __builtin_amdgcn_s_setprio(0);
    }
    // h cols (random gathers; B-frags from LDS)
    #pragma unroll
    for (int s2 = 0; s2 < 2; s2++) {
        short8 afr[2][2];
        #pragma unroll
        for (int b = 0; b < 2; b++)
            #pragma unroll
            for (int m = 0; m < 2; m++)
                afr[b][m] = *reinterpret_cast<const short8*>(
                    hbb[b] + (size_t)colm[m] * 64 + s2 * 32 + kg);
        __builtin_amdgcn_s_setprio(1);
        #pragma unroll
        for (int n = 0; n < 4; n++) {
            short8 bfr = pke1L[((2 + s2) * 4 + n) * 64 + lane];
            #pragma unroll
            for (int b = 0; b < 2; b++)
                #pragma unroll
                for (int m = 0; m < 2; m++)
                    acc[b][m][n] = __builtin_amdgcn_mfma_f32_16x16x32_bf16(afr[b][m], bfr, acc[b][m][n], 0, 0, 0);
        }
        __builtin_amdgcn_s_setprio(0);
    }

    // ---- t1 = silu(acc) -> LDS (both batch tiles) ----
    #pragma unroll
    for (int b = 0; b < 2; b++)
        #pragma unroll
        for (int m = 0; m < 2; m++)
            #pragma unroll
            for (int n = 0; n < 4; n++)
                #pragma unroll
                for (int r = 0; r < 4; r++)
                    sm[b * TILE + (m * 16 + gq * 4 + r) * MSTR + n * 16 + l15] =
                        f2bf(silu_f(acc[b][m][n][r]));
    asm volatile("s_waitcnt lgkmcnt(0)" ::: "memory");

    // ---- GEMM2 ----
    f32x4 acc2[2][2][4];
    #pragma unroll
    for (int n = 0; n < 4; n++) {
        float bias = b_e2[n * 16 + l15];
        #pragma unroll
        for (int b = 0; b < 2; b++)
            #pragma unroll
            for (int m = 0; m < 2; m++) acc2[b][m][n] = f32x4{bias, bias, bias, bias};
    }
    #pragma unroll
    for (int s = 0; s < 2; s++) {
        short8 afr[2][2];
        #pragma unroll
        for (int b = 0; b < 2; b++)
            #pragma unroll
            for (int m = 0; m < 2; m++)
                afr[b][m] = *reinterpret_cast<const short8*>(
                    sm + b * TILE + (m * 16 + l15) * MSTR + s * 32 + kg);
        __builtin_amdgcn_s_setprio(1);
        #pragma unroll
        for (int n = 0; n < 4; n++) {
            short8 bfr = pke2[(s * 4 + n) * 64 + lane];
            #pragma unroll
            for (int b = 0; b < 2; b++)
                #pragma unroll
                for (int m = 0; m < 2; m++)
                    acc2[b][m][n] = __builtin_amdgcn_mfma_f32_16x16x32_bf16(afr[b][m], bfr, acc2[b][m][n], 0, 0, 0);
        }
        __builtin_amdgcn_s_setprio(0);
    }
    asm volatile("s_waitcnt lgkmcnt(0)" ::: "memory");

    // ---- m = softsign(acc2) -> LDS ----
    #pragma unroll
    for (int b = 0; b < 2; b++)
        #pragma unroll
        for (int m = 0; m < 2; m++)
            #pragma unroll
            for (int n = 0; n < 4; n++)
                #pragma unroll
                for (int r = 0; r < 4; r++)
                    sm[b * TILE + (m * 16 + gq * 4 + r) * MSTR + n * 16 + l15] =
                        f2bf(ssgn_f(acc2[b][m][n][r]));
    asm volatile("s_waitcnt lgkmcnt(0)" ::: "memory");

    // ---- GEMM3 + phi ----
    f32x4 acc3[2][2][4];
    #pragma unroll
    for (int n = 0; n < 4; n++) {
        float bias = b_c1[n * 16 + l15];
        #pragma unroll
        for (int b = 0; b < 2; b++)
            #pragma unroll
            for (int m = 0; m < 2; m++) acc3[b][m][n] = f32x4{bias, bias, bias, bias};
    }
    #pragma unroll
    for (int s = 0; s < 2; s++) {
        short8 afr[2][2];
        #pragma unroll
        for (int b = 0; b < 2; b++)
            #pragma unroll
            for (int m = 0; m < 2; m++)
                afr[b][m] = *reinterpret_cast<const short8*>(
                    sm + b * TILE + (m * 16 + l15) * MSTR + s * 32 + kg);
        __builtin_amdgcn_s_setprio(1);
        #pragma unroll
        for (int n = 0; n < 4; n++) {
            short8 bfr = pkc1[(s * 4 + n) * 64 + lane];
            #pragma unroll
            for (int b = 0; b < 2; b++)
                #pragma unroll
                for (int m = 0; m < 2; m++)
                    acc3[b][m][n] = __builtin_amdgcn_mfma_f32_16x16x32_bf16(afr[b][m], bfr, acc3[b][m][n], 0, 0, 0);
        }
        __builtin_amdgcn_s_setprio(0);
    }
    float wc2v[4];
    #pragma unroll
    for (int n = 0; n < 4; n++) wc2v[n] = w_c2[n * 16 + l15];
    #pragma unroll
    for (int b = 0; b < 2; b++)
        #pragma unroll
        for (int m = 0; m < 2; m++)
            #pragma unroll
            for (int r = 0; r < 4; r++) {
                float v = 0.0f;
                #pragma unroll
                for (int n = 0; n < 4; n++) v = fmaf(silu_f(acc3[b][m][n][r]), wc2v[n], v);
                v += __shfl_xor(v, 1); v += __shfl_xor(v, 2);
                v += __shfl_xor(v, 4); v += __shfl_xor(v, 8);
                if (l15 == 0) smf[b * (TILE / 2) + (m * 16 + gq * 4 + r) * 36 + 32] = v;
            }
    asm volatile("s_waitcnt lgkmcnt(0)" ::: "memory");

    // ---- weighted coordinates = lin (from stream) * phi ----
    if (lane < 32) {
        float phi0 = smf[lane * 36 + 32];
        float phi1 = smf[(TILE / 2) + lane * 36 + 32];
        float4 wv0, wv1;
        wv0.x = bf2f(lv[0]) * phi0; wv0.y = bf2f(lv[1]) * phi0;
        wv0.z = bf2f(lv[2]) * phi0; wv0.w = bf2f(lv[3]) * phi0;
        wv1.x = bf2f(lv[4]) * phi1; wv1.y = bf2f(lv[5]) * phi1;
        wv1.z = bf2f(lv[6]) * phi1; wv1.w = bf2f(lv[7]) * phi1;
        *reinterpret_cast<float4*>(smf + lane * 36 + 32) = wv0;
        *reinterpret_cast<float4*>(smf + (TILE / 2) + lane * 36 + 32) = wv1;
    }
    asm volatile("s_waitcnt lgkmcnt(0)" ::: "memory");

    // ---- shared ballot run-merged scatter over 32 edges, both batches ----
    int nrow = __shfl_down(row, 1);
    unsigned long long bmask = __ballot((lane == 31) || (lane < 31 && row != nrow));
    float* aggb0 = agg;
    float* aggb1 = agg + (size_t)NN * 64;
    float* xb    = xagg + (size_t)((lane >> 2) & 1) * NN * 4;   // lanes 0-3 b0, 4-7 b1
    const int xsel = ((lane >> 2) & 1) * (TILE / 2) + (lane & 3);
    float mv0 = 0.0f, mv1 = 0.0f, xv = 0.0f;
    #pragma unroll
    for (int e = 0; e < 32; e++) {
        mv0 += bf2f(sm[e * MSTR + lane]);
        mv1 += bf2f(sm[TILE + e * MSTR + lane]);
        float t = smf[e * 36 + 32 + xsel];
        xv += (lane < 8) ? t : 0.0f;
        if ((bmask >> e) & 1ull) {
            int re = __shfl(row, e);
            atomicAdd(aggb0 + (size_t)re * 64 + lane, mv0);
            atomicAdd(aggb1 + (size_t)re * 64 + lane, mv1);
            if (lane < 8) atomicAdd(xb + (size_t)re * 4 + (lane & 3), xv);
            mv0 = 0.0f; mv1 = 0.0f; xv = 0.0f;
        }
    }
}

// ---------------------------------------------------------------------------
// Node kernel: M=32 tiles (782 blocks -> 2x parallelism vs M=64)
// ---------------------------------------------------------------------------
__global__ __launch_bounds__(256, 4) void node_kernel(
    const short* __restrict__ hb16, const float* __restrict__ x,
    const float* __restrict__ b_f1, const float* __restrict__ b_f2,
    const short* __restrict__ pk,
    const int* __restrict__ off,
    float* out_h, float* out_x)
{
    __shared__ short smem[4][32 * MSTR];
    const int wid  = threadIdx.x >> 6;
    const int lane = threadIdx.x & 63;
    short* sm = smem[wid];

    const int WN = (NN + 31) / 32;   // 1563
    const int gw = blockIdx.x * 4 + wid;
    if (gw >= NB * WN) return;
    const int b  = gw / WN;
    const int n0 = (gw - b * WN) * 32;

    const int l15 = lane & 15;
    const int gq  = lane >> 4;
    const int kg  = gq * 8;

    const short* hbb  = hb16 + (size_t)b * NN * 64;
    const float* aggb = out_h + (size_t)b * NN * 64;

    f32x4 acc[2][4];
    #pragma unroll
    for (int n = 0; n < 4; n++) {
        float bias = b_f1[n * 16 + l15];
        #pragma unroll
        for (int m = 0; m < 2; m++) acc[m][n] = f32x4{bias, bias, bias, bias};
    }
    const short8* pkf1 = reinterpret_cast<const short8*>(pk + P_F1);
    #pragma unroll
    for (int s = 0; s < 4; s++) {
        short8 afr[2];
        #pragma unroll
        for (int m = 0; m < 2; m++) {
            int nd = n0 + m * 16 + l15;
            if (nd >= NN) nd = NN - 1;
            if (s < 2) {
                afr[m] = *reinterpret_cast<const short8*>(
                    hbb + (size_t)nd * 64 + s * 32 + kg);
            } else {
                const float* base = aggb + (size_t)nd * 64 + (s & 1) * 32 + kg;
                float4 lo = *reinterpret_cast<const float4*>(base);
                float4 hi = *reinterpret_cast<const float4*>(base + 4);
                afr[m] = pack8(lo, hi);
            }
        }
        __builtin_amdgcn_s_setprio(1);
        #pragma unroll
        for (int n = 0; n < 4; n++) {
            short8 bfr = pkf1[(s * 4 + n) * 64 + lane];
            #pragma unroll
            for (int m = 0; m < 2; m++)
                acc[m][n] = __builtin_amdgcn_mfma_f32_16x16x32_bf16(afr[m], bfr, acc[m][n], 0, 0, 0);
        }
        __builtin_amdgcn_s_setprio(0);
    }

    #pragma unroll
    for (int m = 0; m < 2; m++)
        #pragma unroll
        for (int n = 0; n < 4; n++)
            #pragma unroll
            for (int r = 0; r < 4; r++)
                sm[(m * 16 + gq * 4 + r) * MSTR + n * 16 + l15] = f2bf(silu_f(acc[m][n][r]));
    asm volatile("s_waitcnt lgkmcnt(0)" ::: "memory");

    f32x4 acc2[2][4];
    #pragma unroll
    for (int n = 0; n < 4; n++) {
        float bias = b_f2[n * 16 + l15];
        #pragma unroll
        for (int m = 0; m < 2; m++) acc2[m][n] = f32x4{bias, bias, bias, bias};
    }
    const short8* pkf2 = reinterpret_cast<const short8*>(pk + P_F2);
    #pragma unroll
    for (int s = 0; s < 2; s++) {
        short8 afr[2];
        #pragma unroll
        for (int m = 0; m < 2; m++)
            afr[m] = *reinterpret_cast<const short8*>(sm + (m * 16 + l15) * MSTR + s * 32 + kg);
        __builtin_amdgcn_s_setprio(1);
        #pragma unroll
        for (int n = 0; n < 4; n++) {
            short8 bfr = pkf2[(s * 4 + n) * 64 + lane];
            #pragma unroll
            for (int m = 0; m < 2; m++)
                acc2[m][n] = __builtin_amdgcn_mfma_f32_16x16x32_bf16(afr[m], bfr, acc2[m][n], 0, 0, 0);
        }
        __builtin_amdgcn_s_setprio(0);
    }

    float* ohb = out_h + (size_t)b * NN * 64;
    #pragma unroll
    for (int m = 0; m < 2; m++)
        #pragma unroll
        for (int r = 0; r < 4; r++) {
            int nd = n0 + m * 16 + gq * 4 + r;
            if (nd < NN) {
                #pragma unroll
                for (int n = 0; n < 4; n++)
                    ohb[(size_t)nd * 64 + n * 16 + l15] = ssgn_f(acc2[m][n][r]);
            }
        }

    const int node = n0 + lane;
    if (lane < 32 && node < NN) {
        int c_i = off[node + 1] - off[node];
        float c = (float)(c_i < 1 ? 1 : c_i);
        float invc = fast_rcp(c);
        const float4 xv = *reinterpret_cast<const float4*>(x + ((size_t)b * NN + node) * 4);
        float* xop = out_x + ((size_t)b * NN + node) * 4;
        float4 xa = *reinterpret_cast<float4*>(xop);
        float4 r;
        r.x = xv.x + xa.x * invc;
        r.y = xv.y + xa.y * invc;
        r.z = xv.z + xa.z * invc;
        r.w = xv.w + xa.w * invc;
        *reinterpret_cast<float4*>(xop) = r;
    }
}

// ---------------------------------------------------------------------------
extern "C" void kernel_launch(void* const* d_in, const int* in_sizes, int n_in,
                              void* d_out, int out_size, void* d_ws, size_t ws_size,
                              hipStream_t stream) {
    const float* h    = (const float*)d_in[0];
    const float* x    = (const float*)d_in[1];
    const int*   ei   = (const int*)d_in[2];
    const float* ea   = (const float*)d_in[3];
    const float* w_e1 = (const float*)d_in[4];
    const float* b_e1 = (const float*)d_in[5];
    const float* w_e2 = (const float*)d_in[6];
    const float* b_e2 = (const float*)d_in[7];
    const float* w_f1 = (const float*)d_in[8];
    const float* b_f1 = (const float*)d_in[9];
    const float* w_f2 = (const float*)d_in[10];
    const float* b_f2 = (const float*)d_in[11];
    const float* w_c1 = (const float*)d_in[12];
    const float* b_c1 = (const float*)d_in[13];
    const float* w_c2 = (const float*)d_in[14];
    const float* smp  = (const float*)d_in[15];
    const float* omp  = (const float*)d_in[16];

    float* out   = (float*)d_out;
    float* agg   = out;
    float* out_x = out + (size_t)NB * NN * 64;

    char* ws = (char*)d_ws;
    int*   cnt_i = (int*)(ws + WS_CNT);
    int*   off   = (int*)(ws + WS_OFF);
    int*   cur   = (int*)(ws + WS_CUR);
    int4*  ecs   = (int4*)(ws + WS_ECS);
    short* pk    = (short*)(ws + WS_PK);
    short* hb16  = (short*)(ws + WS_HB);
    short* lins  = (short*)(ws + WS_LIN);

    hipMemsetAsync(cnt_i, 0, (size_t)NN * sizeof(int), stream);

    prep_kernel<<<PREP_CONV + PREP_PACK + PREP_HIST + PREP_ZERO, 256, 0, stream>>>(
        h, hb16, w_e1, w_e2, w_c1, w_f1, w_f2, pk, ei, cnt_i, out);
    scan_kernel<<<1, 1024, 0, stream>>>(cnt_i, off, cur);
    scatter_kernel<<<(EE + 255) / 256, 256, 0, stream>>>(ei, x, smp, omp, cur, ecs, lins);

    const int edge_waves = EE / 32;                   // 31250 (batch-paired)
    const int edge_blocks = (edge_waves + 3) / 4;     // 7813
    edge_kernel<<<edge_blocks, 256, 0, stream>>>(
        hb16, ea, ecs, lins, b_e1, b_e2, b_c1, w_c2, pk, agg, out_x);

    const int node_waves = NB * ((NN + 31) / 32);     // 3126
    const int node_blocks = (node_waves + 3) / 4;     // 782
    node_kernel<<<node_blocks, 256, 0, stream>>>(
        hb16, x, b_f1, b_f2, pk, off, agg, out_x);
}